// Round 9
// baseline (367.858 us; speedup 1.0000x reference)
//
#include <hip/hip_runtime.h>
#include <math.h>

// ---------------------------------------------------------------------------
// GCN: 4x (bf16-MFMA GEMM (B-in-LDS loaded once, A direct-from-global,
//          barrier-free slab loop; epilogue pre-scales rows by dis) ->
//          pure-sum aggregation (+bias, lrelu)) -> softmax.
// Graph prep per call (bucketed, LDS-local):
//   bin edges by dst>>8 -> per-bucket degree+dis -> scan -> bucket CSR in LDS.
// out[n] = dis[n]*( sum_e h'[s] + h'[n] ) + b,  h'[r] = dis[r]*(h@W)[r]
// Aggregation: quarter-split uint4 gathers (1 VMEM = 4 rows x 256B/4).
// ---------------------------------------------------------------------------

typedef unsigned short ushort_t;
typedef unsigned int   uint_t;
typedef short  bf16x8 __attribute__((ext_vector_type(8)));
typedef float  f32x4  __attribute__((ext_vector_type(4)));

#define BKT_SHIFT 8               // 256 nodes per bucket
#define BKT_CAP   5120            // >= max edges per bucket (mean 4096, +16 sigma)
#define BIN_CHUNK 4096            // edges per bin workgroup

__device__ __forceinline__ ushort_t f2bf(float f) {
    union { float f; uint_t u; } v; v.f = f;
    uint_t u = v.u;
    u += 0x7fffu + ((u >> 16) & 1u);      // round-to-nearest-even
    return (ushort_t)(u >> 16);
}
__device__ __forceinline__ float bflo(uint_t u) {
    union { uint_t q; float f; } v; v.q = u << 16; return v.f;
}
__device__ __forceinline__ float bfhi(uint_t u) {
    union { uint_t q; float f; } v; v.q = u & 0xffff0000u; return v.f;
}

// ------------------------------- graph prep -------------------------------

__global__ __launch_bounds__(256) void bin_kernel(const int* __restrict__ srcArr,
                                                  const int* __restrict__ dstArr,
                                                  int* __restrict__ bkt_cursor,
                                                  uint2* __restrict__ staging,
                                                  int E, int nb) {
    __shared__ int hist[512];
    __shared__ int base[512];
    for (int b = threadIdx.x; b < 512; b += 256) hist[b] = 0;
    __syncthreads();
    const int e0 = blockIdx.x * BIN_CHUNK;
    #pragma unroll 4
    for (int k = 0; k < BIN_CHUNK / 256; ++k) {
        int e = e0 + k * 256 + threadIdx.x;
        if (e < E) atomicAdd(&hist[dstArr[e] >> BKT_SHIFT], 1);
    }
    __syncthreads();
    for (int b = threadIdx.x; b < nb; b += 256) {
        int h = hist[b];
        base[b] = h ? atomicAdd(&bkt_cursor[b], h) : 0;
    }
    __syncthreads();
    for (int b = threadIdx.x; b < 512; b += 256) hist[b] = 0;  // reuse as cursor
    __syncthreads();
    #pragma unroll 4
    for (int k = 0; k < BIN_CHUNK / 256; ++k) {
        int e = e0 + k * 256 + threadIdx.x;
        if (e < E) {
            int s = srcArr[e], d = dstArr[e];
            int b = d >> BKT_SHIFT;
            int p = atomicAdd(&hist[b], 1);
            int idx = base[b] + p;
            if (idx < BKT_CAP)
                staging[(size_t)b * BKT_CAP + idx] = make_uint2((uint_t)s, (uint_t)d);
        }
    }
}

// per-bucket degree count (LDS-local) + dis = rsqrt(deg+1), coalesced writes
__global__ __launch_bounds__(256) void deg_from_staging_kernel(const uint2* __restrict__ staging,
                                                               const int* __restrict__ bkt_cursor,
                                                               int* __restrict__ degi,
                                                               float* __restrict__ dis, int n) {
    __shared__ int cur[256];
    const int b  = blockIdx.x;
    const int lo = b << BKT_SHIFT;
    const int nl = min(256, n - lo);
    cur[threadIdx.x] = 0;
    __syncthreads();
    int cnt = min(bkt_cursor[b], BKT_CAP);
    for (int e = threadIdx.x; e < cnt; e += 256) {
        uint2 p = staging[(size_t)b * BKT_CAP + e];
        atomicAdd(&cur[(int)p.y - lo], 1);
    }
    __syncthreads();
    if ((int)threadIdx.x < nl) {
        int d = cur[threadIdx.x];
        degi[lo + threadIdx.x] = d;
        dis[lo + threadIdx.x] = rsqrtf((float)(d + 1));
    }
}

// hierarchical exclusive scan
__global__ void scan_block_kernel(const int* __restrict__ degi, int* __restrict__ row_excl,
                                  int* __restrict__ bsums, int n) {
    __shared__ int buf[1024];
    int i = blockIdx.x * 1024 + threadIdx.x;
    int v = (i < n) ? degi[i] : 0;
    buf[threadIdx.x] = v;
    __syncthreads();
    for (int off = 1; off < 1024; off <<= 1) {
        int t = (threadIdx.x >= (unsigned)off) ? buf[threadIdx.x - off] : 0;
        __syncthreads();
        buf[threadIdx.x] += t;
        __syncthreads();
    }
    if (i < n) row_excl[i] = buf[threadIdx.x] - v;
    if (threadIdx.x == 1023) bsums[blockIdx.x] = buf[1023];
}

__global__ void scan_sums_kernel(int* __restrict__ bsums, int nb) {
    __shared__ int buf[128];
    int v = ((int)threadIdx.x < nb) ? bsums[threadIdx.x] : 0;
    buf[threadIdx.x] = v;
    __syncthreads();
    for (int off = 1; off < 128; off <<= 1) {
        int t = (threadIdx.x >= (unsigned)off) ? buf[threadIdx.x - off] : 0;
        __syncthreads();
        buf[threadIdx.x] += t;
        __syncthreads();
    }
    if ((int)threadIdx.x < nb) bsums[threadIdx.x] = buf[threadIdx.x] - v;
    if (threadIdx.x == 0) bsums[nb] = buf[127];
}

__global__ void scan_add_kernel(int* __restrict__ row_start, const int* __restrict__ bsums,
                                int n, int nb) {
    int i = blockIdx.x * blockDim.x + threadIdx.x;
    if (i < n) row_start[i] += bsums[i >> 10];
    else if (i == n) row_start[n] = bsums[nb];
}

// build each bucket's CSR segment in LDS, flush coalesced
__global__ __launch_bounds__(256) void csr_build_kernel(const uint2* __restrict__ staging,
                                                        const int* __restrict__ bkt_cursor,
                                                        const int* __restrict__ row_start,
                                                        int* __restrict__ csr_src, int n) {
    __shared__ int rs[257];
    __shared__ int cur[256];
    __shared__ int seg[BKT_CAP];
    const int b  = blockIdx.x;
    const int lo = b << BKT_SHIFT;
    const int nl = min(256, n - lo);
    if ((int)threadIdx.x <= nl) rs[threadIdx.x] = row_start[lo + threadIdx.x];
    cur[threadIdx.x] = 0;
    __syncthreads();
    const int sbase = rs[0];
    int cnt = min(bkt_cursor[b], BKT_CAP);
    for (int e = threadIdx.x; e < cnt; e += 256) {
        uint2 p = staging[(size_t)b * BKT_CAP + e];
        int ln = (int)p.y - lo;
        int q  = atomicAdd(&cur[ln], 1);
        seg[(rs[ln] - sbase) + q] = (int)p.x;
    }
    __syncthreads();
    for (int i = threadIdx.x; i < cnt; i += 256) csr_src[sbase + i] = seg[i];
}

// -------------------- weight transposes (one kernel) -----------------------
__global__ void wt_all_kernel(const float* __restrict__ W1, const float* __restrict__ W2,
                              const float* __restrict__ W3,
                              ushort_t* __restrict__ Wt1, ushort_t* __restrict__ Wt2,
                              ushort_t* __restrict__ Wt3) {
    int idx = blockIdx.x * blockDim.x + threadIdx.x;
    if (idx < 32768) {
        int nn = idx >> 8, k = idx & 255;
        Wt1[idx] = f2bf(W1[(size_t)k * 128 + nn]);
    } else if (idx < 49152) {
        int j = idx - 32768;
        int nn = j >> 7, k = j & 127;
        float v = (nn < 100) ? W2[(size_t)k * 100 + nn] : 0.f;
        Wt2[j] = f2bf(v);
    } else if (idx < 57344) {
        int j = idx - 49152;
        int nn = j >> 7, k = j & 127;
        float v = (k < 100 && nn < 32) ? W3[(size_t)k * 32 + nn] : 0.f;
        Wt3[j] = f2bf(v);
    }
}

// ------------------------ B-in-LDS MFMA GEMM -------------------------------
// C[M x cols nOff..nOff+NFR*16] (bf16) = dis[row] * (A[M x KFR*32] @ Wt^T).
// B tile lives in LDS (loaded once, XOR group-swizzle: group ^= row&7 ->
// bank-spread ds_read_b128). Slab loop has NO barriers: per 32-row slab,
// A fragments straight from global (16B/lane), B frags from LDS, 2*NFR*KFR
// MFMAs (swapped operands), 2*NFR uint2 stores (4 consecutive cols/lane).
template <bool A_FP32, int NFR, int KFR>
__global__ __launch_bounds__(256, 4) void gemm_ldsb(const void* __restrict__ Av,
                                                    const ushort_t* __restrict__ Bt,
                                                    ushort_t* __restrict__ C,
                                                    const float* __restrict__ dis,
                                                    int M, int lda, int ldb, int ldc) {
    constexpr int BROWS = NFR * 16;
    constexpr int BCOLS = KFR * 32;
    constexpr int GR    = BCOLS / 8;         // 16B groups per row
    __shared__ __attribute__((aligned(16))) ushort_t Bs[BROWS][BCOLS];

    const int lane = threadIdx.x & 63;
    const int rsel = lane & 15;
    const int q    = lane >> 4;              // 0..3
    const int kq   = q * 8;
    const int nOff = blockIdx.y * BROWS;

    // one-shot cooperative B load with XOR group swizzle
    for (int idx = threadIdx.x; idx < BROWS * GR; idx += 256) {
        int r = idx / GR, g = idx - r * GR;
        int gs = g ^ (r & 7);
        *(bf16x8*)&Bs[r][gs * 8] = *(const bf16x8*)(Bt + (size_t)(nOff + r) * ldb + g * 8);
    }
    __syncthreads();

    constexpr int KH    = (KFR > 4) ? 2 : 1;  // K halves (reg pressure)
    constexpr int CHUNK = KFR / KH;

    const int nSlab   = (M + 31) >> 5;
    const int wstride = gridDim.x * 4;
    for (int s = blockIdx.x * 4 + (threadIdx.x >> 6); s < nSlab; s += wstride) {
        const int row0 = s * 32;

        f32x4 acc[2][NFR];
        #pragma unroll
        for (int mi = 0; mi < 2; ++mi)
            #pragma unroll
            for (int ni = 0; ni < NFR; ++ni) acc[mi][ni] = (f32x4){0.f, 0.f, 0.f, 0.f};

        #pragma unroll
        for (int kh = 0; kh < KH; ++kh) {
            // A fragments for this K-half: straight from global
            bf16x8 af[2][CHUNK];
            #pragma unroll
            for (int mi = 0; mi < 2; ++mi) {
                const int gm = row0 + mi * 16 + rsel;
                #pragma unroll
                for (int kf = 0; kf < CHUNK; ++kf) {
                    const int kc = (kh * CHUNK + kf) * 32 + kq;
                    bf16x8 v = {0, 0, 0, 0, 0, 0, 0, 0};
                    if (gm < M) {
                        if (A_FP32) {
                            const float* A = (const float*)Av;
                            const float4 f0 = *(const float4*)(A + (size_t)gm * lda + kc);
                            const float4 f1 = *(const float4*)(A + (size_t)gm * lda + kc + 4);
                            ushort_t o[8] = { f2bf(f0.x), f2bf(f0.y), f2bf(f0.z), f2bf(f0.w),
                                              f2bf(f1.x), f2bf(f1.y), f2bf(f1.z), f2bf(f1.w) };
                            v = *(const bf16x8*)o;
                        } else {
                            const ushort_t* A = (const ushort_t*)Av;
                            v = *(const bf16x8*)(A + (size_t)gm * lda + kc);
                        }
                    }
                    af[mi][kf] = v;
                }
            }
            // MFMA: B frags from LDS (swizzled), swapped operands
            #pragma unroll
            for (int kf = 0; kf < CHUNK; ++kf) {
                const int kk = kh * CHUNK + kf;
                bf16x8 bfr[NFR];
                #pragma unroll
                for (int ni = 0; ni < NFR; ++ni) {
                    const int r  = ni * 16 + rsel;
                    const int gs = (kk * 4 + q) ^ (r & 7);
                    bfr[ni] = *(const bf16x8*)&Bs[r][gs * 8];
                }
                #pragma unroll
                for (int mi = 0; mi < 2; ++mi)
                    #pragma unroll
                    for (int ni = 0; ni < NFR; ++ni)
                        acc[mi][ni] = __builtin_amdgcn_mfma_f32_16x16x32_bf16(
                            bfr[ni], af[mi][kf], acc[mi][ni], 0, 0, 0);
            }
        }

        #pragma unroll
        for (int mi = 0; mi < 2; ++mi) {
            const int gm = row0 + mi * 16 + rsel;
            if (gm >= M) continue;
            const float d = dis[gm];
            #pragma unroll
            for (int ni = 0; ni < NFR; ++ni) {
                uint2 o;
                o.x = (uint_t)f2bf(acc[mi][ni][0] * d) | ((uint_t)f2bf(acc[mi][ni][1] * d) << 16);
                o.y = (uint_t)f2bf(acc[mi][ni][2] * d) | ((uint_t)f2bf(acc[mi][ni][3] * d) << 16);
                *(uint2*)(C + (size_t)gm * ldc + nOff + ni * 16 + q * 4) = o;
            }
        }
    }
}

// ---------------------------- aggregation ---------------------------------
// h rows pre-scaled (h' = dis*h). One wave per node. Quarter-split:
// lanes (l&15) cover features fb = (l&15)*8 (one uint4 = 8 bf16 = 16B),
// quarter q = l>>4 takes edge i+q; one VMEM gather = 4 rows x 256B/4 = 1KB.
template <int F>
__global__ void aggregate128_kernel(const ushort_t* __restrict__ h, const int* __restrict__ row_start,
                                    const int* __restrict__ csr_src,
                                    const float* __restrict__ dis, const float* __restrict__ bias,
                                    ushort_t* __restrict__ out, int n) {
    int wid  = threadIdx.x >> 6;
    int lane = threadIdx.x & 63;
    int node = blockIdx.x * 4 + wid;
    if (node >= n) return;
    const int q  = lane >> 4;
    const int fb = (lane & 15) * 8;
    float a[8];
    #pragma unroll
    for (int j = 0; j < 8; ++j) a[j] = 0.f;

    int i = row_start[node], end = row_start[node + 1];

#define ACC8(U)                                                     \
    do {                                                            \
        a[0] += bflo((U).x); a[1] += bfhi((U).x);                   \
        a[2] += bflo((U).y); a[3] += bfhi((U).y);                   \
        a[4] += bflo((U).z); a[5] += bfhi((U).z);                   \
        a[6] += bflo((U).w); a[7] += bfhi((U).w);                   \
    } while (0)

    #pragma unroll 2
    for (; i + 8 <= end; i += 8) {
        int sA = csr_src[i + q];
        int sB = csr_src[i + 4 + q];
        uint4 u = *(const uint4*)(h + (size_t)sA * 128 + fb);
        uint4 v = *(const uint4*)(h + (size_t)sB * 128 + fb);
        ACC8(u);
        ACC8(v);
    }
    int r = end - i;
    if (r > 0) {
        if (q < r) {
            int sA = csr_src[i + q];
            uint4 u = *(const uint4*)(h + (size_t)sA * 128 + fb);
            ACC8(u);
        }
        if (q + 4 < r) {
            int sB = csr_src[i + 4 + q];
            uint4 v = *(const uint4*)(h + (size_t)sB * 128 + fb);
            ACC8(v);
        }
    }
#undef ACC8

    // merge quarters: q0+=q1 (xor16), then +=q2/q3 (xor32)
    #pragma unroll
    for (int j = 0; j < 8; ++j) {
        a[j] += __shfl_xor(a[j], 16);
        a[j] += __shfl_xor(a[j], 32);
    }

    if (q == 0) {
        uint4 su = *(const uint4*)(h + (size_t)node * 128 + fb);   // self-loop
        a[0] += bflo(su.x); a[1] += bfhi(su.x);
        a[2] += bflo(su.y); a[3] += bfhi(su.y);
        a[4] += bflo(su.z); a[5] += bfhi(su.z);
        a[6] += bflo(su.w); a[7] += bfhi(su.w);
        float dn = dis[node];
        #pragma unroll
        for (int j = 0; j < 8; ++j) {
            float b = (fb + j < F) ? bias[fb + j] : 0.f;
            float v = a[j] * dn + b;
            v = (v > 0.f) ? v : 0.1f * v;
            if (fb + j >= F) v = 0.f;          // keep K-padding exactly zero
            a[j] = v;
        }
        uint4 o;
        o.x = (uint_t)f2bf(a[0]) | ((uint_t)f2bf(a[1]) << 16);
        o.y = (uint_t)f2bf(a[2]) | ((uint_t)f2bf(a[3]) << 16);
        o.z = (uint_t)f2bf(a[4]) | ((uint_t)f2bf(a[5]) << 16);
        o.w = (uint_t)f2bf(a[6]) | ((uint_t)f2bf(a[7]) << 16);
        *(uint4*)(out + (size_t)node * 128 + fb) = o;
    }
}

// F=32, h pre-scaled: 16-lane group per node (2 features/lane), 4 nodes/wave
__global__ void aggregate32_kernel(const ushort_t* __restrict__ h, const int* __restrict__ row_start,
                                   const int* __restrict__ csr_src,
                                   const float* __restrict__ dis, const float* __restrict__ bias,
                                   ushort_t* __restrict__ out, int n) {
    int lane16 = threadIdx.x & 15;
    int node = blockIdx.x * (blockDim.x >> 4) + (threadIdx.x >> 4);
    if (node >= n) return;
    const int f0 = 2 * lane16;
    uint_t v = *(const uint_t*)(h + (size_t)node * 32 + f0);
    float acc0 = bflo(v);               // self-loop (pre-scaled)
    float acc1 = bfhi(v);
    int i = row_start[node], end = row_start[node + 1];
    for (; i + 4 <= end; i += 4) {
        int s0 = csr_src[i], s1 = csr_src[i + 1], s2 = csr_src[i + 2], s3 = csr_src[i + 3];
        uint_t u0 = *(const uint_t*)(h + (size_t)s0 * 32 + f0);
        uint_t u1 = *(const uint_t*)(h + (size_t)s1 * 32 + f0);
        uint_t u2 = *(const uint_t*)(h + (size_t)s2 * 32 + f0);
        uint_t u3 = *(const uint_t*)(h + (size_t)s3 * 32 + f0);
        acc0 += bflo(u0) + bflo(u1) + bflo(u2) + bflo(u3);
        acc1 += bfhi(u0) + bfhi(u1) + bfhi(u2) + bfhi(u3);
    }
    for (; i < end; ++i) {
        int s = csr_src[i];
        uint_t u = *(const uint_t*)(h + (size_t)s * 32 + f0);
        acc0 += bflo(u); acc1 += bfhi(u);
    }
    float dn = dis[node];
    acc0 = acc0 * dn + bias[f0];
    acc1 = acc1 * dn + bias[f0 + 1];
    acc0 = (acc0 > 0.f) ? acc0 : 0.1f * acc0;
    acc1 = (acc1 > 0.f) ? acc1 : 0.1f * acc1;
    uint_t o = (uint_t)f2bf(acc0) | ((uint_t)f2bf(acc1) << 16);
    *(uint_t*)(out + (size_t)node * 32 + f0) = o;
}

// layer 4 GEMM: [N x 32] bf16 @ [32 x 2] fp32 -> fp32, pre-scaled by dis[node]
__global__ void gemm32x2_kernel(const ushort_t* __restrict__ H, const float* __restrict__ W4,
                                const float* __restrict__ dis, float* __restrict__ C, int n) {
    int node = blockIdx.x * blockDim.x + threadIdx.x;
    if (node >= n) return;
    const uint_t* row = (const uint_t*)(H + (size_t)node * 32);
    float a0 = 0.f, a1 = 0.f;
    #pragma unroll
    for (int k2 = 0; k2 < 16; ++k2) {
        uint_t u = row[k2];
        float x0 = bflo(u), x1 = bfhi(u);
        int k = 2 * k2;
        a0 += x0 * W4[k * 2]     + x1 * W4[(k + 1) * 2];
        a1 += x0 * W4[k * 2 + 1] + x1 * W4[(k + 1) * 2 + 1];
    }
    float d = dis[node];
    C[2 * (size_t)node]     = a0 * d;
    C[2 * (size_t)node + 1] = a1 * d;
}

// final aggregation (F=2, h pre-scaled) + bias + softmax, one thread per node
__global__ void aggregate2_softmax_kernel(const float* __restrict__ h, const int* __restrict__ row_start,
                                          const int* __restrict__ csr_src,
                                          const float* __restrict__ dis, const float* __restrict__ bias,
                                          float* __restrict__ out, int n) {
    int node = blockIdx.x * blockDim.x + threadIdx.x;
    if (node >= n) return;
    float a0 = h[2 * (size_t)node];
    float a1 = h[2 * (size_t)node + 1];
    int beg = row_start[node], end = row_start[node + 1];
    for (int i = beg; i < end; ++i) {
        int s = csr_src[i];
        a0 += h[2 * (size_t)s];
        a1 += h[2 * (size_t)s + 1];
    }
    float dn = dis[node];
    a0 = a0 * dn + bias[0];
    a1 = a1 * dn + bias[1];
    float m  = fmaxf(a0, a1);
    float e0 = expf(a0 - m), e1 = expf(a1 - m);
    float inv = 1.f / (e0 + e1);
    out[2 * (size_t)node]     = e0 * inv;
    out[2 * (size_t)node + 1] = e1 * inv;
}

// ---------------------------------------------------------------------------

extern "C" void kernel_launch(void* const* d_in, const int* in_sizes, int n_in,
                              void* d_out, int out_size, void* d_ws, size_t ws_size,
                              hipStream_t stream) {
    const float* x  = (const float*)d_in[0];
    const int*   ei = (const int*)d_in[1];
    const float* W1 = (const float*)d_in[2];
    const float* b1 = (const float*)d_in[3];
    const float* W2 = (const float*)d_in[4];
    const float* b2 = (const float*)d_in[5];
    const float* W3 = (const float*)d_in[6];
    const float* b3 = (const float*)d_in[7];
    const float* W4 = (const float*)d_in[8];
    const float* b4 = (const float*)d_in[9];

    const int N = in_sizes[0] / 256;
    const int E = in_sizes[1] / 2;
    const int* srcA = ei;
    const int* dstA = ei + E;
    const int nbkt = (N + 255) >> BKT_SHIFT;

    char* ws = (char*)d_ws;
    size_t off = 0;
    auto alloc = [&](size_t bytes) {
        void* p = ws + off;
        off = (off + bytes + 255) & ~(size_t)255;
        return p;
    };
    int*      degi       = (int*)alloc((size_t)N * 4);
    float*    dis        = (float*)alloc((size_t)N * 4);
    int*      row_start  = (int*)alloc((size_t)(N + 1) * 4);
    int*      bsums      = (int*)alloc(512 * 4);
    int*      bkt_cursor = (int*)alloc((size_t)nbkt * 4);
    int*      csr_src    = (int*)alloc((size_t)E * 4);
    uint2*    staging    = (uint2*)alloc((size_t)nbkt * BKT_CAP * 8);
    ushort_t* bufA       = (ushort_t*)alloc((size_t)N * 128 * 2);
    ushort_t* bufB       = (ushort_t*)alloc((size_t)N * 128 * 2);
    float*    C4         = (float*)alloc((size_t)N * 2 * 4);
    ushort_t* Wt1        = (ushort_t*)alloc((size_t)128 * 256 * 2);
    ushort_t* Wt2        = (ushort_t*)alloc((size_t)128 * 128 * 2);
    ushort_t* Wt3        = (ushort_t*)alloc((size_t)64 * 128 * 2);
    (void)ws_size;

    hipMemsetAsync(bkt_cursor, 0, (size_t)nbkt * 4, stream);

    // graph prep (bucketed)
    bin_kernel<<<(E + BIN_CHUNK - 1) / BIN_CHUNK, 256, 0, stream>>>(
        srcA, dstA, bkt_cursor, staging, E, nbkt);
    deg_from_staging_kernel<<<nbkt, 256, 0, stream>>>(staging, bkt_cursor, degi, dis, N);
    const int nb = (N + 1023) >> 10;
    scan_block_kernel<<<nb, 1024, 0, stream>>>(degi, row_start, bsums, N);
    scan_sums_kernel<<<1, 128, 0, stream>>>(bsums, nb);
    scan_add_kernel<<<(N + 256) / 256, 256, 0, stream>>>(row_start, bsums, N, nb);
    csr_build_kernel<<<nbkt, 256, 0, stream>>>(staging, bkt_cursor, row_start, csr_src, N);

    // weight transposes (bf16, padded) — one kernel
    wt_all_kernel<<<(57344 + 255) / 256, 256, 0, stream>>>(W1, W2, W3, Wt1, Wt2, Wt3);

    const int aggBlocks128 = (N + 3) / 4;    // 4 waves/block, 1 node/wave
    const int aggBlocks32  = (N + 15) / 16;  // 16 nodes/block

    // layer 1: 256 -> 128 (fp32 A converted in-flight; 2 N-halves of 64)
    gemm_ldsb<true, 4, 8><<<dim3(512, 2), 256, 0, stream>>>(
        x, Wt1, bufA, dis, N, 256, 256, 128);
    aggregate128_kernel<128><<<aggBlocks128, 256, 0, stream>>>(
        bufA, row_start, csr_src, dis, b1, bufB, N);
    // layer 2: 128 -> 100 (padded to 128); 2 N-halves of 64
    gemm_ldsb<false, 4, 4><<<dim3(512, 2), 256, 0, stream>>>(
        bufB, Wt2, bufA, dis, N, 128, 128, 128);
    aggregate128_kernel<100><<<aggBlocks128, 256, 0, stream>>>(
        bufA, row_start, csr_src, dis, b2, bufB, N);
    // layer 3: 128(pad) -> 32
    gemm_ldsb<false, 2, 4><<<dim3(1024, 1), 256, 0, stream>>>(
        bufB, Wt3, bufA, dis, N, 128, 128, 32);
    aggregate32_kernel<<<aggBlocks32, 256, 0, stream>>>(
        bufA, row_start, csr_src, dis, b3, bufB, N);
    // layer 4: 32 -> 2, aggregate + softmax
    gemm32x2_kernel<<<(N + 255) / 256, 256, 0, stream>>>(bufB, W4, dis, C4, N);
    aggregate2_softmax_kernel<<<(N + 255) / 256, 256, 0, stream>>>(
        C4, row_start, csr_src, dis, b4, (float*)d_out, N);
}

// Round 10
// 317.399 us; speedup vs baseline: 1.1590x; 1.1590x over previous
//
#include <hip/hip_runtime.h>
#include <math.h>

// ---------------------------------------------------------------------------
// GCN: cast x->bf16 once; 4x (bf16-MFMA tiled GEMM (BM=64,BN=full,BK=64,
//      4 waves 2Mx2N, LDS-staged, epilogue pre-scales rows by dis) ->
//      pure-sum aggregation (+bias, lrelu)) -> softmax.
// Graph prep per call (bucketed, LDS-local):
//   bin edges by dst>>8 -> per-bucket degree+dis -> scan -> bucket CSR in LDS.
// out[n] = dis[n]*( sum_e h'[s] + h'[n] ) + b,  h'[r] = dis[r]*(h@W)[r]
// Aggregation: quarter-split uint4 gathers (1 VMEM = 4 rows x 256B/4).
// ---------------------------------------------------------------------------

typedef unsigned short ushort_t;
typedef unsigned int   uint_t;
typedef short  bf16x8 __attribute__((ext_vector_type(8)));
typedef float  f32x4  __attribute__((ext_vector_type(4)));

#define BKT_SHIFT 8               // 256 nodes per bucket
#define BKT_CAP   5120            // >= max edges per bucket (mean 4096, +16 sigma)
#define BIN_CHUNK 4096            // edges per bin workgroup

__device__ __forceinline__ ushort_t f2bf(float f) {
    union { float f; uint_t u; } v; v.f = f;
    uint_t u = v.u;
    u += 0x7fffu + ((u >> 16) & 1u);      // round-to-nearest-even
    return (ushort_t)(u >> 16);
}
__device__ __forceinline__ float bflo(uint_t u) {
    union { uint_t q; float f; } v; v.q = u << 16; return v.f;
}
__device__ __forceinline__ float bfhi(uint_t u) {
    union { uint_t q; float f; } v; v.q = u & 0xffff0000u; return v.f;
}

// ------------------------------- graph prep -------------------------------

__global__ __launch_bounds__(256) void bin_kernel(const int* __restrict__ srcArr,
                                                  const int* __restrict__ dstArr,
                                                  int* __restrict__ bkt_cursor,
                                                  uint2* __restrict__ staging,
                                                  int E, int nb) {
    __shared__ int hist[512];
    __shared__ int base[512];
    for (int b = threadIdx.x; b < 512; b += 256) hist[b] = 0;
    __syncthreads();
    const int e0 = blockIdx.x * BIN_CHUNK;
    #pragma unroll 4
    for (int k = 0; k < BIN_CHUNK / 256; ++k) {
        int e = e0 + k * 256 + threadIdx.x;
        if (e < E) atomicAdd(&hist[dstArr[e] >> BKT_SHIFT], 1);
    }
    __syncthreads();
    for (int b = threadIdx.x; b < nb; b += 256) {
        int h = hist[b];
        base[b] = h ? atomicAdd(&bkt_cursor[b], h) : 0;
    }
    __syncthreads();
    for (int b = threadIdx.x; b < 512; b += 256) hist[b] = 0;  // reuse as cursor
    __syncthreads();
    #pragma unroll 4
    for (int k = 0; k < BIN_CHUNK / 256; ++k) {
        int e = e0 + k * 256 + threadIdx.x;
        if (e < E) {
            int s = srcArr[e], d = dstArr[e];
            int b = d >> BKT_SHIFT;
            int p = atomicAdd(&hist[b], 1);
            int idx = base[b] + p;
            if (idx < BKT_CAP)
                staging[(size_t)b * BKT_CAP + idx] = make_uint2((uint_t)s, (uint_t)d);
        }
    }
}

// per-bucket degree count (LDS-local) + dis = rsqrt(deg+1), coalesced writes
__global__ __launch_bounds__(256) void deg_from_staging_kernel(const uint2* __restrict__ staging,
                                                               const int* __restrict__ bkt_cursor,
                                                               int* __restrict__ degi,
                                                               float* __restrict__ dis, int n) {
    __shared__ int cur[256];
    const int b  = blockIdx.x;
    const int lo = b << BKT_SHIFT;
    const int nl = min(256, n - lo);
    cur[threadIdx.x] = 0;
    __syncthreads();
    int cnt = min(bkt_cursor[b], BKT_CAP);
    for (int e = threadIdx.x; e < cnt; e += 256) {
        uint2 p = staging[(size_t)b * BKT_CAP + e];
        atomicAdd(&cur[(int)p.y - lo], 1);
    }
    __syncthreads();
    if ((int)threadIdx.x < nl) {
        int d = cur[threadIdx.x];
        degi[lo + threadIdx.x] = d;
        dis[lo + threadIdx.x] = rsqrtf((float)(d + 1));
    }
}

// hierarchical exclusive scan
__global__ void scan_block_kernel(const int* __restrict__ degi, int* __restrict__ row_excl,
                                  int* __restrict__ bsums, int n) {
    __shared__ int buf[1024];
    int i = blockIdx.x * 1024 + threadIdx.x;
    int v = (i < n) ? degi[i] : 0;
    buf[threadIdx.x] = v;
    __syncthreads();
    for (int off = 1; off < 1024; off <<= 1) {
        int t = (threadIdx.x >= (unsigned)off) ? buf[threadIdx.x - off] : 0;
        __syncthreads();
        buf[threadIdx.x] += t;
        __syncthreads();
    }
    if (i < n) row_excl[i] = buf[threadIdx.x] - v;
    if (threadIdx.x == 1023) bsums[blockIdx.x] = buf[1023];
}

__global__ void scan_sums_kernel(int* __restrict__ bsums, int nb) {
    __shared__ int buf[128];
    int v = ((int)threadIdx.x < nb) ? bsums[threadIdx.x] : 0;
    buf[threadIdx.x] = v;
    __syncthreads();
    for (int off = 1; off < 128; off <<= 1) {
        int t = (threadIdx.x >= (unsigned)off) ? buf[threadIdx.x - off] : 0;
        __syncthreads();
        buf[threadIdx.x] += t;
        __syncthreads();
    }
    if ((int)threadIdx.x < nb) bsums[threadIdx.x] = buf[threadIdx.x] - v;
    if (threadIdx.x == 0) bsums[nb] = buf[127];
}

__global__ void scan_add_kernel(int* __restrict__ row_start, const int* __restrict__ bsums,
                                int n, int nb) {
    int i = blockIdx.x * blockDim.x + threadIdx.x;
    if (i < n) row_start[i] += bsums[i >> 10];
    else if (i == n) row_start[n] = bsums[nb];
}

// build each bucket's CSR segment in LDS, flush coalesced
__global__ __launch_bounds__(256) void csr_build_kernel(const uint2* __restrict__ staging,
                                                        const int* __restrict__ bkt_cursor,
                                                        const int* __restrict__ row_start,
                                                        int* __restrict__ csr_src, int n) {
    __shared__ int rs[257];
    __shared__ int cur[256];
    __shared__ int seg[BKT_CAP];
    const int b  = blockIdx.x;
    const int lo = b << BKT_SHIFT;
    const int nl = min(256, n - lo);
    if ((int)threadIdx.x <= nl) rs[threadIdx.x] = row_start[lo + threadIdx.x];
    cur[threadIdx.x] = 0;
    __syncthreads();
    const int sbase = rs[0];
    int cnt = min(bkt_cursor[b], BKT_CAP);
    for (int e = threadIdx.x; e < cnt; e += 256) {
        uint2 p = staging[(size_t)b * BKT_CAP + e];
        int ln = (int)p.y - lo;
        int q  = atomicAdd(&cur[ln], 1);
        seg[(rs[ln] - sbase) + q] = (int)p.x;
    }
    __syncthreads();
    for (int i = threadIdx.x; i < cnt; i += 256) csr_src[sbase + i] = seg[i];
}

// ----------------------------- dtype converts ------------------------------

// x fp32 -> bf16, 8 elems/thread
__global__ void cast_bf16_kernel(const float* __restrict__ in, ushort_t* __restrict__ out, int n8) {
    int i = blockIdx.x * blockDim.x + threadIdx.x;
    if (i >= n8) return;
    const float4 f0 = ((const float4*)in)[2 * i];
    const float4 f1 = ((const float4*)in)[2 * i + 1];
    uint4 o;
    o.x = (uint_t)f2bf(f0.x) | ((uint_t)f2bf(f0.y) << 16);
    o.y = (uint_t)f2bf(f0.z) | ((uint_t)f2bf(f0.w) << 16);
    o.z = (uint_t)f2bf(f1.x) | ((uint_t)f2bf(f1.y) << 16);
    o.w = (uint_t)f2bf(f1.z) | ((uint_t)f2bf(f1.w) << 16);
    ((uint4*)out)[i] = o;
}

// weight transposes (one kernel): Wt[n][k] bf16, zero-padded
__global__ void wt_all_kernel(const float* __restrict__ W1, const float* __restrict__ W2,
                              const float* __restrict__ W3,
                              ushort_t* __restrict__ Wt1, ushort_t* __restrict__ Wt2,
                              ushort_t* __restrict__ Wt3) {
    int idx = blockIdx.x * blockDim.x + threadIdx.x;
    if (idx < 32768) {
        int nn = idx >> 8, k = idx & 255;
        Wt1[idx] = f2bf(W1[(size_t)k * 128 + nn]);
    } else if (idx < 49152) {
        int j = idx - 32768;
        int nn = j >> 7, k = j & 127;
        float v = (nn < 100) ? W2[(size_t)k * 100 + nn] : 0.f;
        Wt2[j] = f2bf(v);
    } else if (idx < 57344) {
        int j = idx - 49152;
        int nn = j >> 7, k = j & 127;
        float v = (k < 100 && nn < 32) ? W3[(size_t)k * 32 + nn] : 0.f;
        Wt3[j] = f2bf(v);
    }
}

// --------------------------- tiled MFMA GEMM -------------------------------
// C[M x BN] (bf16) = dis[row] * (A[M x K] @ Wt[BN x K]^T), BN = NFR*32 = all N.
// BM=64, BK=64, 4 waves (2M x 2N): wave = 32 rows x NFR*16 cols
// (2 m-frags x NFR n-frags). LDS-staged A and B tiles (+8 pad). Swapped-operand
// MFMA: acc = mfma(bfr, af, acc) -> lane holds row rsel, cols q*4..+3 -> uint2.
template <int NFR>
__global__ __launch_bounds__(256) void gemm_tile(const ushort_t* __restrict__ A,
                                                 const ushort_t* __restrict__ Bt,
                                                 ushort_t* __restrict__ C,
                                                 const float* __restrict__ dis,
                                                 int M, int K, int lda, int ldb, int ldc) {
    constexpr int BN = NFR * 32;
    __shared__ __attribute__((aligned(16))) ushort_t As[64][72];   // +8 pad
    __shared__ __attribute__((aligned(16))) ushort_t Bs[BN][72];

    const int t    = threadIdx.x;
    const int lane = t & 63;
    const int w    = t >> 6;
    const int wm   = w >> 1, wn = w & 1;
    const int m0   = blockIdx.x * 64;
    const int rsel = lane & 15;
    const int q    = lane >> 4;

    f32x4 acc[2][NFR];
    #pragma unroll
    for (int mi = 0; mi < 2; ++mi)
        #pragma unroll
        for (int ni = 0; ni < NFR; ++ni) acc[mi][ni] = (f32x4){0.f, 0.f, 0.f, 0.f};

    const int srow = t >> 3;          // 0..31
    const int scol = (t & 7) * 8;     // 0..56

    for (int k0 = 0; k0 < K; k0 += 64) {
        #pragma unroll
        for (int it = 0; it < 2; ++it) {            // A tile 64x64
            int r = srow + it * 32;
            int gm = m0 + r;
            bf16x8 v = {0, 0, 0, 0, 0, 0, 0, 0};
            if (gm < M) v = *(const bf16x8*)(A + (size_t)gm * lda + k0 + scol);
            *(bf16x8*)&As[r][scol] = v;
        }
        #pragma unroll
        for (int it = 0; it < BN / 32; ++it) {      // B tile BNx64
            int r = srow + it * 32;
            bf16x8 v = *(const bf16x8*)(Bt + (size_t)r * ldb + k0 + scol);
            *(bf16x8*)&Bs[r][scol] = v;
        }
        __syncthreads();
        #pragma unroll
        for (int ks = 0; ks < 2; ++ks) {
            const int kc = ks * 32 + q * 8;
            bf16x8 af[2], bfr[NFR];
            #pragma unroll
            for (int mi = 0; mi < 2; ++mi)
                af[mi] = *(const bf16x8*)&As[wm * 32 + mi * 16 + rsel][kc];
            #pragma unroll
            for (int ni = 0; ni < NFR; ++ni)
                bfr[ni] = *(const bf16x8*)&Bs[wn * (BN / 2) + ni * 16 + rsel][kc];
            #pragma unroll
            for (int mi = 0; mi < 2; ++mi)
                #pragma unroll
                for (int ni = 0; ni < NFR; ++ni)
                    acc[mi][ni] = __builtin_amdgcn_mfma_f32_16x16x32_bf16(
                        bfr[ni], af[mi], acc[mi][ni], 0, 0, 0);
        }
        __syncthreads();
    }

    // swapped-operand C/D layout: row = rsel, cols = q*4 .. q*4+3 (uint2)
    #pragma unroll
    for (int mi = 0; mi < 2; ++mi) {
        const int gm = m0 + wm * 32 + mi * 16 + rsel;
        if (gm >= M) continue;
        const float d = dis[gm];
        #pragma unroll
        for (int ni = 0; ni < NFR; ++ni) {
            uint2 o;
            o.x = (uint_t)f2bf(acc[mi][ni][0] * d) | ((uint_t)f2bf(acc[mi][ni][1] * d) << 16);
            o.y = (uint_t)f2bf(acc[mi][ni][2] * d) | ((uint_t)f2bf(acc[mi][ni][3] * d) << 16);
            *(uint2*)(C + (size_t)gm * ldc + wn * (BN / 2) + ni * 16 + q * 4) = o;
        }
    }
}

// ---------------------------- aggregation ---------------------------------
// h rows pre-scaled (h' = dis*h). One wave per node. Quarter-split:
// lanes (l&15) cover features fb = (l&15)*8 (one uint4 = 8 bf16 = 16B),
// quarter q = l>>4 takes edge i+q; one VMEM gather = 4 rows x 256B/4 = 1KB.
template <int F>
__global__ void aggregate128_kernel(const ushort_t* __restrict__ h, const int* __restrict__ row_start,
                                    const int* __restrict__ csr_src,
                                    const float* __restrict__ dis, const float* __restrict__ bias,
                                    ushort_t* __restrict__ out, int n) {
    int wid  = threadIdx.x >> 6;
    int lane = threadIdx.x & 63;
    int node = blockIdx.x * 4 + wid;
    if (node >= n) return;
    const int q  = lane >> 4;
    const int fb = (lane & 15) * 8;
    float a[8];
    #pragma unroll
    for (int j = 0; j < 8; ++j) a[j] = 0.f;

    int i = row_start[node], end = row_start[node + 1];

#define ACC8(U)                                                     \
    do {                                                            \
        a[0] += bflo((U).x); a[1] += bfhi((U).x);                   \
        a[2] += bflo((U).y); a[3] += bfhi((U).y);                   \
        a[4] += bflo((U).z); a[5] += bfhi((U).z);                   \
        a[6] += bflo((U).w); a[7] += bfhi((U).w);                   \
    } while (0)

    #pragma unroll 2
    for (; i + 8 <= end; i += 8) {
        int sA = csr_src[i + q];
        int sB = csr_src[i + 4 + q];
        uint4 u = *(const uint4*)(h + (size_t)sA * 128 + fb);
        uint4 v = *(const uint4*)(h + (size_t)sB * 128 + fb);
        ACC8(u);
        ACC8(v);
    }
    int r = end - i;
    if (r > 0) {
        if (q < r) {
            int sA = csr_src[i + q];
            uint4 u = *(const uint4*)(h + (size_t)sA * 128 + fb);
            ACC8(u);
        }
        if (q + 4 < r) {
            int sB = csr_src[i + 4 + q];
            uint4 v = *(const uint4*)(h + (size_t)sB * 128 + fb);
            ACC8(v);
        }
    }
#undef ACC8

    // merge quarters: q0+=q1 (xor16), then +=q2/q3 (xor32)
    #pragma unroll
    for (int j = 0; j < 8; ++j) {
        a[j] += __shfl_xor(a[j], 16);
        a[j] += __shfl_xor(a[j], 32);
    }

    if (q == 0) {
        uint4 su = *(const uint4*)(h + (size_t)node * 128 + fb);   // self-loop
        a[0] += bflo(su.x); a[1] += bfhi(su.x);
        a[2] += bflo(su.y); a[3] += bfhi(su.y);
        a[4] += bflo(su.z); a[5] += bfhi(su.z);
        a[6] += bflo(su.w); a[7] += bfhi(su.w);
        float dn = dis[node];
        #pragma unroll
        for (int j = 0; j < 8; ++j) {
            float b = (fb + j < F) ? bias[fb + j] : 0.f;
            float v = a[j] * dn + b;
            v = (v > 0.f) ? v : 0.1f * v;
            if (fb + j >= F) v = 0.f;          // keep K-padding exactly zero
            a[j] = v;
        }
        uint4 o;
        o.x = (uint_t)f2bf(a[0]) | ((uint_t)f2bf(a[1]) << 16);
        o.y = (uint_t)f2bf(a[2]) | ((uint_t)f2bf(a[3]) << 16);
        o.z = (uint_t)f2bf(a[4]) | ((uint_t)f2bf(a[5]) << 16);
        o.w = (uint_t)f2bf(a[6]) | ((uint_t)f2bf(a[7]) << 16);
        *(uint4*)(out + (size_t)node * 128 + fb) = o;
    }
}

// F=32, h pre-scaled: 16-lane group per node (2 features/lane), 4 nodes/wave
__global__ void aggregate32_kernel(const ushort_t* __restrict__ h, const int* __restrict__ row_start,
                                   const int* __restrict__ csr_src,
                                   const float* __restrict__ dis, const float* __restrict__ bias,
                                   ushort_t* __restrict__ out, int n) {
    int lane16 = threadIdx.x & 15;
    int node = blockIdx.x * (blockDim.x >> 4) + (threadIdx.x >> 4);
    if (node >= n) return;
    const int f0 = 2 * lane16;
    uint_t v = *(const uint_t*)(h + (size_t)node * 32 + f0);
    float acc0 = bflo(v);               // self-loop (pre-scaled)
    float acc1 = bfhi(v);
    int i = row_start[node], end = row_start[node + 1];
    for (; i + 4 <= end; i += 4) {
        int s0 = csr_src[i], s1 = csr_src[i + 1], s2 = csr_src[i + 2], s3 = csr_src[i + 3];
        uint_t u0 = *(const uint_t*)(h + (size_t)s0 * 32 + f0);
        uint_t u1 = *(const uint_t*)(h + (size_t)s1 * 32 + f0);
        uint_t u2 = *(const uint_t*)(h + (size_t)s2 * 32 + f0);
        uint_t u3 = *(const uint_t*)(h + (size_t)s3 * 32 + f0);
        acc0 += bflo(u0) + bflo(u1) + bflo(u2) + bflo(u3);
        acc1 += bfhi(u0) + bfhi(u1) + bfhi(u2) + bfhi(u3);
    }
    for (; i < end; ++i) {
        int s = csr_src[i];
        uint_t u = *(const uint_t*)(h + (size_t)s * 32 + f0);
        acc0 += bflo(u); acc1 += bfhi(u);
    }
    float dn = dis[node];
    acc0 = acc0 * dn + bias[f0];
    acc1 = acc1 * dn + bias[f0 + 1];
    acc0 = (acc0 > 0.f) ? acc0 : 0.1f * acc0;
    acc1 = (acc1 > 0.f) ? acc1 : 0.1f * acc1;
    uint_t o = (uint_t)f2bf(acc0) | ((uint_t)f2bf(acc1) << 16);
    *(uint_t*)(out + (size_t)node * 32 + f0) = o;
}

// layer 4 GEMM: [N x 32] bf16 @ [32 x 2] fp32 -> fp32, pre-scaled by dis[node]
__global__ void gemm32x2_kernel(const ushort_t* __restrict__ H, const float* __restrict__ W4,
                                const float* __restrict__ dis, float* __restrict__ C, int n) {
    int node = blockIdx.x * blockDim.x + threadIdx.x;
    if (node >= n) return;
    const uint_t* row = (const uint_t*)(H + (size_t)node * 32);
    float a0 = 0.f, a1 = 0.f;
    #pragma unroll
    for (int k2 = 0; k2 < 16; ++k2) {
        uint_t u = row[k2];
        float x0 = bflo(u), x1 = bfhi(u);
        int k = 2 * k2;
        a0 += x0 * W4[k * 2]     + x1 * W4[(k + 1) * 2];
        a1 += x0 * W4[k * 2 + 1] + x1 * W4[(k + 1) * 2 + 1];
    }
    float d = dis[node];
    C[2 * (size_t)node]     = a0 * d;
    C[2 * (size_t)node + 1] = a1 * d;
}

// final aggregation (F=2, h pre-scaled) + bias + softmax, one thread per node
__global__ void aggregate2_softmax_kernel(const float* __restrict__ h, const int* __restrict__ row_start,
                                          const int* __restrict__ csr_src,
                                          const float* __restrict__ dis, const float* __restrict__ bias,
                                          float* __restrict__ out, int n) {
    int node = blockIdx.x * blockDim.x + threadIdx.x;
    if (node >= n) return;
    float a0 = h[2 * (size_t)node];
    float a1 = h[2 * (size_t)node + 1];
    int beg = row_start[node], end = row_start[node + 1];
    for (int i = beg; i < end; ++i) {
        int s = csr_src[i];
        a0 += h[2 * (size_t)s];
        a1 += h[2 * (size_t)s + 1];
    }
    float dn = dis[node];
    a0 = a0 * dn + bias[0];
    a1 = a1 * dn + bias[1];
    float m  = fmaxf(a0, a1);
    float e0 = expf(a0 - m), e1 = expf(a1 - m);
    float inv = 1.f / (e0 + e1);
    out[2 * (size_t)node]     = e0 * inv;
    out[2 * (size_t)node + 1] = e1 * inv;
}

// ---------------------------------------------------------------------------

extern "C" void kernel_launch(void* const* d_in, const int* in_sizes, int n_in,
                              void* d_out, int out_size, void* d_ws, size_t ws_size,
                              hipStream_t stream) {
    const float* x  = (const float*)d_in[0];
    const int*   ei = (const int*)d_in[1];
    const float* W1 = (const float*)d_in[2];
    const float* b1 = (const float*)d_in[3];
    const float* W2 = (const float*)d_in[4];
    const float* b2 = (const float*)d_in[5];
    const float* W3 = (const float*)d_in[6];
    const float* b3 = (const float*)d_in[7];
    const float* W4 = (const float*)d_in[8];
    const float* b4 = (const float*)d_in[9];

    const int N = in_sizes[0] / 256;
    const int E = in_sizes[1] / 2;
    const int* srcA = ei;
    const int* dstA = ei + E;
    const int nbkt = (N + 255) >> BKT_SHIFT;

    char* ws = (char*)d_ws;
    size_t off = 0;
    auto alloc = [&](size_t bytes) {
        void* p = ws + off;
        off = (off + bytes + 255) & ~(size_t)255;
        return p;
    };
    int*      degi       = (int*)alloc((size_t)N * 4);
    float*    dis        = (float*)alloc((size_t)N * 4);
    int*      row_start  = (int*)alloc((size_t)(N + 1) * 4);
    int*      bsums      = (int*)alloc(512 * 4);
    int*      bkt_cursor = (int*)alloc((size_t)nbkt * 4);
    int*      csr_src    = (int*)alloc((size_t)E * 4);
    uint2*    staging    = (uint2*)alloc((size_t)nbkt * BKT_CAP * 8);
    ushort_t* xb         = (ushort_t*)alloc((size_t)N * 256 * 2);
    ushort_t* bufA       = (ushort_t*)alloc((size_t)N * 128 * 2);
    ushort_t* bufB       = (ushort_t*)alloc((size_t)N * 128 * 2);
    float*    C4         = (float*)alloc((size_t)N * 2 * 4);
    ushort_t* Wt1        = (ushort_t*)alloc((size_t)128 * 256 * 2);
    ushort_t* Wt2        = (ushort_t*)alloc((size_t)128 * 128 * 2);
    ushort_t* Wt3        = (ushort_t*)alloc((size_t)64 * 128 * 2);
    (void)ws_size;

    hipMemsetAsync(bkt_cursor, 0, (size_t)nbkt * 4, stream);

    // graph prep (bucketed)
    bin_kernel<<<(E + BIN_CHUNK - 1) / BIN_CHUNK, 256, 0, stream>>>(
        srcA, dstA, bkt_cursor, staging, E, nbkt);
    deg_from_staging_kernel<<<nbkt, 256, 0, stream>>>(staging, bkt_cursor, degi, dis, N);
    const int nb = (N + 1023) >> 10;
    scan_block_kernel<<<nb, 1024, 0, stream>>>(degi, row_start, bsums, N);
    scan_sums_kernel<<<1, 128, 0, stream>>>(bsums, nb);
    scan_add_kernel<<<(N + 256) / 256, 256, 0, stream>>>(row_start, bsums, N, nb);
    csr_build_kernel<<<nbkt, 256, 0, stream>>>(staging, bkt_cursor, row_start, csr_src, N);

    // weight transposes + x cast (bf16)
    wt_all_kernel<<<(57344 + 255) / 256, 256, 0, stream>>>(W1, W2, W3, Wt1, Wt2, Wt3);
    const int n8 = N * 32;   // N*256/8
    cast_bf16_kernel<<<(n8 + 255) / 256, 256, 0, stream>>>(x, xb, n8);

    const int gx = (N + 63) / 64;            // 64 rows per block
    const int aggBlocks128 = (N + 3) / 4;    // 4 waves/block, 1 node/wave
    const int aggBlocks32  = (N + 15) / 16;  // 16 nodes/block

    // layer 1: 256 -> 128, single N pass (BN=128)
    gemm_tile<4><<<gx, 256, 0, stream>>>(xb, Wt1, bufA, dis, N, 256, 256, 256, 128);
    aggregate128_kernel<128><<<aggBlocks128, 256, 0, stream>>>(
        bufA, row_start, csr_src, dis, b1, bufB, N);
    // layer 2: 128 -> 100 (padded to 128)
    gemm_tile<4><<<gx, 256, 0, stream>>>(bufB, Wt2, bufA, dis, N, 128, 128, 128, 128);
    aggregate128_kernel<100><<<aggBlocks128, 256, 0, stream>>>(
        bufA, row_start, csr_src, dis, b2, bufB, N);
    // layer 3: 128(pad) -> 32 (BN=32)
    gemm_tile<1><<<gx, 256, 0, stream>>>(bufB, Wt3, bufA, dis, N, 128, 128, 128, 32);
    aggregate32_kernel<<<aggBlocks32, 256, 0, stream>>>(
        bufA, row_start, csr_src, dis, b3, bufB, N);
    // layer 4: 32 -> 2, aggregate + softmax
    gemm32x2_kernel<<<(N + 255) / 256, 256, 0, stream>>>(bufB, W4, dis, C4, N);
    aggregate2_softmax_kernel<<<(N + 255) / 256, 256, 0, stream>>>(
        C4, row_start, csr_src, dis, b4, (float*)d_out, N);
}

// Round 11
// 299.864 us; speedup vs baseline: 1.2268x; 1.0585x over previous
//
#include <hip/hip_runtime.h>
#include <math.h>

// ---------------------------------------------------------------------------
// GCN: cast x->bf16 once; 4x (bf16-MFMA tiled GEMM (BM=64,BN=full,BK=64,
//      4 waves 2Mx2N, LDS-staged, epilogue pre-scales rows by dis) ->
//      pure-sum aggregation (+bias, lrelu)) -> softmax.
// Graph prep per call (fused, bucketed):
//   bin edges by dst>>8 -> single-block scan of bucket totals ->
//   csr_build2: per-bucket {LDS histogram -> LDS scan -> row_start/dis write
//   -> LDS scatter -> coalesced csr flush}.
// out[n] = dis[n]*( sum_e h'[s] + h'[n] ) + b,  h'[r] = dis[r]*(h@W)[r]
// Aggregation: quarter-split uint4 gathers, 32-bit saddr offsets.
// ---------------------------------------------------------------------------

typedef unsigned short ushort_t;
typedef unsigned int   uint_t;
typedef short  bf16x8 __attribute__((ext_vector_type(8)));
typedef float  f32x4  __attribute__((ext_vector_type(4)));

#define BKT_SHIFT 8               // 256 nodes per bucket
#define BKT_CAP   5120            // >= max edges per bucket (mean 4096, +16 sigma)
#define BIN_CHUNK 4096            // edges per bin workgroup

__device__ __forceinline__ ushort_t f2bf(float f) {
    union { float f; uint_t u; } v; v.f = f;
    uint_t u = v.u;
    u += 0x7fffu + ((u >> 16) & 1u);      // round-to-nearest-even
    return (ushort_t)(u >> 16);
}
__device__ __forceinline__ float bflo(uint_t u) {
    union { uint_t q; float f; } v; v.q = u << 16; return v.f;
}
__device__ __forceinline__ float bfhi(uint_t u) {
    union { uint_t q; float f; } v; v.q = u & 0xffff0000u; return v.f;
}

// ------------------------------- graph prep -------------------------------

__global__ __launch_bounds__(256) void bin_kernel(const int* __restrict__ srcArr,
                                                  const int* __restrict__ dstArr,
                                                  int* __restrict__ bkt_cursor,
                                                  uint2* __restrict__ staging,
                                                  int E, int nb) {
    __shared__ int hist[512];
    __shared__ int base[512];
    for (int b = threadIdx.x; b < 512; b += 256) hist[b] = 0;
    __syncthreads();
    const int e0 = blockIdx.x * BIN_CHUNK;
    #pragma unroll 4
    for (int k = 0; k < BIN_CHUNK / 256; ++k) {
        int e = e0 + k * 256 + threadIdx.x;
        if (e < E) atomicAdd(&hist[dstArr[e] >> BKT_SHIFT], 1);
    }
    __syncthreads();
    for (int b = threadIdx.x; b < nb; b += 256) {
        int h = hist[b];
        base[b] = h ? atomicAdd(&bkt_cursor[b], h) : 0;
    }
    __syncthreads();
    for (int b = threadIdx.x; b < 512; b += 256) hist[b] = 0;  // reuse as cursor
    __syncthreads();
    #pragma unroll 4
    for (int k = 0; k < BIN_CHUNK / 256; ++k) {
        int e = e0 + k * 256 + threadIdx.x;
        if (e < E) {
            int s = srcArr[e], d = dstArr[e];
            int b = d >> BKT_SHIFT;
            int p = atomicAdd(&hist[b], 1);
            int idx = base[b] + p;
            if (idx < BKT_CAP)
                staging[(size_t)b * BKT_CAP + idx] = make_uint2((uint_t)s, (uint_t)d);
        }
    }
}

// single block: exclusive scan of bucket totals -> bkt_base; row_start[n]=E
__global__ __launch_bounds__(512) void bucket_scan_kernel(const int* __restrict__ bkt_cursor,
                                                          int* __restrict__ bkt_base,
                                                          int* __restrict__ row_start,
                                                          int nbkt, int n) {
    __shared__ int buf[512];
    int v = ((int)threadIdx.x < nbkt) ? min(bkt_cursor[threadIdx.x], BKT_CAP) : 0;
    buf[threadIdx.x] = v;
    __syncthreads();
    for (int off = 1; off < 512; off <<= 1) {
        int t = (threadIdx.x >= (unsigned)off) ? buf[threadIdx.x - off] : 0;
        __syncthreads();
        buf[threadIdx.x] += t;
        __syncthreads();
    }
    if ((int)threadIdx.x < nbkt) bkt_base[threadIdx.x] = buf[threadIdx.x] - v;
    if ((int)threadIdx.x == nbkt - 1) row_start[n] = buf[threadIdx.x];
}

// fused: per-bucket degree histogram -> LDS scan -> row_start & dis writes ->
// LDS scatter -> coalesced csr flush
__global__ __launch_bounds__(256) void csr_build2_kernel(const uint2* __restrict__ staging,
                                                         const int* __restrict__ bkt_cursor,
                                                         const int* __restrict__ bkt_base,
                                                         int* __restrict__ row_start,
                                                         float* __restrict__ dis,
                                                         int* __restrict__ csr_src, int n) {
    __shared__ int cnt[256];
    __shared__ int buf[256];
    __shared__ int rsS[256];
    __shared__ int seg[BKT_CAP];
    const int t  = threadIdx.x;
    const int b  = blockIdx.x;
    const int lo = b << BKT_SHIFT;
    const int nl = min(256, n - lo);
    cnt[t] = 0;
    __syncthreads();
    const int cntE = min(bkt_cursor[b], BKT_CAP);
    for (int e = t; e < cntE; e += 256) {
        uint2 p = staging[(size_t)b * BKT_CAP + e];
        atomicAdd(&cnt[(int)p.y - lo], 1);
    }
    __syncthreads();
    const int v = cnt[t];
    buf[t] = v;
    __syncthreads();
    for (int off = 1; off < 256; off <<= 1) {
        int tt = (t >= off) ? buf[t - off] : 0;
        __syncthreads();
        buf[t] += tt;
        __syncthreads();
    }
    rsS[t] = buf[t] - v;                      // exclusive within-bucket
    const int sbase = bkt_base[b];
    if (t < nl) {
        row_start[lo + t] = sbase + (buf[t] - v);
        dis[lo + t] = rsqrtf((float)(v + 1));
    }
    cnt[t] = 0;                               // reuse as scatter cursor
    __syncthreads();
    for (int e = t; e < cntE; e += 256) {
        uint2 p = staging[(size_t)b * BKT_CAP + e];
        int ln = (int)p.y - lo;
        int q  = atomicAdd(&cnt[ln], 1);
        seg[rsS[ln] + q] = (int)p.x;
    }
    __syncthreads();
    for (int i = t; i < cntE; i += 256) csr_src[sbase + i] = seg[i];
}

// ----------------------------- dtype converts ------------------------------

// x fp32 -> bf16, 8 elems/thread
__global__ void cast_bf16_kernel(const float* __restrict__ in, ushort_t* __restrict__ out, int n8) {
    int i = blockIdx.x * blockDim.x + threadIdx.x;
    if (i >= n8) return;
    const float4 f0 = ((const float4*)in)[2 * i];
    const float4 f1 = ((const float4*)in)[2 * i + 1];
    uint4 o;
    o.x = (uint_t)f2bf(f0.x) | ((uint_t)f2bf(f0.y) << 16);
    o.y = (uint_t)f2bf(f0.z) | ((uint_t)f2bf(f0.w) << 16);
    o.z = (uint_t)f2bf(f1.x) | ((uint_t)f2bf(f1.y) << 16);
    o.w = (uint_t)f2bf(f1.z) | ((uint_t)f2bf(f1.w) << 16);
    ((uint4*)out)[i] = o;
}

// weight transposes (one kernel): Wt[n][k] bf16, zero-padded
__global__ void wt_all_kernel(const float* __restrict__ W1, const float* __restrict__ W2,
                              const float* __restrict__ W3,
                              ushort_t* __restrict__ Wt1, ushort_t* __restrict__ Wt2,
                              ushort_t* __restrict__ Wt3) {
    int idx = blockIdx.x * blockDim.x + threadIdx.x;
    if (idx < 32768) {
        int nn = idx >> 8, k = idx & 255;
        Wt1[idx] = f2bf(W1[(size_t)k * 128 + nn]);
    } else if (idx < 49152) {
        int j = idx - 32768;
        int nn = j >> 7, k = j & 127;
        float v = (nn < 100) ? W2[(size_t)k * 100 + nn] : 0.f;
        Wt2[j] = f2bf(v);
    } else if (idx < 57344) {
        int j = idx - 49152;
        int nn = j >> 7, k = j & 127;
        float v = (k < 100 && nn < 32) ? W3[(size_t)k * 32 + nn] : 0.f;
        Wt3[j] = f2bf(v);
    }
}

// --------------------------- tiled MFMA GEMM -------------------------------
// C[M x BN] (bf16) = dis[row] * (A[M x K] @ Wt[BN x K]^T), BN = NFR*32 = all N.
// BM=64, BK=64, 4 waves (2M x 2N). LDS-staged A and B tiles (+8 pad).
// Swapped-operand MFMA -> lane holds row rsel, cols q*4..+3 -> uint2 stores.
template <int NFR>
__global__ __launch_bounds__(256) void gemm_tile(const ushort_t* __restrict__ A,
                                                 const ushort_t* __restrict__ Bt,
                                                 ushort_t* __restrict__ C,
                                                 const float* __restrict__ dis,
                                                 int M, int K, int lda, int ldb, int ldc) {
    constexpr int BN = NFR * 32;
    __shared__ __attribute__((aligned(16))) ushort_t As[64][72];   // +8 pad
    __shared__ __attribute__((aligned(16))) ushort_t Bs[BN][72];

    const int t    = threadIdx.x;
    const int lane = t & 63;
    const int w    = t >> 6;
    const int wm   = w >> 1, wn = w & 1;
    const int m0   = blockIdx.x * 64;
    const int rsel = lane & 15;
    const int q    = lane >> 4;

    f32x4 acc[2][NFR];
    #pragma unroll
    for (int mi = 0; mi < 2; ++mi)
        #pragma unroll
        for (int ni = 0; ni < NFR; ++ni) acc[mi][ni] = (f32x4){0.f, 0.f, 0.f, 0.f};

    const int srow = t >> 3;          // 0..31
    const int scol = (t & 7) * 8;     // 0..56

    for (int k0 = 0; k0 < K; k0 += 64) {
        #pragma unroll
        for (int it = 0; it < 2; ++it) {            // A tile 64x64
            int r = srow + it * 32;
            int gm = m0 + r;
            bf16x8 v = {0, 0, 0, 0, 0, 0, 0, 0};
            if (gm < M) v = *(const bf16x8*)(A + (size_t)gm * lda + k0 + scol);
            *(bf16x8*)&As[r][scol] = v;
        }
        #pragma unroll
        for (int it = 0; it < BN / 32; ++it) {      // B tile BNx64
            int r = srow + it * 32;
            bf16x8 v = *(const bf16x8*)(Bt + (size_t)r * ldb + k0 + scol);
            *(bf16x8*)&Bs[r][scol] = v;
        }
        __syncthreads();
        #pragma unroll
        for (int ks = 0; ks < 2; ++ks) {
            const int kc = ks * 32 + q * 8;
            bf16x8 af[2], bfr[NFR];
            #pragma unroll
            for (int mi = 0; mi < 2; ++mi)
                af[mi] = *(const bf16x8*)&As[wm * 32 + mi * 16 + rsel][kc];
            #pragma unroll
            for (int ni = 0; ni < NFR; ++ni)
                bfr[ni] = *(const bf16x8*)&Bs[wn * (BN / 2) + ni * 16 + rsel][kc];
            #pragma unroll
            for (int mi = 0; mi < 2; ++mi)
                #pragma unroll
                for (int ni = 0; ni < NFR; ++ni)
                    acc[mi][ni] = __builtin_amdgcn_mfma_f32_16x16x32_bf16(
                        bfr[ni], af[mi], acc[mi][ni], 0, 0, 0);
        }
        __syncthreads();
    }

    // swapped-operand C/D layout: row = rsel, cols = q*4 .. q*4+3 (uint2)
    #pragma unroll
    for (int mi = 0; mi < 2; ++mi) {
        const int gm = m0 + wm * 32 + mi * 16 + rsel;
        if (gm >= M) continue;
        const float d = dis[gm];
        #pragma unroll
        for (int ni = 0; ni < NFR; ++ni) {
            uint2 o;
            o.x = (uint_t)f2bf(acc[mi][ni][0] * d) | ((uint_t)f2bf(acc[mi][ni][1] * d) << 16);
            o.y = (uint_t)f2bf(acc[mi][ni][2] * d) | ((uint_t)f2bf(acc[mi][ni][3] * d) << 16);
            *(uint2*)(C + (size_t)gm * ldc + wn * (BN / 2) + ni * 16 + q * 4) = o;
        }
    }
}

// ---------------------------- aggregation ---------------------------------
// h rows pre-scaled (h' = dis*h). One wave per node. Quarter-split:
// lanes (l&15) cover bytes fbb = (l&15)*16 of the 256B row (uint4 = 8 bf16),
// quarter q = l>>4 takes edge i+q. 32-bit saddr offsets: base h + (s<<8)+fbb.
template <int F>
__global__ void aggregate128_kernel(const ushort_t* __restrict__ h, const int* __restrict__ row_start,
                                    const int* __restrict__ csr_src,
                                    const float* __restrict__ dis, const float* __restrict__ bias,
                                    ushort_t* __restrict__ out, int n) {
    int wid  = threadIdx.x >> 6;
    int lane = threadIdx.x & 63;
    int node = blockIdx.x * 4 + wid;
    if (node >= n) return;
    const int q    = lane >> 4;
    const uint_t fbb = (uint_t)(lane & 15) << 4;   // byte offset within row
    const char* hb = (const char*)h;
    float a[8];
    #pragma unroll
    for (int j = 0; j < 8; ++j) a[j] = 0.f;

    int i = row_start[node], end = row_start[node + 1];

#define LOADR(S) (*(const uint4*)(hb + (((uint_t)(S) << 8) + fbb)))
#define ACC8(U)                                                     \
    do {                                                            \
        a[0] += bflo((U).x); a[1] += bfhi((U).x);                   \
        a[2] += bflo((U).y); a[3] += bfhi((U).y);                   \
        a[4] += bflo((U).z); a[5] += bfhi((U).z);                   \
        a[6] += bflo((U).w); a[7] += bfhi((U).w);                   \
    } while (0)

    #pragma unroll 2
    for (; i + 8 <= end; i += 8) {
        int sA = csr_src[i + q];
        int sB = csr_src[i + 4 + q];
        uint4 u = LOADR(sA);
        uint4 v = LOADR(sB);
        ACC8(u);
        ACC8(v);
    }
    int r = end - i;
    if (r > 0) {
        if (q < r) {
            uint4 u = LOADR(csr_src[i + q]);
            ACC8(u);
        }
        if (q + 4 < r) {
            uint4 v = LOADR(csr_src[i + 4 + q]);
            ACC8(v);
        }
    }

    // merge quarters: q0+=q1 (xor16), then +=q2/q3 (xor32)
    #pragma unroll
    for (int j = 0; j < 8; ++j) {
        a[j] += __shfl_xor(a[j], 16);
        a[j] += __shfl_xor(a[j], 32);
    }

    if (q == 0) {
        uint4 su = LOADR(node);                   // self-loop (pre-scaled)
        ACC8(su);
        float dn = dis[node];
        const int fb = (lane & 15) * 8;
        #pragma unroll
        for (int j = 0; j < 8; ++j) {
            float b = (fb + j < F) ? bias[fb + j] : 0.f;
            float v = a[j] * dn + b;
            v = (v > 0.f) ? v : 0.1f * v;
            if (fb + j >= F) v = 0.f;          // keep K-padding exactly zero
            a[j] = v;
        }
        uint4 o;
        o.x = (uint_t)f2bf(a[0]) | ((uint_t)f2bf(a[1]) << 16);
        o.y = (uint_t)f2bf(a[2]) | ((uint_t)f2bf(a[3]) << 16);
        o.z = (uint_t)f2bf(a[4]) | ((uint_t)f2bf(a[5]) << 16);
        o.w = (uint_t)f2bf(a[6]) | ((uint_t)f2bf(a[7]) << 16);
        *(uint4*)((char*)out + (((uint_t)node << 8) + fbb)) = o;
    }
#undef ACC8
#undef LOADR
}

// F=32, h pre-scaled: 16-lane group per node (2 features/lane), 4 nodes/wave
__global__ void aggregate32_kernel(const ushort_t* __restrict__ h, const int* __restrict__ row_start,
                                   const int* __restrict__ csr_src,
                                   const float* __restrict__ dis, const float* __restrict__ bias,
                                   ushort_t* __restrict__ out, int n) {
    int lane16 = threadIdx.x & 15;
    int node = blockIdx.x * (blockDim.x >> 4) + (threadIdx.x >> 4);
    if (node >= n) return;
    const uint_t fbb = (uint_t)lane16 << 2;        // byte offset within 64B row
    const char* hb = (const char*)h;
#define LOADR32(S) (*(const uint_t*)(hb + (((uint_t)(S) << 6) + fbb)))
    uint_t v = LOADR32(node);
    float acc0 = bflo(v);               // self-loop (pre-scaled)
    float acc1 = bfhi(v);
    int i = row_start[node], end = row_start[node + 1];
    for (; i + 4 <= end; i += 4) {
        uint_t u0 = LOADR32(csr_src[i]);
        uint_t u1 = LOADR32(csr_src[i + 1]);
        uint_t u2 = LOADR32(csr_src[i + 2]);
        uint_t u3 = LOADR32(csr_src[i + 3]);
        acc0 += bflo(u0) + bflo(u1) + bflo(u2) + bflo(u3);
        acc1 += bfhi(u0) + bfhi(u1) + bfhi(u2) + bfhi(u3);
    }
    for (; i < end; ++i) {
        uint_t u = LOADR32(csr_src[i]);
        acc0 += bflo(u); acc1 += bfhi(u);
    }
#undef LOADR32
    float dn = dis[node];
    const int f0 = 2 * lane16;
    acc0 = acc0 * dn + bias[f0];
    acc1 = acc1 * dn + bias[f0 + 1];
    acc0 = (acc0 > 0.f) ? acc0 : 0.1f * acc0;
    acc1 = (acc1 > 0.f) ? acc1 : 0.1f * acc1;
    uint_t o = (uint_t)f2bf(acc0) | ((uint_t)f2bf(acc1) << 16);
    *(uint_t*)((char*)out + (((uint_t)node << 6) + fbb)) = o;
}

// layer 4 GEMM: [N x 32] bf16 @ [32 x 2] fp32 -> fp32, pre-scaled by dis[node]
__global__ void gemm32x2_kernel(const ushort_t* __restrict__ H, const float* __restrict__ W4,
                                const float* __restrict__ dis, float* __restrict__ C, int n) {
    int node = blockIdx.x * blockDim.x + threadIdx.x;
    if (node >= n) return;
    const uint_t* row = (const uint_t*)(H + (size_t)node * 32);
    float a0 = 0.f, a1 = 0.f;
    #pragma unroll
    for (int k2 = 0; k2 < 16; ++k2) {
        uint_t u = row[k2];
        float x0 = bflo(u), x1 = bfhi(u);
        int k = 2 * k2;
        a0 += x0 * W4[k * 2]     + x1 * W4[(k + 1) * 2];
        a1 += x0 * W4[k * 2 + 1] + x1 * W4[(k + 1) * 2 + 1];
    }
    float d = dis[node];
    C[2 * (size_t)node]     = a0 * d;
    C[2 * (size_t)node + 1] = a1 * d;
}

// final aggregation (F=2, h pre-scaled) + bias + softmax, one thread per node
__global__ void aggregate2_softmax_kernel(const float* __restrict__ h, const int* __restrict__ row_start,
                                          const int* __restrict__ csr_src,
                                          const float* __restrict__ dis, const float* __restrict__ bias,
                                          float* __restrict__ out, int n) {
    int node = blockIdx.x * blockDim.x + threadIdx.x;
    if (node >= n) return;
    const char* hb = (const char*)h;
    float a0 = h[2 * (size_t)node];
    float a1 = h[2 * (size_t)node + 1];
    int beg = row_start[node], end = row_start[node + 1];
    for (int i = beg; i < end; ++i) {
        uint_t off = (uint_t)csr_src[i] << 3;
        float2 u = *(const float2*)(hb + off);
        a0 += u.x;
        a1 += u.y;
    }
    float dn = dis[node];
    a0 = a0 * dn + bias[0];
    a1 = a1 * dn + bias[1];
    float m  = fmaxf(a0, a1);
    float e0 = expf(a0 - m), e1 = expf(a1 - m);
    float inv = 1.f / (e0 + e1);
    out[2 * (size_t)node]     = e0 * inv;
    out[2 * (size_t)node + 1] = e1 * inv;
}

// ---------------------------------------------------------------------------

extern "C" void kernel_launch(void* const* d_in, const int* in_sizes, int n_in,
                              void* d_out, int out_size, void* d_ws, size_t ws_size,
                              hipStream_t stream) {
    const float* x  = (const float*)d_in[0];
    const int*   ei = (const int*)d_in[1];
    const float* W1 = (const float*)d_in[2];
    const float* b1 = (const float*)d_in[3];
    const float* W2 = (const float*)d_in[4];
    const float* b2 = (const float*)d_in[5];
    const float* W3 = (const float*)d_in[6];
    const float* b3 = (const float*)d_in[7];
    const float* W4 = (const float*)d_in[8];
    const float* b4 = (const float*)d_in[9];

    const int N = in_sizes[0] / 256;
    const int E = in_sizes[1] / 2;
    const int* srcA = ei;
    const int* dstA = ei + E;
    const int nbkt = (N + 255) >> BKT_SHIFT;

    char* ws = (char*)d_ws;
    size_t off = 0;
    auto alloc = [&](size_t bytes) {
        void* p = ws + off;
        off = (off + bytes + 255) & ~(size_t)255;
        return p;
    };
    float*    dis        = (float*)alloc((size_t)N * 4);
    int*      row_start  = (int*)alloc((size_t)(N + 1) * 4);
    int*      bkt_cursor = (int*)alloc(512 * 4);
    int*      bkt_base   = (int*)alloc(512 * 4);
    int*      csr_src    = (int*)alloc((size_t)E * 4);
    uint2*    staging    = (uint2*)alloc((size_t)nbkt * BKT_CAP * 8);
    ushort_t* xb         = (ushort_t*)alloc((size_t)N * 256 * 2);
    ushort_t* bufA       = (ushort_t*)alloc((size_t)N * 128 * 2);
    ushort_t* bufB       = (ushort_t*)alloc((size_t)N * 128 * 2);
    float*    C4         = (float*)alloc((size_t)N * 2 * 4);
    ushort_t* Wt1        = (ushort_t*)alloc((size_t)128 * 256 * 2);
    ushort_t* Wt2        = (ushort_t*)alloc((size_t)128 * 128 * 2);
    ushort_t* Wt3        = (ushort_t*)alloc((size_t)64 * 128 * 2);
    (void)ws_size;

    hipMemsetAsync(bkt_cursor, 0, 512 * 4, stream);

    // graph prep (bucketed, fused)
    bin_kernel<<<(E + BIN_CHUNK - 1) / BIN_CHUNK, 256, 0, stream>>>(
        srcA, dstA, bkt_cursor, staging, E, nbkt);
    bucket_scan_kernel<<<1, 512, 0, stream>>>(bkt_cursor, bkt_base, row_start, nbkt, N);
    csr_build2_kernel<<<nbkt, 256, 0, stream>>>(staging, bkt_cursor, bkt_base,
                                                row_start, dis, csr_src, N);

    // weight transposes + x cast (bf16)
    wt_all_kernel<<<(57344 + 255) / 256, 256, 0, stream>>>(W1, W2, W3, Wt1, Wt2, Wt3);
    const int n8 = N * 32;   // N*256/8
    cast_bf16_kernel<<<(n8 + 255) / 256, 256, 0, stream>>>(x, xb, n8);

    const int gx = (N + 63) / 64;            // 64 rows per block
    const int aggBlocks128 = (N + 3) / 4;    // 4 waves/block, 1 node/wave
    const int aggBlocks32  = (N + 15) / 16;  // 16 nodes/block

    // layer 1: 256 -> 128, single N pass (BN=128)
    gemm_tile<4><<<gx, 256, 0, stream>>>(xb, Wt1, bufA, dis, N, 256, 256, 256, 128);
    aggregate128_kernel<128><<<aggBlocks128, 256, 0, stream>>>(
        bufA, row_start, csr_src, dis, b1, bufB, N);
    // layer 2: 128 -> 100 (padded to 128)
    gemm_tile<4><<<gx, 256, 0, stream>>>(bufB, Wt2, bufA, dis, N, 128, 128, 128, 128);
    aggregate128_kernel<100><<<aggBlocks128, 256, 0, stream>>>(
        bufA, row_start, csr_src, dis, b2, bufB, N);
    // layer 3: 128(pad) -> 32 (BN=32)
    gemm_tile<1><<<gx, 256, 0, stream>>>(bufB, Wt3, bufA, dis, N, 128, 128, 128, 32);
    aggregate32_kernel<<<aggBlocks32, 256, 0, stream>>>(
        bufA, row_start, csr_src, dis, b3, bufB, N);
    // layer 4: 32 -> 2, aggregate + softmax
    gemm32x2_kernel<<<(N + 255) / 256, 256, 0, stream>>>(bufB, W4, dis, C4, N);
    aggregate2_softmax_kernel<<<(N + 255) / 256, 256, 0, stream>>>(
        C4, row_start, csr_src, dis, b4, (float*)d_out, N);
}

// Round 12
// 299.348 us; speedup vs baseline: 1.2289x; 1.0017x over previous
//
#include <hip/hip_runtime.h>
#include <math.h>

// ---------------------------------------------------------------------------
// GCN: cast x->bf16 once; 4x (bf16-MFMA tiled GEMM (BM=64,BN=full,BK=64,
//      4 waves 2Mx2N, LDS-staged, epilogue pre-scales rows by dis) ->
//      pure-sum aggregation (+bias, lrelu)) -> softmax.
// Graph prep per call (fused, bucketed):
//   bin edges by dst>>8 -> single-block scan of bucket totals ->
//   csr_build2: per-bucket {LDS histogram -> LDS scan -> row_start/dis write
//   -> LDS scatter -> coalesced csr flush}.
// out[n] = dis[n]*( sum_e h'[s] + h'[n] ) + b,  h'[r] = dis[r]*(h@W)[r]
// Aggregation: 4 nodes/wave, 16 lanes/node (full 256B row per group),
// 32-bit saddr offsets; epilogue runs on all 64 lanes.
// ---------------------------------------------------------------------------

typedef unsigned short ushort_t;
typedef unsigned int   uint_t;
typedef short  bf16x8 __attribute__((ext_vector_type(8)));
typedef float  f32x4  __attribute__((ext_vector_type(4)));

#define BKT_SHIFT 8               // 256 nodes per bucket
#define BKT_CAP   5120            // >= max edges per bucket (mean 4096, +16 sigma)
#define BIN_CHUNK 4096            // edges per bin workgroup

__device__ __forceinline__ ushort_t f2bf(float f) {
    union { float f; uint_t u; } v; v.f = f;
    uint_t u = v.u;
    u += 0x7fffu + ((u >> 16) & 1u);      // round-to-nearest-even
    return (ushort_t)(u >> 16);
}
__device__ __forceinline__ float bflo(uint_t u) {
    union { uint_t q; float f; } v; v.q = u << 16; return v.f;
}
__device__ __forceinline__ float bfhi(uint_t u) {
    union { uint_t q; float f; } v; v.q = u & 0xffff0000u; return v.f;
}

// ------------------------------- graph prep -------------------------------

__global__ __launch_bounds__(256) void bin_kernel(const int* __restrict__ srcArr,
                                                  const int* __restrict__ dstArr,
                                                  int* __restrict__ bkt_cursor,
                                                  uint2* __restrict__ staging,
                                                  int E, int nb) {
    __shared__ int hist[512];
    __shared__ int base[512];
    for (int b = threadIdx.x; b < 512; b += 256) hist[b] = 0;
    __syncthreads();
    const int e0 = blockIdx.x * BIN_CHUNK;
    #pragma unroll 4
    for (int k = 0; k < BIN_CHUNK / 256; ++k) {
        int e = e0 + k * 256 + threadIdx.x;
        if (e < E) atomicAdd(&hist[dstArr[e] >> BKT_SHIFT], 1);
    }
    __syncthreads();
    for (int b = threadIdx.x; b < nb; b += 256) {
        int h = hist[b];
        base[b] = h ? atomicAdd(&bkt_cursor[b], h) : 0;
    }
    __syncthreads();
    for (int b = threadIdx.x; b < 512; b += 256) hist[b] = 0;  // reuse as cursor
    __syncthreads();
    #pragma unroll 4
    for (int k = 0; k < BIN_CHUNK / 256; ++k) {
        int e = e0 + k * 256 + threadIdx.x;
        if (e < E) {
            int s = srcArr[e], d = dstArr[e];
            int b = d >> BKT_SHIFT;
            int p = atomicAdd(&hist[b], 1);
            int idx = base[b] + p;
            if (idx < BKT_CAP)
                staging[(size_t)b * BKT_CAP + idx] = make_uint2((uint_t)s, (uint_t)d);
        }
    }
}

// single block: exclusive scan of bucket totals -> bkt_base; row_start[n]=E
__global__ __launch_bounds__(512) void bucket_scan_kernel(const int* __restrict__ bkt_cursor,
                                                          int* __restrict__ bkt_base,
                                                          int* __restrict__ row_start,
                                                          int nbkt, int n) {
    __shared__ int buf[512];
    int v = ((int)threadIdx.x < nbkt) ? min(bkt_cursor[threadIdx.x], BKT_CAP) : 0;
    buf[threadIdx.x] = v;
    __syncthreads();
    for (int off = 1; off < 512; off <<= 1) {
        int t = (threadIdx.x >= (unsigned)off) ? buf[threadIdx.x - off] : 0;
        __syncthreads();
        buf[threadIdx.x] += t;
        __syncthreads();
    }
    if ((int)threadIdx.x < nbkt) bkt_base[threadIdx.x] = buf[threadIdx.x] - v;
    if ((int)threadIdx.x == nbkt - 1) row_start[n] = buf[threadIdx.x];
}

// fused: per-bucket degree histogram -> LDS scan -> row_start & dis writes ->
// LDS scatter -> coalesced csr flush
__global__ __launch_bounds__(256) void csr_build2_kernel(const uint2* __restrict__ staging,
                                                         const int* __restrict__ bkt_cursor,
                                                         const int* __restrict__ bkt_base,
                                                         int* __restrict__ row_start,
                                                         float* __restrict__ dis,
                                                         int* __restrict__ csr_src, int n) {
    __shared__ int cnt[256];
    __shared__ int buf[256];
    __shared__ int rsS[256];
    __shared__ int seg[BKT_CAP];
    const int t  = threadIdx.x;
    const int b  = blockIdx.x;
    const int lo = b << BKT_SHIFT;
    const int nl = min(256, n - lo);
    cnt[t] = 0;
    __syncthreads();
    const int cntE = min(bkt_cursor[b], BKT_CAP);
    for (int e = t; e < cntE; e += 256) {
        uint2 p = staging[(size_t)b * BKT_CAP + e];
        atomicAdd(&cnt[(int)p.y - lo], 1);
    }
    __syncthreads();
    const int v = cnt[t];
    buf[t] = v;
    __syncthreads();
    for (int off = 1; off < 256; off <<= 1) {
        int tt = (t >= off) ? buf[t - off] : 0;
        __syncthreads();
        buf[t] += tt;
        __syncthreads();
    }
    rsS[t] = buf[t] - v;                      // exclusive within-bucket
    const int sbase = bkt_base[b];
    if (t < nl) {
        row_start[lo + t] = sbase + (buf[t] - v);
        dis[lo + t] = rsqrtf((float)(v + 1));
    }
    cnt[t] = 0;                               // reuse as scatter cursor
    __syncthreads();
    for (int e = t; e < cntE; e += 256) {
        uint2 p = staging[(size_t)b * BKT_CAP + e];
        int ln = (int)p.y - lo;
        int q  = atomicAdd(&cnt[ln], 1);
        seg[rsS[ln] + q] = (int)p.x;
    }
    __syncthreads();
    for (int i = t; i < cntE; i += 256) csr_src[sbase + i] = seg[i];
}

// ----------------------------- dtype converts ------------------------------

// x fp32 -> bf16, 8 elems/thread
__global__ void cast_bf16_kernel(const float* __restrict__ in, ushort_t* __restrict__ out, int n8) {
    int i = blockIdx.x * blockDim.x + threadIdx.x;
    if (i >= n8) return;
    const float4 f0 = ((const float4*)in)[2 * i];
    const float4 f1 = ((const float4*)in)[2 * i + 1];
    uint4 o;
    o.x = (uint_t)f2bf(f0.x) | ((uint_t)f2bf(f0.y) << 16);
    o.y = (uint_t)f2bf(f0.z) | ((uint_t)f2bf(f0.w) << 16);
    o.z = (uint_t)f2bf(f1.x) | ((uint_t)f2bf(f1.y) << 16);
    o.w = (uint_t)f2bf(f1.z) | ((uint_t)f2bf(f1.w) << 16);
    ((uint4*)out)[i] = o;
}

// weight transposes (one kernel): Wt[n][k] bf16, zero-padded
__global__ void wt_all_kernel(const float* __restrict__ W1, const float* __restrict__ W2,
                              const float* __restrict__ W3,
                              ushort_t* __restrict__ Wt1, ushort_t* __restrict__ Wt2,
                              ushort_t* __restrict__ Wt3) {
    int idx = blockIdx.x * blockDim.x + threadIdx.x;
    if (idx < 32768) {
        int nn = idx >> 8, k = idx & 255;
        Wt1[idx] = f2bf(W1[(size_t)k * 128 + nn]);
    } else if (idx < 49152) {
        int j = idx - 32768;
        int nn = j >> 7, k = j & 127;
        float v = (nn < 100) ? W2[(size_t)k * 100 + nn] : 0.f;
        Wt2[j] = f2bf(v);
    } else if (idx < 57344) {
        int j = idx - 49152;
        int nn = j >> 7, k = j & 127;
        float v = (k < 100 && nn < 32) ? W3[(size_t)k * 32 + nn] : 0.f;
        Wt3[j] = f2bf(v);
    }
}

// --------------------------- tiled MFMA GEMM -------------------------------
// C[M x BN] (bf16) = dis[row] * (A[M x K] @ Wt[BN x K]^T), BN = NFR*32 = all N.
// BM=64, BK=64, 4 waves (2M x 2N). LDS-staged A and B tiles (+8 pad).
// Swapped-operand MFMA -> lane holds row rsel, cols q*4..+3 -> uint2 stores.
template <int NFR>
__global__ __launch_bounds__(256) void gemm_tile(const ushort_t* __restrict__ A,
                                                 const ushort_t* __restrict__ Bt,
                                                 ushort_t* __restrict__ C,
                                                 const float* __restrict__ dis,
                                                 int M, int K, int lda, int ldb, int ldc) {
    constexpr int BN = NFR * 32;
    __shared__ __attribute__((aligned(16))) ushort_t As[64][72];   // +8 pad
    __shared__ __attribute__((aligned(16))) ushort_t Bs[BN][72];

    const int t    = threadIdx.x;
    const int lane = t & 63;
    const int w    = t >> 6;
    const int wm   = w >> 1, wn = w & 1;
    const int m0   = blockIdx.x * 64;
    const int rsel = lane & 15;
    const int q    = lane >> 4;

    f32x4 acc[2][NFR];
    #pragma unroll
    for (int mi = 0; mi < 2; ++mi)
        #pragma unroll
        for (int ni = 0; ni < NFR; ++ni) acc[mi][ni] = (f32x4){0.f, 0.f, 0.f, 0.f};

    const int srow = t >> 3;          // 0..31
    const int scol = (t & 7) * 8;     // 0..56

    for (int k0 = 0; k0 < K; k0 += 64) {
        #pragma unroll
        for (int it = 0; it < 2; ++it) {            // A tile 64x64
            int r = srow + it * 32;
            int gm = m0 + r;
            bf16x8 v = {0, 0, 0, 0, 0, 0, 0, 0};
            if (gm < M) v = *(const bf16x8*)(A + (size_t)gm * lda + k0 + scol);
            *(bf16x8*)&As[r][scol] = v;
        }
        #pragma unroll
        for (int it = 0; it < BN / 32; ++it) {      // B tile BNx64
            int r = srow + it * 32;
            bf16x8 v = *(const bf16x8*)(Bt + (size_t)r * ldb + k0 + scol);
            *(bf16x8*)&Bs[r][scol] = v;
        }
        __syncthreads();
        #pragma unroll
        for (int ks = 0; ks < 2; ++ks) {
            const int kc = ks * 32 + q * 8;
            bf16x8 af[2], bfr[NFR];
            #pragma unroll
            for (int mi = 0; mi < 2; ++mi)
                af[mi] = *(const bf16x8*)&As[wm * 32 + mi * 16 + rsel][kc];
            #pragma unroll
            for (int ni = 0; ni < NFR; ++ni)
                bfr[ni] = *(const bf16x8*)&Bs[wn * (BN / 2) + ni * 16 + rsel][kc];
            #pragma unroll
            for (int mi = 0; mi < 2; ++mi)
                #pragma unroll
                for (int ni = 0; ni < NFR; ++ni)
                    acc[mi][ni] = __builtin_amdgcn_mfma_f32_16x16x32_bf16(
                        bfr[ni], af[mi], acc[mi][ni], 0, 0, 0);
        }
        __syncthreads();
    }

    // swapped-operand C/D layout: row = rsel, cols = q*4 .. q*4+3 (uint2)
    #pragma unroll
    for (int mi = 0; mi < 2; ++mi) {
        const int gm = m0 + wm * 32 + mi * 16 + rsel;
        if (gm >= M) continue;
        const float d = dis[gm];
        #pragma unroll
        for (int ni = 0; ni < NFR; ++ni) {
            uint2 o;
            o.x = (uint_t)f2bf(acc[mi][ni][0] * d) | ((uint_t)f2bf(acc[mi][ni][1] * d) << 16);
            o.y = (uint_t)f2bf(acc[mi][ni][2] * d) | ((uint_t)f2bf(acc[mi][ni][3] * d) << 16);
            *(uint2*)(C + (size_t)gm * ldc + wn * (BN / 2) + ni * 16 + q * 4) = o;
        }
    }
}

// ---------------------------- aggregation ---------------------------------
// h rows pre-scaled (h' = dis*h). 4 nodes per wave, 16 lanes per node: each
// group covers the full 256B row (lane = 16B chunk = 8 bf16). Per iteration a
// group consumes 4 of its node's edges (4 gathers in flight). No cross-lane
// merge needed; prologue/epilogue/store run with all 64 lanes productive.
template <int F>
__global__ void aggregate128_kernel(const ushort_t* __restrict__ h, const int* __restrict__ row_start,
                                    const int* __restrict__ csr_src,
                                    const float* __restrict__ dis, const float* __restrict__ bias,
                                    ushort_t* __restrict__ out, int n) {
    const int lane = threadIdx.x & 63;
    const int grp  = lane >> 4;                     // node-group within wave
    const int node = blockIdx.x * 16 + (int)(threadIdx.x >> 6) * 4 + grp;
    if (node >= n) return;
    const uint_t fbb = (uint_t)(lane & 15) << 4;    // byte offset within row
    const char* hb = (const char*)h;
    float a[8];
    #pragma unroll
    for (int j = 0; j < 8; ++j) a[j] = 0.f;

    int i = row_start[node];
    const int end = row_start[node + 1];

#define LOADR(S) (*(const uint4*)(hb + (((uint_t)(S) << 8) + fbb)))
#define ACC8(U)                                                     \
    do {                                                            \
        a[0] += bflo((U).x); a[1] += bfhi((U).x);                   \
        a[2] += bflo((U).y); a[3] += bfhi((U).y);                   \
        a[4] += bflo((U).z); a[5] += bfhi((U).z);                   \
        a[6] += bflo((U).w); a[7] += bfhi((U).w);                   \
    } while (0)

    for (; i + 4 <= end; i += 4) {                  // 4 edges per iteration
        int s0 = csr_src[i];
        int s1 = csr_src[i + 1];
        int s2 = csr_src[i + 2];
        int s3 = csr_src[i + 3];
        uint4 u0 = LOADR(s0);
        uint4 u1 = LOADR(s1);
        uint4 u2 = LOADR(s2);
        uint4 u3 = LOADR(s3);
        ACC8(u0); ACC8(u1); ACC8(u2); ACC8(u3);
    }
    for (; i < end; ++i) {
        uint4 u = LOADR(csr_src[i]);
        ACC8(u);
    }
    {
        uint4 su = LOADR(node);                     // self-loop (pre-scaled)
        ACC8(su);
    }
    float dn = dis[node];
    const int fb = (lane & 15) * 8;
    #pragma unroll
    for (int j = 0; j < 8; ++j) {
        float b = (fb + j < F) ? bias[fb + j] : 0.f;
        float v = a[j] * dn + b;
        v = (v > 0.f) ? v : 0.1f * v;
        if (fb + j >= F) v = 0.f;                   // keep K-padding exactly zero
        a[j] = v;
    }
    uint4 o;
    o.x = (uint_t)f2bf(a[0]) | ((uint_t)f2bf(a[1]) << 16);
    o.y = (uint_t)f2bf(a[2]) | ((uint_t)f2bf(a[3]) << 16);
    o.z = (uint_t)f2bf(a[4]) | ((uint_t)f2bf(a[5]) << 16);
    o.w = (uint_t)f2bf(a[6]) | ((uint_t)f2bf(a[7]) << 16);
    *(uint4*)((char*)out + (((uint_t)node << 8) + fbb)) = o;
#undef ACC8
#undef LOADR
}

// F=32, h pre-scaled: 16-lane group per node (2 features/lane), 4 nodes/wave
__global__ void aggregate32_kernel(const ushort_t* __restrict__ h, const int* __restrict__ row_start,
                                   const int* __restrict__ csr_src,
                                   const float* __restrict__ dis, const float* __restrict__ bias,
                                   ushort_t* __restrict__ out, int n) {
    int lane16 = threadIdx.x & 15;
    int node = blockIdx.x * (blockDim.x >> 4) + (threadIdx.x >> 4);
    if (node >= n) return;
    const uint_t fbb = (uint_t)lane16 << 2;        // byte offset within 64B row
    const char* hb = (const char*)h;
#define LOADR32(S) (*(const uint_t*)(hb + (((uint_t)(S) << 6) + fbb)))
    uint_t v = LOADR32(node);
    float acc0 = bflo(v);               // self-loop (pre-scaled)
    float acc1 = bfhi(v);
    int i = row_start[node], end = row_start[node + 1];
    for (; i + 4 <= end; i += 4) {
        uint_t u0 = LOADR32(csr_src[i]);
        uint_t u1 = LOADR32(csr_src[i + 1]);
        uint_t u2 = LOADR32(csr_src[i + 2]);
        uint_t u3 = LOADR32(csr_src[i + 3]);
        acc0 += bflo(u0) + bflo(u1) + bflo(u2) + bflo(u3);
        acc1 += bfhi(u0) + bfhi(u1) + bfhi(u2) + bfhi(u3);
    }
    for (; i < end; ++i) {
        uint_t u = LOADR32(csr_src[i]);
        acc0 += bflo(u); acc1 += bfhi(u);
    }
#undef LOADR32
    float dn = dis[node];
    const int f0 = 2 * lane16;
    acc0 = acc0 * dn + bias[f0];
    acc1 = acc1 * dn + bias[f0 + 1];
    acc0 = (acc0 > 0.f) ? acc0 : 0.1f * acc0;
    acc1 = (acc1 > 0.f) ? acc1 : 0.1f * acc1;
    uint_t o = (uint_t)f2bf(acc0) | ((uint_t)f2bf(acc1) << 16);
    *(uint_t*)((char*)out + (((uint_t)node << 6) + fbb)) = o;
}

// layer 4 GEMM: [N x 32] bf16 @ [32 x 2] fp32 -> fp32, pre-scaled by dis[node]
__global__ void gemm32x2_kernel(const ushort_t* __restrict__ H, const float* __restrict__ W4,
                                const float* __restrict__ dis, float* __restrict__ C, int n) {
    int node = blockIdx.x * blockDim.x + threadIdx.x;
    if (node >= n) return;
    const uint_t* row = (const uint_t*)(H + (size_t)node * 32);
    float a0 = 0.f, a1 = 0.f;
    #pragma unroll
    for (int k2 = 0; k2 < 16; ++k2) {
        uint_t u = row[k2];
        float x0 = bflo(u), x1 = bfhi(u);
        int k = 2 * k2;
        a0 += x0 * W4[k * 2]     + x1 * W4[(k + 1) * 2];
        a1 += x0 * W4[k * 2 + 1] + x1 * W4[(k + 1) * 2 + 1];
    }
    float d = dis[node];
    C[2 * (size_t)node]     = a0 * d;
    C[2 * (size_t)node + 1] = a1 * d;
}

// final aggregation (F=2, h pre-scaled) + bias + softmax, one thread per node
__global__ void aggregate2_softmax_kernel(const float* __restrict__ h, const int* __restrict__ row_start,
                                          const int* __restrict__ csr_src,
                                          const float* __restrict__ dis, const float* __restrict__ bias,
                                          float* __restrict__ out, int n) {
    int node = blockIdx.x * blockDim.x + threadIdx.x;
    if (node >= n) return;
    const char* hb = (const char*)h;
    float a0 = h[2 * (size_t)node];
    float a1 = h[2 * (size_t)node + 1];
    int beg = row_start[node], end = row_start[node + 1];
    for (int i = beg; i < end; ++i) {
        uint_t off = (uint_t)csr_src[i] << 3;
        float2 u = *(const float2*)(hb + off);
        a0 += u.x;
        a1 += u.y;
    }
    float dn = dis[node];
    a0 = a0 * dn + bias[0];
    a1 = a1 * dn + bias[1];
    float m  = fmaxf(a0, a1);
    float e0 = expf(a0 - m), e1 = expf(a1 - m);
    float inv = 1.f / (e0 + e1);
    out[2 * (size_t)node]     = e0 * inv;
    out[2 * (size_t)node + 1] = e1 * inv;
}

// ---------------------------------------------------------------------------

extern "C" void kernel_launch(void* const* d_in, const int* in_sizes, int n_in,
                              void* d_out, int out_size, void* d_ws, size_t ws_size,
                              hipStream_t stream) {
    const float* x  = (const float*)d_in[0];
    const int*   ei = (const int*)d_in[1];
    const float* W1 = (const float*)d_in[2];
    const float* b1 = (const float*)d_in[3];
    const float* W2 = (const float*)d_in[4];
    const float* b2 = (const float*)d_in[5];
    const float* W3 = (const float*)d_in[6];
    const float* b3 = (const float*)d_in[7];
    const float* W4 = (const float*)d_in[8];
    const float* b4 = (const float*)d_in[9];

    const int N = in_sizes[0] / 256;
    const int E = in_sizes[1] / 2;
    const int* srcA = ei;
    const int* dstA = ei + E;
    const int nbkt = (N + 255) >> BKT_SHIFT;

    char* ws = (char*)d_ws;
    size_t off = 0;
    auto alloc = [&](size_t bytes) {
        void* p = ws + off;
        off = (off + bytes + 255) & ~(size_t)255;
        return p;
    };
    float*    dis        = (float*)alloc((size_t)N * 4);
    int*      row_start  = (int*)alloc((size_t)(N + 1) * 4);
    int*      bkt_cursor = (int*)alloc(512 * 4);
    int*      bkt_base   = (int*)alloc(512 * 4);
    int*      csr_src    = (int*)alloc((size_t)E * 4);
    uint2*    staging    = (uint2*)alloc((size_t)nbkt * BKT_CAP * 8);
    ushort_t* xb         = (ushort_t*)alloc((size_t)N * 256 * 2);
    ushort_t* bufA       = (ushort_t*)alloc((size_t)N * 128 * 2);
    ushort_t* bufB       = (ushort_t*)alloc((size_t)N * 128 * 2);
    float*    C4         = (float*)alloc((size_t)N * 2 * 4);
    ushort_t* Wt1        = (ushort_t*)alloc((size_t)128 * 256 * 2);
    ushort_t* Wt2        = (ushort_t*)alloc((size_t)128 * 128 * 2);
    ushort_t* Wt3        = (ushort_t*)alloc((size_t)64 * 128 * 2);
    (void)ws_size;

    hipMemsetAsync(bkt_cursor, 0, 512 * 4, stream);

    // graph prep (bucketed, fused)
    bin_kernel<<<(E + BIN_CHUNK - 1) / BIN_CHUNK, 256, 0, stream>>>(
        srcA, dstA, bkt_cursor, staging, E, nbkt);
    bucket_scan_kernel<<<1, 512, 0, stream>>>(bkt_cursor, bkt_base, row_start, nbkt, N);
    csr_build2_kernel<<<nbkt, 256, 0, stream>>>(staging, bkt_cursor, bkt_base,
                                                row_start, dis, csr_src, N);

    // weight transposes + x cast (bf16)
    wt_all_kernel<<<(57344 + 255) / 256, 256, 0, stream>>>(W1, W2, W3, Wt1, Wt2, Wt3);
    const int n8 = N * 32;   // N*256/8
    cast_bf16_kernel<<<(n8 + 255) / 256, 256, 0, stream>>>(x, xb, n8);

    const int gx = (N + 63) / 64;            // 64 rows per block
    const int aggBlocks128 = (N + 15) / 16;  // 4 waves/block, 4 nodes/wave
    const int aggBlocks32  = (N + 15) / 16;  // 16 nodes/block

    // layer 1: 256 -> 128, single N pass (BN=128)
    gemm_tile<4><<<gx, 256, 0, stream>>>(xb, Wt1, bufA, dis, N, 256, 256, 256, 128);
    aggregate128_kernel<128><<<aggBlocks128, 256, 0, stream>>>(
        bufA, row_start, csr_src, dis, b1, bufB, N);
    // layer 2: 128 -> 100 (padded to 128)
    gemm_tile<4><<<gx, 256, 0, stream>>>(bufB, Wt2, bufA, dis, N, 128, 128, 128, 128);
    aggregate128_kernel<100><<<aggBlocks128, 256, 0, stream>>>(
        bufA, row_start, csr_src, dis, b2, bufB, N);
    // layer 3: 128(pad) -> 32 (BN=32)
    gemm_tile<1><<<gx, 256, 0, stream>>>(bufB, Wt3, bufA, dis, N, 128, 128, 128, 32);
    aggregate32_kernel<<<aggBlocks32, 256, 0, stream>>>(
        bufA, row_start, csr_src, dis, b3, bufB, N);
    // layer 4: 32 -> 2, aggregate + softmax
    gemm32x2_kernel<<<(N + 255) / 256, 256, 0, stream>>>(bufB, W4, dis, C4, N);
    aggregate2_softmax_kernel<<<(N + 255) / 256, 256, 0, stream>>>(
        C4, row_start, csr_src, dis, b4, (float*)d_out, N);
}

// Round 13
// 279.345 us; speedup vs baseline: 1.3169x; 1.0716x over previous
//
#include <hip/hip_runtime.h>
#include <math.h>

// ---------------------------------------------------------------------------
// GCN: 4x (bf16-MFMA tiled GEMM (BM=64,BN=full,BK=64, 4 waves 2Mx2N,
//      LDS-staged; layer-1 converts fp32 A in-staging; epilogue pre-scales
//      rows by dis) -> pure-sum aggregation (+bias, lrelu)) -> softmax.
// Graph prep per call (fused, bucketed, packed-uint staging):
//   bin edges by dst>>8 (edges register-cached) -> single-block bucket scan ->
//   csr_build2: per-bucket {LDS histogram -> LDS scan -> row_start/dis write
//   -> LDS scatter -> coalesced csr flush}.
// out[n] = dis[n]*( sum_e h'[s] + h'[n] ) + b,  h'[r] = dis[r]*(h@W)[r]
// Aggregation: 4 nodes/wave, 16 lanes/node, 8 gathers in flight per iter.
// ---------------------------------------------------------------------------

typedef unsigned short ushort_t;
typedef unsigned int   uint_t;
typedef short  bf16x8 __attribute__((ext_vector_type(8)));
typedef float  f32x4  __attribute__((ext_vector_type(4)));

#define BKT_SHIFT 8               // 256 nodes per bucket
#define BKT_CAP   5120            // >= max edges per bucket (mean 4096, +16 sigma)
#define BIN_CHUNK 4096            // edges per bin workgroup

__device__ __forceinline__ ushort_t f2bf(float f) {
    union { float f; uint_t u; } v; v.f = f;
    uint_t u = v.u;
    u += 0x7fffu + ((u >> 16) & 1u);      // round-to-nearest-even
    return (ushort_t)(u >> 16);
}
__device__ __forceinline__ float bflo(uint_t u) {
    union { uint_t q; float f; } v; v.q = u << 16; return v.f;
}
__device__ __forceinline__ float bfhi(uint_t u) {
    union { uint_t q; float f; } v; v.q = u & 0xffff0000u; return v.f;
}

// ------------------------------- graph prep -------------------------------

// Edges register-cached across phases; staging entry = (src<<8)|dst_local.
__global__ __launch_bounds__(256) void bin_kernel(const int* __restrict__ srcArr,
                                                  const int* __restrict__ dstArr,
                                                  int* __restrict__ bkt_cursor,
                                                  uint_t* __restrict__ staging,
                                                  int E, int nb) {
    __shared__ int hist[512];
    __shared__ int base[512];
    for (int b = threadIdx.x; b < 512; b += 256) hist[b] = 0;
    __syncthreads();
    const int e0 = blockIdx.x * BIN_CHUNK;
    int sv[16], dv[16];
    #pragma unroll
    for (int k = 0; k < 16; ++k) {
        int e = e0 + k * 256 + threadIdx.x;
        if (e < E) {
            sv[k] = srcArr[e];
            dv[k] = dstArr[e];
            atomicAdd(&hist[dv[k] >> BKT_SHIFT], 1);
        } else {
            sv[k] = 0; dv[k] = -1;
        }
    }
    __syncthreads();
    for (int b = threadIdx.x; b < nb; b += 256) {
        int h = hist[b];
        base[b] = h ? atomicAdd(&bkt_cursor[b], h) : 0;
    }
    __syncthreads();
    for (int b = threadIdx.x; b < 512; b += 256) hist[b] = 0;  // reuse as cursor
    __syncthreads();
    #pragma unroll
    for (int k = 0; k < 16; ++k) {
        if (dv[k] >= 0) {
            int b = dv[k] >> BKT_SHIFT;
            int p = atomicAdd(&hist[b], 1);
            int idx = base[b] + p;
            if (idx < BKT_CAP)
                staging[(size_t)b * BKT_CAP + idx] =
                    ((uint_t)sv[k] << 8) | (uint_t)(dv[k] & 255);
        }
    }
}

// single block: exclusive scan of bucket totals -> bkt_base; row_start[n]=E
__global__ __launch_bounds__(512) void bucket_scan_kernel(const int* __restrict__ bkt_cursor,
                                                          int* __restrict__ bkt_base,
                                                          int* __restrict__ row_start,
                                                          int nbkt, int n) {
    __shared__ int buf[512];
    int v = ((int)threadIdx.x < nbkt) ? min(bkt_cursor[threadIdx.x], BKT_CAP) : 0;
    buf[threadIdx.x] = v;
    __syncthreads();
    for (int off = 1; off < 512; off <<= 1) {
        int t = (threadIdx.x >= (unsigned)off) ? buf[threadIdx.x - off] : 0;
        __syncthreads();
        buf[threadIdx.x] += t;
        __syncthreads();
    }
    if ((int)threadIdx.x < nbkt) bkt_base[threadIdx.x] = buf[threadIdx.x] - v;
    if ((int)threadIdx.x == nbkt - 1) row_start[n] = buf[threadIdx.x];
}

// fused: per-bucket degree histogram -> LDS scan -> row_start & dis writes ->
// LDS scatter -> coalesced csr flush  (packed-uint staging)
__global__ __launch_bounds__(256) void csr_build2_kernel(const uint_t* __restrict__ staging,
                                                         const int* __restrict__ bkt_cursor,
                                                         const int* __restrict__ bkt_base,
                                                         int* __restrict__ row_start,
                                                         float* __restrict__ dis,
                                                         int* __restrict__ csr_src, int n) {
    __shared__ int cnt[256];
    __shared__ int buf[256];
    __shared__ int rsS[256];
    __shared__ int seg[BKT_CAP];
    const int t  = threadIdx.x;
    const int b  = blockIdx.x;
    const int lo = b << BKT_SHIFT;
    const int nl = min(256, n - lo);
    cnt[t] = 0;
    __syncthreads();
    const int cntE = min(bkt_cursor[b], BKT_CAP);
    for (int e = t; e < cntE; e += 256) {
        uint_t p = staging[(size_t)b * BKT_CAP + e];
        atomicAdd(&cnt[p & 255u], 1);
    }
    __syncthreads();
    const int v = cnt[t];
    buf[t] = v;
    __syncthreads();
    for (int off = 1; off < 256; off <<= 1) {
        int tt = (t >= off) ? buf[t - off] : 0;
        __syncthreads();
        buf[t] += tt;
        __syncthreads();
    }
    rsS[t] = buf[t] - v;                      // exclusive within-bucket
    const int sbase = bkt_base[b];
    if (t < nl) {
        row_start[lo + t] = sbase + (buf[t] - v);
        dis[lo + t] = rsqrtf((float)(v + 1));
    }
    cnt[t] = 0;                               // reuse as scatter cursor
    __syncthreads();
    for (int e = t; e < cntE; e += 256) {
        uint_t p = staging[(size_t)b * BKT_CAP + e];
        int ln = (int)(p & 255u);
        int q  = atomicAdd(&cnt[ln], 1);
        seg[rsS[ln] + q] = (int)(p >> 8);
    }
    __syncthreads();
    for (int i = t; i < cntE; i += 256) csr_src[sbase + i] = seg[i];
}

// -------------------- weight transposes (one kernel) -----------------------
__global__ void wt_all_kernel(const float* __restrict__ W1, const float* __restrict__ W2,
                              const float* __restrict__ W3,
                              ushort_t* __restrict__ Wt1, ushort_t* __restrict__ Wt2,
                              ushort_t* __restrict__ Wt3) {
    int idx = blockIdx.x * blockDim.x + threadIdx.x;
    if (idx < 32768) {
        int nn = idx >> 8, k = idx & 255;
        Wt1[idx] = f2bf(W1[(size_t)k * 128 + nn]);
    } else if (idx < 49152) {
        int j = idx - 32768;
        int nn = j >> 7, k = j & 127;
        float v = (nn < 100) ? W2[(size_t)k * 100 + nn] : 0.f;
        Wt2[j] = f2bf(v);
    } else if (idx < 57344) {
        int j = idx - 49152;
        int nn = j >> 7, k = j & 127;
        float v = (k < 100 && nn < 32) ? W3[(size_t)k * 32 + nn] : 0.f;
        Wt3[j] = f2bf(v);
    }
}

// --------------------------- tiled MFMA GEMM -------------------------------
// C[M x BN] (bf16) = dis[row] * (A[M x K] @ Wt[BN x K]^T), BN = NFR*32 = all N.
// BM=64, BK=64, 4 waves (2M x 2N). LDS-staged A and B tiles (+8 pad).
// A_FP32: fp32 A converted to bf16 during staging (layer 1, reads x once).
// Swapped-operand MFMA -> lane holds row rsel, cols q*4..+3 -> uint2 stores.
template <bool A_FP32, int NFR>
__global__ __launch_bounds__(256) void gemm_tile(const void* __restrict__ Av,
                                                 const ushort_t* __restrict__ Bt,
                                                 ushort_t* __restrict__ C,
                                                 const float* __restrict__ dis,
                                                 int M, int K, int lda, int ldb, int ldc) {
    constexpr int BN = NFR * 32;
    __shared__ __attribute__((aligned(16))) ushort_t As[64][72];   // +8 pad
    __shared__ __attribute__((aligned(16))) ushort_t Bs[BN][72];

    const int t    = threadIdx.x;
    const int lane = t & 63;
    const int w    = t >> 6;
    const int wm   = w >> 1, wn = w & 1;
    const int m0   = blockIdx.x * 64;
    const int rsel = lane & 15;
    const int q    = lane >> 4;

    f32x4 acc[2][NFR];
    #pragma unroll
    for (int mi = 0; mi < 2; ++mi)
        #pragma unroll
        for (int ni = 0; ni < NFR; ++ni) acc[mi][ni] = (f32x4){0.f, 0.f, 0.f, 0.f};

    const int srow = t >> 3;          // 0..31
    const int scol = (t & 7) * 8;     // 0..56

    for (int k0 = 0; k0 < K; k0 += 64) {
        #pragma unroll
        for (int it = 0; it < 2; ++it) {            // A tile 64x64
            int r = srow + it * 32;
            int gm = m0 + r;
            bf16x8 v = {0, 0, 0, 0, 0, 0, 0, 0};
            if (gm < M) {
                if (A_FP32) {
                    const float* A = (const float*)Av;
                    const float4 f0 = *(const float4*)(A + (size_t)gm * lda + k0 + scol);
                    const float4 f1 = *(const float4*)(A + (size_t)gm * lda + k0 + scol + 4);
                    ushort_t o[8] = { f2bf(f0.x), f2bf(f0.y), f2bf(f0.z), f2bf(f0.w),
                                      f2bf(f1.x), f2bf(f1.y), f2bf(f1.z), f2bf(f1.w) };
                    v = *(const bf16x8*)o;
                } else {
                    const ushort_t* A = (const ushort_t*)Av;
                    v = *(const bf16x8*)(A + (size_t)gm * lda + k0 + scol);
                }
            }
            *(bf16x8*)&As[r][scol] = v;
        }
        #pragma unroll
        for (int it = 0; it < BN / 32; ++it) {      // B tile BNx64
            int r = srow + it * 32;
            bf16x8 v = *(const bf16x8*)(Bt + (size_t)r * ldb + k0 + scol);
            *(bf16x8*)&Bs[r][scol] = v;
        }
        __syncthreads();
        #pragma unroll
        for (int ks = 0; ks < 2; ++ks) {
            const int kc = ks * 32 + q * 8;
            bf16x8 af[2], bfr[NFR];
            #pragma unroll
            for (int mi = 0; mi < 2; ++mi)
                af[mi] = *(const bf16x8*)&As[wm * 32 + mi * 16 + rsel][kc];
            #pragma unroll
            for (int ni = 0; ni < NFR; ++ni)
                bfr[ni] = *(const bf16x8*)&Bs[wn * (BN / 2) + ni * 16 + rsel][kc];
            #pragma unroll
            for (int mi = 0; mi < 2; ++mi)
                #pragma unroll
                for (int ni = 0; ni < NFR; ++ni)
                    acc[mi][ni] = __builtin_amdgcn_mfma_f32_16x16x32_bf16(
                        bfr[ni], af[mi], acc[mi][ni], 0, 0, 0);
        }
        __syncthreads();
    }

    // swapped-operand C/D layout: row = rsel, cols = q*4 .. q*4+3 (uint2)
    #pragma unroll
    for (int mi = 0; mi < 2; ++mi) {
        const int gm = m0 + wm * 32 + mi * 16 + rsel;
        if (gm >= M) continue;
        const float d = dis[gm];
        #pragma unroll
        for (int ni = 0; ni < NFR; ++ni) {
            uint2 o;
            o.x = (uint_t)f2bf(acc[mi][ni][0] * d) | ((uint_t)f2bf(acc[mi][ni][1] * d) << 16);
            o.y = (uint_t)f2bf(acc[mi][ni][2] * d) | ((uint_t)f2bf(acc[mi][ni][3] * d) << 16);
            *(uint2*)(C + (size_t)gm * ldc + wn * (BN / 2) + ni * 16 + q * 4) = o;
        }
    }
}

// ---------------------------- aggregation ---------------------------------
// h rows pre-scaled (h' = dis*h). 4 nodes per wave, 16 lanes per node: each
// group covers the full 256B row (lane = 16B chunk = 8 bf16). Per iteration a
// group consumes 8 of its node's edges (8 gathers in flight). No cross-lane
// merge; prologue/epilogue/store run with all 64 lanes productive.
template <int F>
__global__ void aggregate128_kernel(const ushort_t* __restrict__ h, const int* __restrict__ row_start,
                                    const int* __restrict__ csr_src,
                                    const float* __restrict__ dis, const float* __restrict__ bias,
                                    ushort_t* __restrict__ out, int n) {
    const int lane = threadIdx.x & 63;
    const int grp  = lane >> 4;                     // node-group within wave
    const int node = blockIdx.x * 16 + (int)(threadIdx.x >> 6) * 4 + grp;
    if (node >= n) return;
    const uint_t fbb = (uint_t)(lane & 15) << 4;    // byte offset within row
    const char* hb = (const char*)h;
    float a[8];
    #pragma unroll
    for (int j = 0; j < 8; ++j) a[j] = 0.f;

    int i = row_start[node];
    const int end = row_start[node + 1];

#define LOADR(S) (*(const uint4*)(hb + (((uint_t)(S) << 8) + fbb)))
#define ACC8(U)                                                     \
    do {                                                            \
        a[0] += bflo((U).x); a[1] += bfhi((U).x);                   \
        a[2] += bflo((U).y); a[3] += bfhi((U).y);                   \
        a[4] += bflo((U).z); a[5] += bfhi((U).z);                   \
        a[6] += bflo((U).w); a[7] += bfhi((U).w);                   \
    } while (0)

    for (; i + 8 <= end; i += 8) {                  // 8 gathers in flight
        int s0 = csr_src[i];
        int s1 = csr_src[i + 1];
        int s2 = csr_src[i + 2];
        int s3 = csr_src[i + 3];
        int s4 = csr_src[i + 4];
        int s5 = csr_src[i + 5];
        int s6 = csr_src[i + 6];
        int s7 = csr_src[i + 7];
        uint4 u0 = LOADR(s0);
        uint4 u1 = LOADR(s1);
        uint4 u2 = LOADR(s2);
        uint4 u3 = LOADR(s3);
        uint4 u4 = LOADR(s4);
        uint4 u5 = LOADR(s5);
        uint4 u6 = LOADR(s6);
        uint4 u7 = LOADR(s7);
        ACC8(u0); ACC8(u1); ACC8(u2); ACC8(u3);
        ACC8(u4); ACC8(u5); ACC8(u6); ACC8(u7);
    }
    for (; i + 4 <= end; i += 4) {
        int s0 = csr_src[i];
        int s1 = csr_src[i + 1];
        int s2 = csr_src[i + 2];
        int s3 = csr_src[i + 3];
        uint4 u0 = LOADR(s0);
        uint4 u1 = LOADR(s1);
        uint4 u2 = LOADR(s2);
        uint4 u3 = LOADR(s3);
        ACC8(u0); ACC8(u1); ACC8(u2); ACC8(u3);
    }
    for (; i < end; ++i) {
        uint4 u = LOADR(csr_src[i]);
        ACC8(u);
    }
    {
        uint4 su = LOADR(node);                     // self-loop (pre-scaled)
        ACC8(su);
    }
    float dn = dis[node];
    const int fb = (lane & 15) * 8;
    #pragma unroll
    for (int j = 0; j < 8; ++j) {
        float b = (fb + j < F) ? bias[fb + j] : 0.f;
        float v = a[j] * dn + b;
        v = (v > 0.f) ? v : 0.1f * v;
        if (fb + j >= F) v = 0.f;                   // keep K-padding exactly zero
        a[j] = v;
    }
    uint4 o;
    o.x = (uint_t)f2bf(a[0]) | ((uint_t)f2bf(a[1]) << 16);
    o.y = (uint_t)f2bf(a[2]) | ((uint_t)f2bf(a[3]) << 16);
    o.z = (uint_t)f2bf(a[4]) | ((uint_t)f2bf(a[5]) << 16);
    o.w = (uint_t)f2bf(a[6]) | ((uint_t)f2bf(a[7]) << 16);
    *(uint4*)((char*)out + (((uint_t)node << 8) + fbb)) = o;
#undef ACC8
#undef LOADR
}

// F=32, h pre-scaled: 16-lane group per node (2 features/lane), 4 nodes/wave
__global__ void aggregate32_kernel(const ushort_t* __restrict__ h, const int* __restrict__ row_start,
                                   const int* __restrict__ csr_src,
                                   const float* __restrict__ dis, const float* __restrict__ bias,
                                   ushort_t* __restrict__ out, int n) {
    int lane16 = threadIdx.x & 15;
    int node = blockIdx.x * (blockDim.x >> 4) + (threadIdx.x >> 4);
    if (node >= n) return;
    const uint_t fbb = (uint_t)lane16 << 2;        // byte offset within 64B row
    const char* hb = (const char*)h;
#define LOADR32(S) (*(const uint_t*)(hb + (((uint_t)(S) << 6) + fbb)))
    uint_t v = LOADR32(node);
    float acc0 = bflo(v);               // self-loop (pre-scaled)
    float acc1 = bfhi(v);
    int i = row_start[node], end = row_start[node + 1];
    for (; i + 4 <= end; i += 4) {
        uint_t u0 = LOADR32(csr_src[i]);
        uint_t u1 = LOADR32(csr_src[i + 1]);
        uint_t u2 = LOADR32(csr_src[i + 2]);
        uint_t u3 = LOADR32(csr_src[i + 3]);
        acc0 += bflo(u0) + bflo(u1) + bflo(u2) + bflo(u3);
        acc1 += bfhi(u0) + bfhi(u1) + bfhi(u2) + bfhi(u3);
    }
    for (; i < end; ++i) {
        uint_t u = LOADR32(csr_src[i]);
        acc0 += bflo(u); acc1 += bfhi(u);
    }
#undef LOADR32
    float dn = dis[node];
    const int f0 = 2 * lane16;
    acc0 = acc0 * dn + bias[f0];
    acc1 = acc1 * dn + bias[f0 + 1];
    acc0 = (acc0 > 0.f) ? acc0 : 0.1f * acc0;
    acc1 = (acc1 > 0.f) ? acc1 : 0.1f * acc1;
    uint_t o = (uint_t)f2bf(acc0) | ((uint_t)f2bf(acc1) << 16);
    *(uint_t*)((char*)out + (((uint_t)node << 6) + fbb)) = o;
}

// layer 4 GEMM: [N x 32] bf16 @ [32 x 2] fp32 -> fp32, pre-scaled by dis[node]
__global__ void gemm32x2_kernel(const ushort_t* __restrict__ H, const float* __restrict__ W4,
                                const float* __restrict__ dis, float* __restrict__ C, int n) {
    int node = blockIdx.x * blockDim.x + threadIdx.x;
    if (node >= n) return;
    const uint_t* row = (const uint_t*)(H + (size_t)node * 32);
    float a0 = 0.f, a1 = 0.f;
    #pragma unroll
    for (int k2 = 0; k2 < 16; ++k2) {
        uint_t u = row[k2];
        float x0 = bflo(u), x1 = bfhi(u);
        int k = 2 * k2;
        a0 += x0 * W4[k * 2]     + x1 * W4[(k + 1) * 2];
        a1 += x0 * W4[k * 2 + 1] + x1 * W4[(k + 1) * 2 + 1];
    }
    float d = dis[node];
    C[2 * (size_t)node]     = a0 * d;
    C[2 * (size_t)node + 1] = a1 * d;
}

// final aggregation (F=2, h pre-scaled) + bias + softmax, one thread per node
__global__ void aggregate2_softmax_kernel(const float* __restrict__ h, const int* __restrict__ row_start,
                                          const int* __restrict__ csr_src,
                                          const float* __restrict__ dis, const float* __restrict__ bias,
                                          float* __restrict__ out, int n) {
    int node = blockIdx.x * blockDim.x + threadIdx.x;
    if (node >= n) return;
    const char* hb = (const char*)h;
    float a0 = h[2 * (size_t)node];
    float a1 = h[2 * (size_t)node + 1];
    int beg = row_start[node], end = row_start[node + 1];
    for (int i = beg; i < end; ++i) {
        uint_t off = (uint_t)csr_src[i] << 3;
        float2 u = *(const float2*)(hb + off);
        a0 += u.x;
        a1 += u.y;
    }
    float dn = dis[node];
    a0 = a0 * dn + bias[0];
    a1 = a1 * dn + bias[1];
    float m  = fmaxf(a0, a1);
    float e0 = expf(a0 - m), e1 = expf(a1 - m);
    float inv = 1.f / (e0 + e1);
    out[2 * (size_t)node]     = e0 * inv;
    out[2 * (size_t)node + 1] = e1 * inv;
}

// ---------------------------------------------------------------------------

extern "C" void kernel_launch(void* const* d_in, const int* in_sizes, int n_in,
                              void* d_out, int out_size, void* d_ws, size_t ws_size,
                              hipStream_t stream) {
    const float* x  = (const float*)d_in[0];
    const int*   ei = (const int*)d_in[1];
    const float* W1 = (const float*)d_in[2];
    const float* b1 = (const float*)d_in[3];
    const float* W2 = (const float*)d_in[4];
    const float* b2 = (const float*)d_in[5];
    const float* W3 = (const float*)d_in[6];
    const float* b3 = (const float*)d_in[7];
    const float* W4 = (const float*)d_in[8];
    const float* b4 = (const float*)d_in[9];

    const int N = in_sizes[0] / 256;
    const int E = in_sizes[1] / 2;
    const int* srcA = ei;
    const int* dstA = ei + E;
    const int nbkt = (N + 255) >> BKT_SHIFT;

    char* ws = (char*)d_ws;
    size_t off = 0;
    auto alloc = [&](size_t bytes) {
        void* p = ws + off;
        off = (off + bytes + 255) & ~(size_t)255;
        return p;
    };
    float*    dis        = (float*)alloc((size_t)N * 4);
    int*      row_start  = (int*)alloc((size_t)(N + 1) * 4);
    int*      bkt_cursor = (int*)alloc(512 * 4);
    int*      bkt_base   = (int*)alloc(512 * 4);
    int*      csr_src    = (int*)alloc((size_t)E * 4);
    uint_t*   staging    = (uint_t*)alloc((size_t)nbkt * BKT_CAP * 4);
    ushort_t* bufA       = (ushort_t*)alloc((size_t)N * 128 * 2);
    ushort_t* bufB       = (ushort_t*)alloc((size_t)N * 128 * 2);
    float*    C4         = (float*)alloc((size_t)N * 2 * 4);
    ushort_t* Wt1        = (ushort_t*)alloc((size_t)128 * 256 * 2);
    ushort_t* Wt2        = (ushort_t*)alloc((size_t)128 * 128 * 2);
    ushort_t* Wt3        = (ushort_t*)alloc((size_t)64 * 128 * 2);
    (void)ws_size;

    hipMemsetAsync(bkt_cursor, 0, 512 * 4, stream);

    // graph prep (bucketed, fused, packed staging)
    bin_kernel<<<(E + BIN_CHUNK - 1) / BIN_CHUNK, 256, 0, stream>>>(
        srcA, dstA, bkt_cursor, staging, E, nbkt);
    bucket_scan_kernel<<<1, 512, 0, stream>>>(bkt_cursor, bkt_base, row_start, nbkt, N);
    csr_build2_kernel<<<nbkt, 256, 0, stream>>>(staging, bkt_cursor, bkt_base,
                                                row_start, dis, csr_src, N);

    // weight transposes (bf16, padded)
    wt_all_kernel<<<(57344 + 255) / 256, 256, 0, stream>>>(W1, W2, W3, Wt1, Wt2, Wt3);

    const int gx = (N + 63) / 64;            // 64 rows per block
    const int aggBlocks128 = (N + 15) / 16;  // 4 waves/block, 4 nodes/wave
    const int aggBlocks32  = (N + 15) / 16;  // 16 nodes/block

    // layer 1: 256 -> 128, fp32 A converted in-staging (x read once)
    gemm_tile<true, 4><<<gx, 256, 0, stream>>>(x, Wt1, bufA, dis, N, 256, 256, 256, 128);
    aggregate128_kernel<128><<<aggBlocks128, 256, 0, stream>>>(
        bufA, row_start, csr_src, dis, b1, bufB, N);
    // layer 2: 128 -> 100 (padded to 128)
    gemm_tile<false, 4><<<gx, 256, 0, stream>>>(bufB, Wt2, bufA, dis, N, 128, 128, 128, 128);
    aggregate128_kernel<100><<<aggBlocks128, 256, 0, stream>>>(
        bufA, row_start, csr_src, dis, b2, bufB, N);
    // layer 3: 128(pad) -> 32 (BN=32)
    gemm_tile<false, 1><<<gx, 256, 0, stream>>>(bufB, Wt3, bufA, dis, N, 128, 128, 128, 32);
    aggregate32_kernel<<<aggBlocks32, 256, 0, stream>>>(
        bufA, row_start, csr_src, dis, b3, bufB, N);
    // layer 4: 32 -> 2, aggregate + softmax
    gemm32x2_kernel<<<(N + 255) / 256, 256, 0, stream>>>(bufB, W4, dis, C4, N);
    aggregate2_softmax_kernel<<<(N + 255) / 256, 256, 0, stream>>>(
        C4, row_start, csr_src, dis, b4, (float*)d_out, N);
}

// Round 14
// 279.122 us; speedup vs baseline: 1.3179x; 1.0008x over previous
//
#include <hip/hip_runtime.h>
#include <math.h>

// ---------------------------------------------------------------------------
// GCN: 4x (bf16-MFMA tiled GEMM (BM=64,BN=full,BK=64, 4 waves 2Mx2N,
//      LDS-staged; layer-1 converts fp32 A in-staging; epilogue pre-scales
//      rows by dis) -> pure-sum aggregation (+bias, lrelu)) -> softmax.
// Graph prep per call (fused, bucketed, packed-uint staging):
//   bin edges by dst>>8 (edges register-cached) -> single-block bucket scan ->
//   csr_build2: per-bucket {LDS histogram -> LDS scan -> row_start/dis write
//   -> LDS scatter -> coalesced csr flush}.
// out[n] = dis[n]*( sum_e h'[s] + h'[n] ) + b,  h'[r] = dis[r]*(h@W)[r]
// Aggregation: 4 nodes/wave, 16 lanes/node, 8 gathers in flight per iter.
// ---------------------------------------------------------------------------

typedef unsigned short ushort_t;
typedef unsigned int   uint_t;
typedef short  bf16x8 __attribute__((ext_vector_type(8)));
typedef float  f32x4  __attribute__((ext_vector_type(4)));

#define BKT_SHIFT 8               // 256 nodes per bucket
#define BKT_CAP   5120            // >= max edges per bucket (mean 4096, +16 sigma)
#define BIN_CHUNK 4096            // edges per bin workgroup

__device__ __forceinline__ ushort_t f2bf(float f) {
    union { float f; uint_t u; } v; v.f = f;
    uint_t u = v.u;
    u += 0x7fffu + ((u >> 16) & 1u);      // round-to-nearest-even
    return (ushort_t)(u >> 16);
}
__device__ __forceinline__ float bflo(uint_t u) {
    union { uint_t q; float f; } v; v.q = u << 16; return v.f;
}
__device__ __forceinline__ float bfhi(uint_t u) {
    union { uint_t q; float f; } v; v.q = u & 0xffff0000u; return v.f;
}

// ------------------------------- graph prep -------------------------------

// Edges register-cached across phases; staging entry = (src<<8)|dst_local.
__global__ __launch_bounds__(256) void bin_kernel(const int* __restrict__ srcArr,
                                                  const int* __restrict__ dstArr,
                                                  int* __restrict__ bkt_cursor,
                                                  uint_t* __restrict__ staging,
                                                  int E, int nb) {
    __shared__ int hist[512];
    __shared__ int base[512];
    for (int b = threadIdx.x; b < 512; b += 256) hist[b] = 0;
    __syncthreads();
    const int e0 = blockIdx.x * BIN_CHUNK;
    int sv[16], dv[16];
    #pragma unroll
    for (int k = 0; k < 16; ++k) {
        int e = e0 + k * 256 + threadIdx.x;
        if (e < E) {
            sv[k] = srcArr[e];
            dv[k] = dstArr[e];
            atomicAdd(&hist[dv[k] >> BKT_SHIFT], 1);
        } else {
            sv[k] = 0; dv[k] = -1;
        }
    }
    __syncthreads();
    for (int b = threadIdx.x; b < nb; b += 256) {
        int h = hist[b];
        base[b] = h ? atomicAdd(&bkt_cursor[b], h) : 0;
    }
    __syncthreads();
    for (int b = threadIdx.x; b < 512; b += 256) hist[b] = 0;  // reuse as cursor
    __syncthreads();
    #pragma unroll
    for (int k = 0; k < 16; ++k) {
        if (dv[k] >= 0) {
            int b = dv[k] >> BKT_SHIFT;
            int p = atomicAdd(&hist[b], 1);
            int idx = base[b] + p;
            if (idx < BKT_CAP)
                staging[(size_t)b * BKT_CAP + idx] =
                    ((uint_t)sv[k] << 8) | (uint_t)(dv[k] & 255);
        }
    }
}

// single block: exclusive scan of bucket totals -> bkt_base; row_start[n]=E
__global__ __launch_bounds__(512) void bucket_scan_kernel(const int* __restrict__ bkt_cursor,
                                                          int* __restrict__ bkt_base,
                                                          int* __restrict__ row_start,
                                                          int nbkt, int n) {
    __shared__ int buf[512];
    int v = ((int)threadIdx.x < nbkt) ? min(bkt_cursor[threadIdx.x], BKT_CAP) : 0;
    buf[threadIdx.x] = v;
    __syncthreads();
    for (int off = 1; off < 512; off <<= 1) {
        int t = (threadIdx.x >= (unsigned)off) ? buf[threadIdx.x - off] : 0;
        __syncthreads();
        buf[threadIdx.x] += t;
        __syncthreads();
    }
    if ((int)threadIdx.x < nbkt) bkt_base[threadIdx.x] = buf[threadIdx.x] - v;
    if ((int)threadIdx.x == nbkt - 1) row_start[n] = buf[threadIdx.x];
}

// fused: per-bucket degree histogram -> LDS scan -> row_start & dis writes ->
// LDS scatter -> coalesced csr flush  (packed-uint staging)
__global__ __launch_bounds__(256) void csr_build2_kernel(const uint_t* __restrict__ staging,
                                                         const int* __restrict__ bkt_cursor,
                                                         const int* __restrict__ bkt_base,
                                                         int* __restrict__ row_start,
                                                         float* __restrict__ dis,
                                                         int* __restrict__ csr_src, int n) {
    __shared__ int cnt[256];
    __shared__ int buf[256];
    __shared__ int rsS[256];
    __shared__ int seg[BKT_CAP];
    const int t  = threadIdx.x;
    const int b  = blockIdx.x;
    const int lo = b << BKT_SHIFT;
    const int nl = min(256, n - lo);
    cnt[t] = 0;
    __syncthreads();
    const int cntE = min(bkt_cursor[b], BKT_CAP);
    for (int e = t; e < cntE; e += 256) {
        uint_t p = staging[(size_t)b * BKT_CAP + e];
        atomicAdd(&cnt[p & 255u], 1);
    }
    __syncthreads();
    const int v = cnt[t];
    buf[t] = v;
    __syncthreads();
    for (int off = 1; off < 256; off <<= 1) {
        int tt = (t >= off) ? buf[t - off] : 0;
        __syncthreads();
        buf[t] += tt;
        __syncthreads();
    }
    rsS[t] = buf[t] - v;                      // exclusive within-bucket
    const int sbase = bkt_base[b];
    if (t < nl) {
        row_start[lo + t] = sbase + (buf[t] - v);
        dis[lo + t] = rsqrtf((float)(v + 1));
    }
    cnt[t] = 0;                               // reuse as scatter cursor
    __syncthreads();
    for (int e = t; e < cntE; e += 256) {
        uint_t p = staging[(size_t)b * BKT_CAP + e];
        int ln = (int)(p & 255u);
        int q  = atomicAdd(&cnt[ln], 1);
        seg[rsS[ln] + q] = (int)(p >> 8);
    }
    __syncthreads();
    for (int i = t; i < cntE; i += 256) csr_src[sbase + i] = seg[i];
}

// -------------------- weight transposes (one kernel) -----------------------
__global__ void wt_all_kernel(const float* __restrict__ W1, const float* __restrict__ W2,
                              const float* __restrict__ W3,
                              ushort_t* __restrict__ Wt1, ushort_t* __restrict__ Wt2,
                              ushort_t* __restrict__ Wt3) {
    int idx = blockIdx.x * blockDim.x + threadIdx.x;
    if (idx < 32768) {
        int nn = idx >> 8, k = idx & 255;
        Wt1[idx] = f2bf(W1[(size_t)k * 128 + nn]);
    } else if (idx < 49152) {
        int j = idx - 32768;
        int nn = j >> 7, k = j & 127;
        float v = (nn < 100) ? W2[(size_t)k * 100 + nn] : 0.f;
        Wt2[j] = f2bf(v);
    } else if (idx < 57344) {
        int j = idx - 49152;
        int nn = j >> 7, k = j & 127;
        float v = (k < 100 && nn < 32) ? W3[(size_t)k * 32 + nn] : 0.f;
        Wt3[j] = f2bf(v);
    }
}

// --------------------------- tiled MFMA GEMM -------------------------------
// C[M x BN] (bf16) = dis[row] * (A[M x K] @ Wt[BN x K]^T), BN = NFR*32 = all N.
// BM=64, BK=64, 4 waves (2M x 2N). LDS-staged A and B tiles (+8 pad).
// A_FP32: fp32 A converted to bf16 during staging (layer 1, reads x once).
// Swapped-operand MFMA -> lane holds row rsel, cols q*4..+3 -> uint2 stores.
template <bool A_FP32, int NFR>
__global__ __launch_bounds__(256) void gemm_tile(const void* __restrict__ Av,
                                                 const ushort_t* __restrict__ Bt,
                                                 ushort_t* __restrict__ C,
                                                 const float* __restrict__ dis,
                                                 int M, int K, int lda, int ldb, int ldc) {
    constexpr int BN = NFR * 32;
    __shared__ __attribute__((aligned(16))) ushort_t As[64][72];   // +8 pad
    __shared__ __attribute__((aligned(16))) ushort_t Bs[BN][72];

    const int t    = threadIdx.x;
    const int lane = t & 63;
    const int w    = t >> 6;
    const int wm   = w >> 1, wn = w & 1;
    const int m0   = blockIdx.x * 64;
    const int rsel = lane & 15;
    const int q    = lane >> 4;

    f32x4 acc[2][NFR];
    #pragma unroll
    for (int mi = 0; mi < 2; ++mi)
        #pragma unroll
        for (int ni = 0; ni < NFR; ++ni) acc[mi][ni] = (f32x4){0.f, 0.f, 0.f, 0.f};

    const int srow = t >> 3;          // 0..31
    const int scol = (t & 7) * 8;     // 0..56

    for (int k0 = 0; k0 < K; k0 += 64) {
        #pragma unroll
        for (int it = 0; it < 2; ++it) {            // A tile 64x64
            int r = srow + it * 32;
            int gm = m0 + r;
            bf16x8 v = {0, 0, 0, 0, 0, 0, 0, 0};
            if (gm < M) {
                if (A_FP32) {
                    const float* A = (const float*)Av;
                    const float4 f0 = *(const float4*)(A + (size_t)gm * lda + k0 + scol);
                    const float4 f1 = *(const float4*)(A + (size_t)gm * lda + k0 + scol + 4);
                    ushort_t o[8] = { f2bf(f0.x), f2bf(f0.y), f2bf(f0.z), f2bf(f0.w),
                                      f2bf(f1.x), f2bf(f1.y), f2bf(f1.z), f2bf(f1.w) };
                    v = *(const bf16x8*)o;
                } else {
                    const ushort_t* A = (const ushort_t*)Av;
                    v = *(const bf16x8*)(A + (size_t)gm * lda + k0 + scol);
                }
            }
            *(bf16x8*)&As[r][scol] = v;
        }
        #pragma unroll
        for (int it = 0; it < BN / 32; ++it) {      // B tile BNx64
            int r = srow + it * 32;
            bf16x8 v = *(const bf16x8*)(Bt + (size_t)r * ldb + k0 + scol);
            *(bf16x8*)&Bs[r][scol] = v;
        }
        __syncthreads();
        #pragma unroll
        for (int ks = 0; ks < 2; ++ks) {
            const int kc = ks * 32 + q * 8;
            bf16x8 af[2], bfr[NFR];
            #pragma unroll
            for (int mi = 0; mi < 2; ++mi)
                af[mi] = *(const bf16x8*)&As[wm * 32 + mi * 16 + rsel][kc];
            #pragma unroll
            for (int ni = 0; ni < NFR; ++ni)
                bfr[ni] = *(const bf16x8*)&Bs[wn * (BN / 2) + ni * 16 + rsel][kc];
            #pragma unroll
            for (int mi = 0; mi < 2; ++mi)
                #pragma unroll
                for (int ni = 0; ni < NFR; ++ni)
                    acc[mi][ni] = __builtin_amdgcn_mfma_f32_16x16x32_bf16(
                        bfr[ni], af[mi], acc[mi][ni], 0, 0, 0);
        }
        __syncthreads();
    }

    // swapped-operand C/D layout: row = rsel, cols = q*4 .. q*4+3 (uint2)
    #pragma unroll
    for (int mi = 0; mi < 2; ++mi) {
        const int gm = m0 + wm * 32 + mi * 16 + rsel;
        if (gm >= M) continue;
        const float d = dis[gm];
        #pragma unroll
        for (int ni = 0; ni < NFR; ++ni) {
            uint2 o;
            o.x = (uint_t)f2bf(acc[mi][ni][0] * d) | ((uint_t)f2bf(acc[mi][ni][1] * d) << 16);
            o.y = (uint_t)f2bf(acc[mi][ni][2] * d) | ((uint_t)f2bf(acc[mi][ni][3] * d) << 16);
            *(uint2*)(C + (size_t)gm * ldc + wn * (BN / 2) + ni * 16 + q * 4) = o;
        }
    }
}

// ---------------------------- aggregation ---------------------------------
// h rows pre-scaled (h' = dis*h). 4 nodes per wave, 16 lanes per node: each
// group covers the full 256B row (lane = 16B chunk = 8 bf16). Per iteration a
// group consumes 8 of its node's edges (8 gathers in flight). No cross-lane
// merge; prologue/epilogue/store run with all 64 lanes productive.
template <int F>
__global__ void aggregate128_kernel(const ushort_t* __restrict__ h, const int* __restrict__ row_start,
                                    const int* __restrict__ csr_src,
                                    const float* __restrict__ dis, const float* __restrict__ bias,
                                    ushort_t* __restrict__ out, int n) {
    const int lane = threadIdx.x & 63;
    const int grp  = lane >> 4;                     // node-group within wave
    const int node = blockIdx.x * 16 + (int)(threadIdx.x >> 6) * 4 + grp;
    if (node >= n) return;
    const uint_t fbb = (uint_t)(lane & 15) << 4;    // byte offset within row
    const char* hb = (const char*)h;
    float a[8];
    #pragma unroll
    for (int j = 0; j < 8; ++j) a[j] = 0.f;

    int i = row_start[node];
    const int end = row_start[node + 1];

#define LOADR(S) (*(const uint4*)(hb + (((uint_t)(S) << 8) + fbb)))
#define ACC8(U)                                                     \
    do {                                                            \
        a[0] += bflo((U).x); a[1] += bfhi((U).x);                   \
        a[2] += bflo((U).y); a[3] += bfhi((U).y);                   \
        a[4] += bflo((U).z); a[5] += bfhi((U).z);                   \
        a[6] += bflo((U).w); a[7] += bfhi((U).w);                   \
    } while (0)

    for (; i + 8 <= end; i += 8) {                  // 8 gathers in flight
        int s0 = csr_src[i];
        int s1 = csr_src[i + 1];
        int s2 = csr_src[i + 2];
        int s3 = csr_src[i + 3];
        int s4 = csr_src[i + 4];
        int s5 = csr_src[i + 5];
        int s6 = csr_src[i + 6];
        int s7 = csr_src[i + 7];
        uint4 u0 = LOADR(s0);
        uint4 u1 = LOADR(s1);
        uint4 u2 = LOADR(s2);
        uint4 u3 = LOADR(s3);
        uint4 u4 = LOADR(s4);
        uint4 u5 = LOADR(s5);
        uint4 u6 = LOADR(s6);
        uint4 u7 = LOADR(s7);
        ACC8(u0); ACC8(u1); ACC8(u2); ACC8(u3);
        ACC8(u4); ACC8(u5); ACC8(u6); ACC8(u7);
    }
    for (; i + 4 <= end; i += 4) {
        int s0 = csr_src[i];
        int s1 = csr_src[i + 1];
        int s2 = csr_src[i + 2];
        int s3 = csr_src[i + 3];
        uint4 u0 = LOADR(s0);
        uint4 u1 = LOADR(s1);
        uint4 u2 = LOADR(s2);
        uint4 u3 = LOADR(s3);
        ACC8(u0); ACC8(u1); ACC8(u2); ACC8(u3);
    }
    for (; i < end; ++i) {
        uint4 u = LOADR(csr_src[i]);
        ACC8(u);
    }
    {
        uint4 su = LOADR(node);                     // self-loop (pre-scaled)
        ACC8(su);
    }
    float dn = dis[node];
    const int fb = (lane & 15) * 8;
    #pragma unroll
    for (int j = 0; j < 8; ++j) {
        float b = (fb + j < F) ? bias[fb + j] : 0.f;
        float v = a[j] * dn + b;
        v = (v > 0.f) ? v : 0.1f * v;
        if (fb + j >= F) v = 0.f;                   // keep K-padding exactly zero
        a[j] = v;
    }
    uint4 o;
    o.x = (uint_t)f2bf(a[0]) | ((uint_t)f2bf(a[1]) << 16);
    o.y = (uint_t)f2bf(a[2]) | ((uint_t)f2bf(a[3]) << 16);
    o.z = (uint_t)f2bf(a[4]) | ((uint_t)f2bf(a[5]) << 16);
    o.w = (uint_t)f2bf(a[6]) | ((uint_t)f2bf(a[7]) << 16);
    *(uint4*)((char*)out + (((uint_t)node << 8) + fbb)) = o;
#undef ACC8
#undef LOADR
}

// F=32, h pre-scaled: 16-lane group per node (2 features/lane), 4 nodes/wave
__global__ void aggregate32_kernel(const ushort_t* __restrict__ h, const int* __restrict__ row_start,
                                   const int* __restrict__ csr_src,
                                   const float* __restrict__ dis, const float* __restrict__ bias,
                                   ushort_t* __restrict__ out, int n) {
    int lane16 = threadIdx.x & 15;
    int node = blockIdx.x * (blockDim.x >> 4) + (threadIdx.x >> 4);
    if (node >= n) return;
    const uint_t fbb = (uint_t)lane16 << 2;        // byte offset within 64B row
    const char* hb = (const char*)h;
#define LOADR32(S) (*(const uint_t*)(hb + (((uint_t)(S) << 6) + fbb)))
    uint_t v = LOADR32(node);
    float acc0 = bflo(v);               // self-loop (pre-scaled)
    float acc1 = bfhi(v);
    int i = row_start[node], end = row_start[node + 1];
    for (; i + 4 <= end; i += 4) {
        uint_t u0 = LOADR32(csr_src[i]);
        uint_t u1 = LOADR32(csr_src[i + 1]);
        uint_t u2 = LOADR32(csr_src[i + 2]);
        uint_t u3 = LOADR32(csr_src[i + 3]);
        acc0 += bflo(u0) + bflo(u1) + bflo(u2) + bflo(u3);
        acc1 += bfhi(u0) + bfhi(u1) + bfhi(u2) + bfhi(u3);
    }
    for (; i < end; ++i) {
        uint_t u = LOADR32(csr_src[i]);
        acc0 += bflo(u); acc1 += bfhi(u);
    }
#undef LOADR32
    float dn = dis[node];
    const int f0 = 2 * lane16;
    acc0 = acc0 * dn + bias[f0];
    acc1 = acc1 * dn + bias[f0 + 1];
    acc0 = (acc0 > 0.f) ? acc0 : 0.1f * acc0;
    acc1 = (acc1 > 0.f) ? acc1 : 0.1f * acc1;
    uint_t o = (uint_t)f2bf(acc0) | ((uint_t)f2bf(acc1) << 16);
    *(uint_t*)((char*)out + (((uint_t)node << 6) + fbb)) = o;
}

// layer 4 GEMM: [N x 32] bf16 @ [32 x 2] fp32 -> fp32, pre-scaled by dis[node]
__global__ void gemm32x2_kernel(const ushort_t* __restrict__ H, const float* __restrict__ W4,
                                const float* __restrict__ dis, float* __restrict__ C, int n) {
    int node = blockIdx.x * blockDim.x + threadIdx.x;
    if (node >= n) return;
    const uint_t* row = (const uint_t*)(H + (size_t)node * 32);
    float a0 = 0.f, a1 = 0.f;
    #pragma unroll
    for (int k2 = 0; k2 < 16; ++k2) {
        uint_t u = row[k2];
        float x0 = bflo(u), x1 = bfhi(u);
        int k = 2 * k2;
        a0 += x0 * W4[k * 2]     + x1 * W4[(k + 1) * 2];
        a1 += x0 * W4[k * 2 + 1] + x1 * W4[(k + 1) * 2 + 1];
    }
    float d = dis[node];
    C[2 * (size_t)node]     = a0 * d;
    C[2 * (size_t)node + 1] = a1 * d;
}

// final aggregation (F=2, h pre-scaled) + bias + softmax, one thread per node
__global__ void aggregate2_softmax_kernel(const float* __restrict__ h, const int* __restrict__ row_start,
                                          const int* __restrict__ csr_src,
                                          const float* __restrict__ dis, const float* __restrict__ bias,
                                          float* __restrict__ out, int n) {
    int node = blockIdx.x * blockDim.x + threadIdx.x;
    if (node >= n) return;
    const char* hb = (const char*)h;
    float a0 = h[2 * (size_t)node];
    float a1 = h[2 * (size_t)node + 1];
    int beg = row_start[node], end = row_start[node + 1];
    for (int i = beg; i < end; ++i) {
        uint_t off = (uint_t)csr_src[i] << 3;
        float2 u = *(const float2*)(hb + off);
        a0 += u.x;
        a1 += u.y;
    }
    float dn = dis[node];
    a0 = a0 * dn + bias[0];
    a1 = a1 * dn + bias[1];
    float m  = fmaxf(a0, a1);
    float e0 = expf(a0 - m), e1 = expf(a1 - m);
    float inv = 1.f / (e0 + e1);
    out[2 * (size_t)node]     = e0 * inv;
    out[2 * (size_t)node + 1] = e1 * inv;
}

// ---------------------------------------------------------------------------

extern "C" void kernel_launch(void* const* d_in, const int* in_sizes, int n_in,
                              void* d_out, int out_size, void* d_ws, size_t ws_size,
                              hipStream_t stream) {
    const float* x  = (const float*)d_in[0];
    const int*   ei = (const int*)d_in[1];
    const float* W1 = (const float*)d_in[2];
    const float* b1 = (const float*)d_in[3];
    const float* W2 = (const float*)d_in[4];
    const float* b2 = (const float*)d_in[5];
    const float* W3 = (const float*)d_in[6];
    const float* b3 = (const float*)d_in[7];
    const float* W4 = (const float*)d_in[8];
    const float* b4 = (const float*)d_in[9];

    const int N = in_sizes[0] / 256;
    const int E = in_sizes[1] / 2;
    const int* srcA = ei;
    const int* dstA = ei + E;
    const int nbkt = (N + 255) >> BKT_SHIFT;

    char* ws = (char*)d_ws;
    size_t off = 0;
    auto alloc = [&](size_t bytes) {
        void* p = ws + off;
        off = (off + bytes + 255) & ~(size_t)255;
        return p;
    };
    float*    dis        = (float*)alloc((size_t)N * 4);
    int*      row_start  = (int*)alloc((size_t)(N + 1) * 4);
    int*      bkt_cursor = (int*)alloc(512 * 4);
    int*      bkt_base   = (int*)alloc(512 * 4);
    int*      csr_src    = (int*)alloc((size_t)E * 4);
    uint_t*   staging    = (uint_t*)alloc((size_t)nbkt * BKT_CAP * 4);
    ushort_t* bufA       = (ushort_t*)alloc((size_t)N * 128 * 2);
    ushort_t* bufB       = (ushort_t*)alloc((size_t)N * 128 * 2);
    float*    C4         = (float*)alloc((size_t)N * 2 * 4);
    ushort_t* Wt1        = (ushort_t*)alloc((size_t)128 * 256 * 2);
    ushort_t* Wt2        = (ushort_t*)alloc((size_t)128 * 128 * 2);
    ushort_t* Wt3        = (ushort_t*)alloc((size_t)64 * 128 * 2);
    (void)ws_size;

    hipMemsetAsync(bkt_cursor, 0, 512 * 4, stream);

    // graph prep (bucketed, fused, packed staging)
    bin_kernel<<<(E + BIN_CHUNK - 1) / BIN_CHUNK, 256, 0, stream>>>(
        srcA, dstA, bkt_cursor, staging, E, nbkt);
    bucket_scan_kernel<<<1, 512, 0, stream>>>(bkt_cursor, bkt_base, row_start, nbkt, N);
    csr_build2_kernel<<<nbkt, 256, 0, stream>>>(staging, bkt_cursor, bkt_base,
                                                row_start, dis, csr_src, N);

    // weight transposes (bf16, padded)
    wt_all_kernel<<<(57344 + 255) / 256, 256, 0, stream>>>(W1, W2, W3, Wt1, Wt2, Wt3);

    const int gx = (N + 63) / 64;            // 64 rows per block
    const int aggBlocks128 = (N + 15) / 16;  // 4 waves/block, 4 nodes/wave
    const int aggBlocks32  = (N + 15) / 16;  // 16 nodes/block

    // layer 1: 256 -> 128, fp32 A converted in-staging (x read once)
    gemm_tile<true, 4><<<gx, 256, 0, stream>>>(x, Wt1, bufA, dis, N, 256, 256, 256, 128);
    aggregate128_kernel<128><<<aggBlocks128, 256, 0, stream>>>(
        bufA, row_start, csr_src, dis, b1, bufB, N);
    // layer 2: 128 -> 100 (padded to 128)
    gemm_tile<false, 4><<<gx, 256, 0, stream>>>(bufB, Wt2, bufA, dis, N, 128, 128, 128, 128);
    aggregate128_kernel<100><<<aggBlocks128, 256, 0, stream>>>(
        bufA, row_start, csr_src, dis, b2, bufB, N);
    // layer 3: 128(pad) -> 32 (BN=32)
    gemm_tile<false, 1><<<gx, 256, 0, stream>>>(bufB, Wt3, bufA, dis, N, 128, 128, 128, 32);
    aggregate32_kernel<<<aggBlocks32, 256, 0, stream>>>(
        bufA, row_start, csr_src, dis, b3, bufB, N);
    // layer 4: 32 -> 2, aggregate + softmax
    gemm32x2_kernel<<<(N + 255) / 256, 256, 0, stream>>>(bufB, W4, dis, C4, N);
    aggregate2_softmax_kernel<<<(N + 255) / 256, 256, 0, stream>>>(
        C4, row_start, csr_src, dis, b4, (float*)d_out, N);
}

// Round 15
// 279.043 us; speedup vs baseline: 1.3183x; 1.0003x over previous
//
#include <hip/hip_runtime.h>
#include <math.h>

// ---------------------------------------------------------------------------
// GCN: 4x (bf16-MFMA tiled GEMM (BM=64,BN=full,BK=64, 4 waves 2Mx2N,
//      LDS-staged; layer-1 converts fp32 A in-staging; epilogue pre-scales
//      rows by dis) -> pure-sum aggregation (+bias, lrelu)) -> softmax.
// Layer-2/3 intermediate rows packed to stride 112 (224B; cols>=112 never
// stored, cols 100..111 are exact zeros via zero-padded weights).
// Layer-4 GEMM (32->2) fused into aggregate32's epilogue (shfl reduce).
// Graph prep per call (fused, bucketed, packed-uint staging).
// out[n] = dis[n]*( sum_e h'[s] + h'[n] ) + b,  h'[r] = dis[r]*(h@W)[r]
// ---------------------------------------------------------------------------

typedef unsigned short ushort_t;
typedef unsigned int   uint_t;
typedef short  bf16x8 __attribute__((ext_vector_type(8)));
typedef float  f32x4  __attribute__((ext_vector_type(4)));

#define BKT_SHIFT 8               // 256 nodes per bucket
#define BKT_CAP   5120            // >= max edges per bucket (mean 4096, +16 sigma)
#define BIN_CHUNK 4096            // edges per bin workgroup

__device__ __forceinline__ ushort_t f2bf(float f) {
    union { float f; uint_t u; } v; v.f = f;
    uint_t u = v.u;
    u += 0x7fffu + ((u >> 16) & 1u);      // round-to-nearest-even
    return (ushort_t)(u >> 16);
}
__device__ __forceinline__ float bflo(uint_t u) {
    union { uint_t q; float f; } v; v.q = u << 16; return v.f;
}
__device__ __forceinline__ float bfhi(uint_t u) {
    union { uint_t q; float f; } v; v.q = u & 0xffff0000u; return v.f;
}

// ------------------------------- graph prep -------------------------------

// Edges register-cached across phases; staging entry = (src<<8)|dst_local.
__global__ __launch_bounds__(256) void bin_kernel(const int* __restrict__ srcArr,
                                                  const int* __restrict__ dstArr,
                                                  int* __restrict__ bkt_cursor,
                                                  uint_t* __restrict__ staging,
                                                  int E, int nb) {
    __shared__ int hist[512];
    __shared__ int base[512];
    for (int b = threadIdx.x; b < 512; b += 256) hist[b] = 0;
    __syncthreads();
    const int e0 = blockIdx.x * BIN_CHUNK;
    int sv[16], dv[16];
    #pragma unroll
    for (int k = 0; k < 16; ++k) {
        int e = e0 + k * 256 + threadIdx.x;
        if (e < E) {
            sv[k] = srcArr[e];
            dv[k] = dstArr[e];
            atomicAdd(&hist[dv[k] >> BKT_SHIFT], 1);
        } else {
            sv[k] = 0; dv[k] = -1;
        }
    }
    __syncthreads();
    for (int b = threadIdx.x; b < nb; b += 256) {
        int h = hist[b];
        base[b] = h ? atomicAdd(&bkt_cursor[b], h) : 0;
    }
    __syncthreads();
    for (int b = threadIdx.x; b < 512; b += 256) hist[b] = 0;  // reuse as cursor
    __syncthreads();
    #pragma unroll
    for (int k = 0; k < 16; ++k) {
        if (dv[k] >= 0) {
            int b = dv[k] >> BKT_SHIFT;
            int p = atomicAdd(&hist[b], 1);
            int idx = base[b] + p;
            if (idx < BKT_CAP)
                staging[(size_t)b * BKT_CAP + idx] =
                    ((uint_t)sv[k] << 8) | (uint_t)(dv[k] & 255);
        }
    }
}

// single block: exclusive scan of bucket totals -> bkt_base; row_start[n]=E
__global__ __launch_bounds__(512) void bucket_scan_kernel(const int* __restrict__ bkt_cursor,
                                                          int* __restrict__ bkt_base,
                                                          int* __restrict__ row_start,
                                                          int nbkt, int n) {
    __shared__ int buf[512];
    int v = ((int)threadIdx.x < nbkt) ? min(bkt_cursor[threadIdx.x], BKT_CAP) : 0;
    buf[threadIdx.x] = v;
    __syncthreads();
    for (int off = 1; off < 512; off <<= 1) {
        int t = (threadIdx.x >= (unsigned)off) ? buf[threadIdx.x - off] : 0;
        __syncthreads();
        buf[threadIdx.x] += t;
        __syncthreads();
    }
    if ((int)threadIdx.x < nbkt) bkt_base[threadIdx.x] = buf[threadIdx.x] - v;
    if ((int)threadIdx.x == nbkt - 1) row_start[n] = buf[threadIdx.x];
}

// fused: per-bucket degree histogram -> LDS scan -> row_start & dis writes ->
// LDS scatter -> coalesced csr flush  (packed-uint staging)
__global__ __launch_bounds__(256) void csr_build2_kernel(const uint_t* __restrict__ staging,
                                                         const int* __restrict__ bkt_cursor,
                                                         const int* __restrict__ bkt_base,
                                                         int* __restrict__ row_start,
                                                         float* __restrict__ dis,
                                                         int* __restrict__ csr_src, int n) {
    __shared__ int cnt[256];
    __shared__ int buf[256];
    __shared__ int rsS[256];
    __shared__ int seg[BKT_CAP];
    const int t  = threadIdx.x;
    const int b  = blockIdx.x;
    const int lo = b << BKT_SHIFT;
    const int nl = min(256, n - lo);
    cnt[t] = 0;
    __syncthreads();
    const int cntE = min(bkt_cursor[b], BKT_CAP);
    for (int e = t; e < cntE; e += 256) {
        uint_t p = staging[(size_t)b * BKT_CAP + e];
        atomicAdd(&cnt[p & 255u], 1);
    }
    __syncthreads();
    const int v = cnt[t];
    buf[t] = v;
    __syncthreads();
    for (int off = 1; off < 256; off <<= 1) {
        int tt = (t >= off) ? buf[t - off] : 0;
        __syncthreads();
        buf[t] += tt;
        __syncthreads();
    }
    rsS[t] = buf[t] - v;                      // exclusive within-bucket
    const int sbase = bkt_base[b];
    if (t < nl) {
        row_start[lo + t] = sbase + (buf[t] - v);
        dis[lo + t] = rsqrtf((float)(v + 1));
    }
    cnt[t] = 0;                               // reuse as scatter cursor
    __syncthreads();
    for (int e = t; e < cntE; e += 256) {
        uint_t p = staging[(size_t)b * BKT_CAP + e];
        int ln = (int)(p & 255u);
        int q  = atomicAdd(&cnt[ln], 1);
        seg[rsS[ln] + q] = (int)(p >> 8);
    }
    __syncthreads();
    for (int i = t; i < cntE; i += 256) csr_src[sbase + i] = seg[i];
}

// -------------------- weight transposes (one kernel) -----------------------
__global__ void wt_all_kernel(const float* __restrict__ W1, const float* __restrict__ W2,
                              const float* __restrict__ W3,
                              ushort_t* __restrict__ Wt1, ushort_t* __restrict__ Wt2,
                              ushort_t* __restrict__ Wt3) {
    int idx = blockIdx.x * blockDim.x + threadIdx.x;
    if (idx < 32768) {
        int nn = idx >> 8, k = idx & 255;
        Wt1[idx] = f2bf(W1[(size_t)k * 128 + nn]);
    } else if (idx < 49152) {
        int j = idx - 32768;
        int nn = j >> 7, k = j & 127;
        float v = (nn < 100) ? W2[(size_t)k * 100 + nn] : 0.f;
        Wt2[j] = f2bf(v);
    } else if (idx < 57344) {
        int j = idx - 49152;
        int nn = j >> 7, k = j & 127;
        float v = (k < 100 && nn < 32) ? W3[(size_t)k * 32 + nn] : 0.f;
        Wt3[j] = f2bf(v);
    }
}

// --------------------------- tiled MFMA GEMM -------------------------------
// C[M x <ldc stored cols>] (bf16) = dis[row] * (A[M x K] @ Wt[BN x K]^T).
// BM=64, BK=64, 4 waves (2M x 2N). LDS-staged A and B tiles (+8 pad).
// A_FP32: fp32 A converted to bf16 during staging. Store guard col<ldc
// supports packed output strides (ldc < BN). A rows may be read past K
// into the next row iff Wt is zero-padded there (layer 3, lda=112,K=128).
template <bool A_FP32, int NFR>
__global__ __launch_bounds__(256) void gemm_tile(const void* __restrict__ Av,
                                                 const ushort_t* __restrict__ Bt,
                                                 ushort_t* __restrict__ C,
                                                 const float* __restrict__ dis,
                                                 int M, int K, int lda, int ldb, int ldc) {
    constexpr int BN = NFR * 32;
    __shared__ __attribute__((aligned(16))) ushort_t As[64][72];   // +8 pad
    __shared__ __attribute__((aligned(16))) ushort_t Bs[BN][72];

    const int t    = threadIdx.x;
    const int lane = t & 63;
    const int w    = t >> 6;
    const int wm   = w >> 1, wn = w & 1;
    const int m0   = blockIdx.x * 64;
    const int rsel = lane & 15;
    const int q    = lane >> 4;

    f32x4 acc[2][NFR];
    #pragma unroll
    for (int mi = 0; mi < 2; ++mi)
        #pragma unroll
        for (int ni = 0; ni < NFR; ++ni) acc[mi][ni] = (f32x4){0.f, 0.f, 0.f, 0.f};

    const int srow = t >> 3;          // 0..31
    const int scol = (t & 7) * 8;     // 0..56

    for (int k0 = 0; k0 < K; k0 += 64) {
        #pragma unroll
        for (int it = 0; it < 2; ++it) {            // A tile 64x64
            int r = srow + it * 32;
            int gm = m0 + r;
            bf16x8 v = {0, 0, 0, 0, 0, 0, 0, 0};
            if (gm < M) {
                if (A_FP32) {
                    const float* A = (const float*)Av;
                    const float4 f0 = *(const float4*)(A + (size_t)gm * lda + k0 + scol);
                    const float4 f1 = *(const float4*)(A + (size_t)gm * lda + k0 + scol + 4);
                    ushort_t o[8] = { f2bf(f0.x), f2bf(f0.y), f2bf(f0.z), f2bf(f0.w),
                                      f2bf(f1.x), f2bf(f1.y), f2bf(f1.z), f2bf(f1.w) };
                    v = *(const bf16x8*)o;
                } else {
                    const ushort_t* A = (const ushort_t*)Av;
                    v = *(const bf16x8*)(A + (size_t)gm * lda + k0 + scol);
                }
            }
            *(bf16x8*)&As[r][scol] = v;
        }
        #pragma unroll
        for (int it = 0; it < BN / 32; ++it) {      // B tile BNx64
            int r = srow + it * 32;
            bf16x8 v = *(const bf16x8*)(Bt + (size_t)r * ldb + k0 + scol);
            *(bf16x8*)&Bs[r][scol] = v;
        }
        __syncthreads();
        #pragma unroll
        for (int ks = 0; ks < 2; ++ks) {
            const int kc = ks * 32 + q * 8;
            bf16x8 af[2], bfr[NFR];
            #pragma unroll
            for (int mi = 0; mi < 2; ++mi)
                af[mi] = *(const bf16x8*)&As[wm * 32 + mi * 16 + rsel][kc];
            #pragma unroll
            for (int ni = 0; ni < NFR; ++ni)
                bfr[ni] = *(const bf16x8*)&Bs[wn * (BN / 2) + ni * 16 + rsel][kc];
            #pragma unroll
            for (int mi = 0; mi < 2; ++mi)
                #pragma unroll
                for (int ni = 0; ni < NFR; ++ni)
                    acc[mi][ni] = __builtin_amdgcn_mfma_f32_16x16x32_bf16(
                        bfr[ni], af[mi], acc[mi][ni], 0, 0, 0);
        }
        __syncthreads();
    }

    // swapped-operand C/D layout: row = rsel, cols = cb .. cb+3 (uint2)
    #pragma unroll
    for (int mi = 0; mi < 2; ++mi) {
        const int gm = m0 + wm * 32 + mi * 16 + rsel;
        if (gm >= M) continue;
        const float d = dis[gm];
        #pragma unroll
        for (int ni = 0; ni < NFR; ++ni) {
            const int cb = wn * (BN / 2) + ni * 16 + q * 4;
            if (cb >= ldc) continue;               // packed-stride guard
            uint2 o;
            o.x = (uint_t)f2bf(acc[mi][ni][0] * d) | ((uint_t)f2bf(acc[mi][ni][1] * d) << 16);
            o.y = (uint_t)f2bf(acc[mi][ni][2] * d) | ((uint_t)f2bf(acc[mi][ni][3] * d) << 16);
            *(uint2*)(C + (size_t)gm * ldc + cb) = o;
        }
    }
}

// ---------------------------- aggregation ---------------------------------
// h rows pre-scaled (h' = dis*h), row byte stride = CHUNKS*16. 4 nodes per
// wave, CHUNKS lanes per 16-lane group active (lane = 16B chunk). 8 gathers
// in flight per iter. No cross-lane merge; epilogue all lanes productive.
template <int F, int CHUNKS>
__global__ void aggregate128_kernel(const ushort_t* __restrict__ h, const int* __restrict__ row_start,
                                    const int* __restrict__ csr_src,
                                    const float* __restrict__ dis, const float* __restrict__ bias,
                                    ushort_t* __restrict__ out, int n) {
    const int lane = threadIdx.x & 63;
    const int grp  = lane >> 4;                     // node-group within wave
    const int node = blockIdx.x * 16 + (int)(threadIdx.x >> 6) * 4 + grp;
    if (node >= n) return;
    const int l16 = lane & 15;
    if (l16 >= CHUNKS) return;
    const uint_t STRIDE = (uint_t)CHUNKS * 16u;     // row byte stride
    const uint_t fbb = (uint_t)l16 << 4;            // byte offset within row
    const char* hb = (const char*)h;
    float a[8];
    #pragma unroll
    for (int j = 0; j < 8; ++j) a[j] = 0.f;

    int i = row_start[node];
    const int end = row_start[node + 1];

#define LOADR(S) (*(const uint4*)(hb + ((uint_t)(S) * STRIDE + fbb)))
#define ACC8(U)                                                     \
    do {                                                            \
        a[0] += bflo((U).x); a[1] += bfhi((U).x);                   \
        a[2] += bflo((U).y); a[3] += bfhi((U).y);                   \
        a[4] += bflo((U).z); a[5] += bfhi((U).z);                   \
        a[6] += bflo((U).w); a[7] += bfhi((U).w);                   \
    } while (0)

    for (; i + 8 <= end; i += 8) {                  // 8 gathers in flight
        int s0 = csr_src[i];
        int s1 = csr_src[i + 1];
        int s2 = csr_src[i + 2];
        int s3 = csr_src[i + 3];
        int s4 = csr_src[i + 4];
        int s5 = csr_src[i + 5];
        int s6 = csr_src[i + 6];
        int s7 = csr_src[i + 7];
        uint4 u0 = LOADR(s0);
        uint4 u1 = LOADR(s1);
        uint4 u2 = LOADR(s2);
        uint4 u3 = LOADR(s3);
        uint4 u4 = LOADR(s4);
        uint4 u5 = LOADR(s5);
        uint4 u6 = LOADR(s6);
        uint4 u7 = LOADR(s7);
        ACC8(u0); ACC8(u1); ACC8(u2); ACC8(u3);
        ACC8(u4); ACC8(u5); ACC8(u6); ACC8(u7);
    }
    for (; i + 4 <= end; i += 4) {
        int s0 = csr_src[i];
        int s1 = csr_src[i + 1];
        int s2 = csr_src[i + 2];
        int s3 = csr_src[i + 3];
        uint4 u0 = LOADR(s0);
        uint4 u1 = LOADR(s1);
        uint4 u2 = LOADR(s2);
        uint4 u3 = LOADR(s3);
        ACC8(u0); ACC8(u1); ACC8(u2); ACC8(u3);
    }
    for (; i < end; ++i) {
        uint4 u = LOADR(csr_src[i]);
        ACC8(u);
    }
    {
        uint4 su = LOADR(node);                     // self-loop (pre-scaled)
        ACC8(su);
    }
    float dn = dis[node];
    const int fb = l16 * 8;
    #pragma unroll
    for (int j = 0; j < 8; ++j) {
        float b = (fb + j < F) ? bias[fb + j] : 0.f;
        float v = a[j] * dn + b;
        v = (v > 0.f) ? v : 0.1f * v;
        if (fb + j >= F) v = 0.f;                   // keep K-padding exactly zero
        a[j] = v;
    }
    uint4 o;
    o.x = (uint_t)f2bf(a[0]) | ((uint_t)f2bf(a[1]) << 16);
    o.y = (uint_t)f2bf(a[2]) | ((uint_t)f2bf(a[3]) << 16);
    o.z = (uint_t)f2bf(a[4]) | ((uint_t)f2bf(a[5]) << 16);
    o.w = (uint_t)f2bf(a[6]) | ((uint_t)f2bf(a[7]) << 16);
    *(uint4*)((char*)out + ((uint_t)node * STRIDE + fbb)) = o;
#undef ACC8
#undef LOADR
}

// F=32 aggregation fused with layer-4 GEMM (32->2): 16-lane group per node
// (2 features/lane), 4 nodes/wave. After bias+lrelu, each lane computes its
// 2x2 partial product with W4, 4-round shfl_xor reduce, lane0 writes
// C4[node] = dis[node] * (h3[node] @ W4).
__global__ void aggregate32_w4_kernel(const ushort_t* __restrict__ h, const int* __restrict__ row_start,
                                      const int* __restrict__ csr_src,
                                      const float* __restrict__ dis, const float* __restrict__ bias,
                                      const float* __restrict__ W4, float* __restrict__ C4, int n) {
    int lane16 = threadIdx.x & 15;
    int node = blockIdx.x * (blockDim.x >> 4) + (threadIdx.x >> 4);
    if (node >= n) return;
    const uint_t fbb = (uint_t)lane16 << 2;        // byte offset within 64B row
    const char* hb = (const char*)h;
#define LOADR32(S) (*(const uint_t*)(hb + (((uint_t)(S) << 6) + fbb)))
    uint_t v = LOADR32(node);
    float acc0 = bflo(v);               // self-loop (pre-scaled)
    float acc1 = bfhi(v);
    int i = row_start[node], end = row_start[node + 1];
    for (; i + 4 <= end; i += 4) {
        uint_t u0 = LOADR32(csr_src[i]);
        uint_t u1 = LOADR32(csr_src[i + 1]);
        uint_t u2 = LOADR32(csr_src[i + 2]);
        uint_t u3 = LOADR32(csr_src[i + 3]);
        acc0 += bflo(u0) + bflo(u1) + bflo(u2) + bflo(u3);
        acc1 += bfhi(u0) + bfhi(u1) + bfhi(u2) + bfhi(u3);
    }
    for (; i < end; ++i) {
        uint_t u = LOADR32(csr_src[i]);
        acc0 += bflo(u); acc1 += bfhi(u);
    }
#undef LOADR32
    float dn = dis[node];
    const int f0 = 2 * lane16;
    acc0 = acc0 * dn + bias[f0];
    acc1 = acc1 * dn + bias[f0 + 1];
    acc0 = (acc0 > 0.f) ? acc0 : 0.1f * acc0;
    acc1 = (acc1 > 0.f) ? acc1 : 0.1f * acc1;
    // fused 32->2 GEMM: W4 row-major [32][2]; lane covers rows f0, f0+1
    const float4 w = *(const float4*)(W4 + 4 * lane16);  // {W4[f0][0],W4[f0][1],W4[f1][0],W4[f1][1]}
    float p0 = acc0 * w.x + acc1 * w.z;
    float p1 = acc0 * w.y + acc1 * w.w;
    #pragma unroll
    for (int m = 1; m < 16; m <<= 1) {
        p0 += __shfl_xor(p0, m);
        p1 += __shfl_xor(p1, m);
    }
    if (lane16 == 0) {
        float2 o = { p0 * dn, p1 * dn };
        *(float2*)(C4 + 2 * (size_t)node) = o;
    }
}

// final aggregation (F=2, h pre-scaled) + bias + softmax, one thread per node
__global__ void aggregate2_softmax_kernel(const float* __restrict__ h, const int* __restrict__ row_start,
                                          const int* __restrict__ csr_src,
                                          const float* __restrict__ dis, const float* __restrict__ bias,
                                          float* __restrict__ out, int n) {
    int node = blockIdx.x * blockDim.x + threadIdx.x;
    if (node >= n) return;
    const char* hb = (const char*)h;
    float a0 = h[2 * (size_t)node];
    float a1 = h[2 * (size_t)node + 1];
    int beg = row_start[node], end = row_start[node + 1];
    for (int i = beg; i < end; ++i) {
        uint_t off = (uint_t)csr_src[i] << 3;
        float2 u = *(const float2*)(hb + off);
        a0 += u.x;
        a1 += u.y;
    }
    float dn = dis[node];
    a0 = a0 * dn + bias[0];
    a1 = a1 * dn + bias[1];
    float m  = fmaxf(a0, a1);
    float e0 = expf(a0 - m), e1 = expf(a1 - m);
    float inv = 1.f / (e0 + e1);
    out[2 * (size_t)node]     = e0 * inv;
    out[2 * (size_t)node + 1] = e1 * inv;
}

// ---------------------------------------------------------------------------

extern "C" void kernel_launch(void* const* d_in, const int* in_sizes, int n_in,
                              void* d_out, int out_size, void* d_ws, size_t ws_size,
                              hipStream_t stream) {
    const float* x  = (const float*)d_in[0];
    const int*   ei = (const int*)d_in[1];
    const float* W1 = (const float*)d_in[2];
    const float* b1 = (const float*)d_in[3];
    const float* W2 = (const float*)d_in[4];
    const float* b2 = (const float*)d_in[5];
    const float* W3 = (const float*)d_in[6];
    const float* b3 = (const float*)d_in[7];
    const float* W4 = (const float*)d_in[8];
    const float* b4 = (const float*)d_in[9];

    const int N = in_sizes[0] / 256;
    const int E = in_sizes[1] / 2;
    const int* srcA = ei;
    const int* dstA = ei + E;
    const int nbkt = (N + 255) >> BKT_SHIFT;

    char* ws = (char*)d_ws;
    size_t off = 0;
    auto alloc = [&](size_t bytes) {
        void* p = ws + off;
        off = (off + bytes + 255) & ~(size_t)255;
        return p;
    };
    float*    dis        = (float*)alloc((size_t)N * 4);
    int*      row_start  = (int*)alloc((size_t)(N + 1) * 4);
    int*      bkt_cursor = (int*)alloc(512 * 4);
    int*      bkt_base   = (int*)alloc(512 * 4);
    int*      csr_src    = (int*)alloc((size_t)E * 4);
    uint_t*   staging    = (uint_t*)alloc((size_t)nbkt * BKT_CAP * 4);
    ushort_t* bufA       = (ushort_t*)alloc((size_t)N * 128 * 2);
    ushort_t* bufB       = (ushort_t*)alloc((size_t)N * 128 * 2);
    float*    C4         = (float*)alloc((size_t)N * 2 * 4);
    ushort_t* Wt1        = (ushort_t*)alloc((size_t)128 * 256 * 2);
    ushort_t* Wt2        = (ushort_t*)alloc((size_t)128 * 128 * 2);
    ushort_t* Wt3        = (ushort_t*)alloc((size_t)64 * 128 * 2);
    (void)ws_size;

    hipMemsetAsync(bkt_cursor, 0, 512 * 4, stream);

    // graph prep (bucketed, fused, packed staging)
    bin_kernel<<<(E + BIN_CHUNK - 1) / BIN_CHUNK, 256, 0, stream>>>(
        srcA, dstA, bkt_cursor, staging, E, nbkt);
    bucket_scan_kernel<<<1, 512, 0, stream>>>(bkt_cursor, bkt_base, row_start, nbkt, N);
    csr_build2_kernel<<<nbkt, 256, 0, stream>>>(staging, bkt_cursor, bkt_base,
                                                row_start, dis, csr_src, N);

    // weight transposes (bf16, padded)
    wt_all_kernel<<<(57344 + 255) / 256, 256, 0, stream>>>(W1, W2, W3, Wt1, Wt2, Wt3);

    const int gx = (N + 63) / 64;            // 64 rows per block
    const int aggBlocks = (N + 15) / 16;     // 4 waves/block, 4 nodes/wave (or 16 nodes)

    // layer 1: 256 -> 128, fp32 A converted in-staging (x read once)
    gemm_tile<true, 4><<<gx, 256, 0, stream>>>(x, Wt1, bufA, dis, N, 256, 256, 256, 128);
    aggregate128_kernel<128, 16><<<aggBlocks, 256, 0, stream>>>(
        bufA, row_start, csr_src, dis, b1, bufB, N);
    // layer 2: 128 -> 100, packed output stride 112 (cols 100..111 zero)
    gemm_tile<false, 4><<<gx, 256, 0, stream>>>(bufB, Wt2, bufA, dis, N, 128, 128, 128, 112);
    aggregate128_kernel<100, 14><<<aggBlocks, 256, 0, stream>>>(
        bufA, row_start, csr_src, dis, b2, bufB, N);
    // layer 3: 112-packed -> 32 (lda=112, K=128 overlap-read; Wt3 zero-padded)
    gemm_tile<false, 1><<<gx, 256, 0, stream>>>(bufB, Wt3, bufA, dis, N, 128, 112, 128, 32);
    // layer 3 aggregation + fused layer-4 GEMM (32 -> 2)
    aggregate32_w4_kernel<<<aggBlocks, 256, 0, stream>>>(
        bufA, row_start, csr_src, dis, b3, W4, C4, N);
    // final aggregation + softmax
    aggregate2_softmax_kernel<<<(N + 255) / 256, 256, 0, stream>>>(
        C4, row_start, csr_src, dis, b4, (float*)d_out, N);
}

// Round 16
// 277.413 us; speedup vs baseline: 1.3260x; 1.0059x over previous
//
#include <hip/hip_runtime.h>
#include <math.h>

// ---------------------------------------------------------------------------
// GCN: 4x (bf16-MFMA tiled GEMM (BM=64,BN=full,BK=64, 4 waves 2Mx2N,
//      LDS-staged; layer-1 converts fp32 A in-staging; epilogue pre-scales
//      rows by dis) -> pure-sum aggregation (+bias, lrelu)) -> softmax.
// All intermediate rows stride 128 (256B, cache-line aligned — packing to
// 112 measured SLOWER: misaligned rows fetch extra sectors, round 15).
// Layer-4 GEMM (32->2) fused into aggregate32's epilogue (shfl reduce).
// Graph prep per call (fused, bucketed, packed-uint staging).
// out[n] = dis[n]*( sum_e h'[s] + h'[n] ) + b,  h'[r] = dis[r]*(h@W)[r]
// ---------------------------------------------------------------------------

typedef unsigned short ushort_t;
typedef unsigned int   uint_t;
typedef short  bf16x8 __attribute__((ext_vector_type(8)));
typedef float  f32x4  __attribute__((ext_vector_type(4)));

#define BKT_SHIFT 8               // 256 nodes per bucket
#define BKT_CAP   5120            // >= max edges per bucket (mean 4096, +16 sigma)
#define BIN_CHUNK 4096            // edges per bin workgroup

__device__ __forceinline__ ushort_t f2bf(float f) {
    union { float f; uint_t u; } v; v.f = f;
    uint_t u = v.u;
    u += 0x7fffu + ((u >> 16) & 1u);      // round-to-nearest-even
    return (ushort_t)(u >> 16);
}
__device__ __forceinline__ float bflo(uint_t u) {
    union { uint_t q; float f; } v; v.q = u << 16; return v.f;
}
__device__ __forceinline__ float bfhi(uint_t u) {
    union { uint_t q; float f; } v; v.q = u & 0xffff0000u; return v.f;
}

// ------------------------------- graph prep -------------------------------

// Edges register-cached across phases; staging entry = (src<<8)|dst_local.
__global__ __launch_bounds__(256) void bin_kernel(const int* __restrict__ srcArr,
                                                  const int* __restrict__ dstArr,
                                                  int* __restrict__ bkt_cursor,
                                                  uint_t* __restrict__ staging,
                                                  int E, int nb) {
    __shared__ int hist[512];
    __shared__ int base[512];
    for (int b = threadIdx.x; b < 512; b += 256) hist[b] = 0;
    __syncthreads();
    const int e0 = blockIdx.x * BIN_CHUNK;
    int sv[16], dv[16];
    #pragma unroll
    for (int k = 0; k < 16; ++k) {
        int e = e0 + k * 256 + threadIdx.x;
        if (e < E) {
            sv[k] = srcArr[e];
            dv[k] = dstArr[e];
            atomicAdd(&hist[dv[k] >> BKT_SHIFT], 1);
        } else {
            sv[k] = 0; dv[k] = -1;
        }
    }
    __syncthreads();
    for (int b = threadIdx.x; b < nb; b += 256) {
        int h = hist[b];
        base[b] = h ? atomicAdd(&bkt_cursor[b], h) : 0;
    }
    __syncthreads();
    for (int b = threadIdx.x; b < 512; b += 256) hist[b] = 0;  // reuse as cursor
    __syncthreads();
    #pragma unroll
    for (int k = 0; k < 16; ++k) {
        if (dv[k] >= 0) {
            int b = dv[k] >> BKT_SHIFT;
            int p = atomicAdd(&hist[b], 1);
            int idx = base[b] + p;
            if (idx < BKT_CAP)
                staging[(size_t)b * BKT_CAP + idx] =
                    ((uint_t)sv[k] << 8) | (uint_t)(dv[k] & 255);
        }
    }
}

// single block: exclusive scan of bucket totals -> bkt_base; row_start[n]=E
__global__ __launch_bounds__(512) void bucket_scan_kernel(const int* __restrict__ bkt_cursor,
                                                          int* __restrict__ bkt_base,
                                                          int* __restrict__ row_start,
                                                          int nbkt, int n) {
    __shared__ int buf[512];
    int v = ((int)threadIdx.x < nbkt) ? min(bkt_cursor[threadIdx.x], BKT_CAP) : 0;
    buf[threadIdx.x] = v;
    __syncthreads();
    for (int off = 1; off < 512; off <<= 1) {
        int t = (threadIdx.x >= (unsigned)off) ? buf[threadIdx.x - off] : 0;
        __syncthreads();
        buf[threadIdx.x] += t;
        __syncthreads();
    }
    if ((int)threadIdx.x < nbkt) bkt_base[threadIdx.x] = buf[threadIdx.x] - v;
    if ((int)threadIdx.x == nbkt - 1) row_start[n] = buf[threadIdx.x];
}

// fused: per-bucket degree histogram -> LDS scan -> row_start & dis writes ->
// LDS scatter -> coalesced csr flush  (packed-uint staging)
__global__ __launch_bounds__(256) void csr_build2_kernel(const uint_t* __restrict__ staging,
                                                         const int* __restrict__ bkt_cursor,
                                                         const int* __restrict__ bkt_base,
                                                         int* __restrict__ row_start,
                                                         float* __restrict__ dis,
                                                         int* __restrict__ csr_src, int n) {
    __shared__ int cnt[256];
    __shared__ int buf[256];
    __shared__ int rsS[256];
    __shared__ int seg[BKT_CAP];
    const int t  = threadIdx.x;
    const int b  = blockIdx.x;
    const int lo = b << BKT_SHIFT;
    const int nl = min(256, n - lo);
    cnt[t] = 0;
    __syncthreads();
    const int cntE = min(bkt_cursor[b], BKT_CAP);
    for (int e = t; e < cntE; e += 256) {
        uint_t p = staging[(size_t)b * BKT_CAP + e];
        atomicAdd(&cnt[p & 255u], 1);
    }
    __syncthreads();
    const int v = cnt[t];
    buf[t] = v;
    __syncthreads();
    for (int off = 1; off < 256; off <<= 1) {
        int tt = (t >= off) ? buf[t - off] : 0;
        __syncthreads();
        buf[t] += tt;
        __syncthreads();
    }
    rsS[t] = buf[t] - v;                      // exclusive within-bucket
    const int sbase = bkt_base[b];
    if (t < nl) {
        row_start[lo + t] = sbase + (buf[t] - v);
        dis[lo + t] = rsqrtf((float)(v + 1));
    }
    cnt[t] = 0;                               // reuse as scatter cursor
    __syncthreads();
    for (int e = t; e < cntE; e += 256) {
        uint_t p = staging[(size_t)b * BKT_CAP + e];
        int ln = (int)(p & 255u);
        int q  = atomicAdd(&cnt[ln], 1);
        seg[rsS[ln] + q] = (int)(p >> 8);
    }
    __syncthreads();
    for (int i = t; i < cntE; i += 256) csr_src[sbase + i] = seg[i];
}

// -------------------- weight transposes (one kernel) -----------------------
__global__ void wt_all_kernel(const float* __restrict__ W1, const float* __restrict__ W2,
                              const float* __restrict__ W3,
                              ushort_t* __restrict__ Wt1, ushort_t* __restrict__ Wt2,
                              ushort_t* __restrict__ Wt3) {
    int idx = blockIdx.x * blockDim.x + threadIdx.x;
    if (idx < 32768) {
        int nn = idx >> 8, k = idx & 255;
        Wt1[idx] = f2bf(W1[(size_t)k * 128 + nn]);
    } else if (idx < 49152) {
        int j = idx - 32768;
        int nn = j >> 7, k = j & 127;
        float v = (nn < 100) ? W2[(size_t)k * 100 + nn] : 0.f;
        Wt2[j] = f2bf(v);
    } else if (idx < 57344) {
        int j = idx - 49152;
        int nn = j >> 7, k = j & 127;
        float v = (k < 100 && nn < 32) ? W3[(size_t)k * 32 + nn] : 0.f;
        Wt3[j] = f2bf(v);
    }
}

// --------------------------- tiled MFMA GEMM -------------------------------
// C[M x BN] (bf16) = dis[row] * (A[M x K] @ Wt[BN x K]^T), BN = NFR*32 = all N.
// BM=64, BK=64, 4 waves (2M x 2N). LDS-staged A and B tiles (+8 pad).
// A_FP32: fp32 A converted to bf16 during staging (layer 1, reads x once).
// Swapped-operand MFMA -> lane holds row rsel, cols q*4..+3 -> uint2 stores.
template <bool A_FP32, int NFR>
__global__ __launch_bounds__(256) void gemm_tile(const void* __restrict__ Av,
                                                 const ushort_t* __restrict__ Bt,
                                                 ushort_t* __restrict__ C,
                                                 const float* __restrict__ dis,
                                                 int M, int K, int lda, int ldb, int ldc) {
    constexpr int BN = NFR * 32;
    __shared__ __attribute__((aligned(16))) ushort_t As[64][72];   // +8 pad
    __shared__ __attribute__((aligned(16))) ushort_t Bs[BN][72];

    const int t    = threadIdx.x;
    const int lane = t & 63;
    const int w    = t >> 6;
    const int wm   = w >> 1, wn = w & 1;
    const int m0   = blockIdx.x * 64;
    const int rsel = lane & 15;
    const int q    = lane >> 4;

    f32x4 acc[2][NFR];
    #pragma unroll
    for (int mi = 0; mi < 2; ++mi)
        #pragma unroll
        for (int ni = 0; ni < NFR; ++ni) acc[mi][ni] = (f32x4){0.f, 0.f, 0.f, 0.f};

    const int srow = t >> 3;          // 0..31
    const int scol = (t & 7) * 8;     // 0..56

    for (int k0 = 0; k0 < K; k0 += 64) {
        #pragma unroll
        for (int it = 0; it < 2; ++it) {            // A tile 64x64
            int r = srow + it * 32;
            int gm = m0 + r;
            bf16x8 v = {0, 0, 0, 0, 0, 0, 0, 0};
            if (gm < M) {
                if (A_FP32) {
                    const float* A = (const float*)Av;
                    const float4 f0 = *(const float4*)(A + (size_t)gm * lda + k0 + scol);
                    const float4 f1 = *(const float4*)(A + (size_t)gm * lda + k0 + scol + 4);
                    ushort_t o[8] = { f2bf(f0.x), f2bf(f0.y), f2bf(f0.z), f2bf(f0.w),
                                      f2bf(f1.x), f2bf(f1.y), f2bf(f1.z), f2bf(f1.w) };
                    v = *(const bf16x8*)o;
                } else {
                    const ushort_t* A = (const ushort_t*)Av;
                    v = *(const bf16x8*)(A + (size_t)gm * lda + k0 + scol);
                }
            }
            *(bf16x8*)&As[r][scol] = v;
        }
        #pragma unroll
        for (int it = 0; it < BN / 32; ++it) {      // B tile BNx64
            int r = srow + it * 32;
            bf16x8 v = *(const bf16x8*)(Bt + (size_t)r * ldb + k0 + scol);
            *(bf16x8*)&Bs[r][scol] = v;
        }
        __syncthreads();
        #pragma unroll
        for (int ks = 0; ks < 2; ++ks) {
            const int kc = ks * 32 + q * 8;
            bf16x8 af[2], bfr[NFR];
            #pragma unroll
            for (int mi = 0; mi < 2; ++mi)
                af[mi] = *(const bf16x8*)&As[wm * 32 + mi * 16 + rsel][kc];
            #pragma unroll
            for (int ni = 0; ni < NFR; ++ni)
                bfr[ni] = *(const bf16x8*)&Bs[wn * (BN / 2) + ni * 16 + rsel][kc];
            #pragma unroll
            for (int mi = 0; mi < 2; ++mi)
                #pragma unroll
                for (int ni = 0; ni < NFR; ++ni)
                    acc[mi][ni] = __builtin_amdgcn_mfma_f32_16x16x32_bf16(
                        bfr[ni], af[mi], acc[mi][ni], 0, 0, 0);
        }
        __syncthreads();
    }

    // swapped-operand C/D layout: row = rsel, cols = q*4 .. q*4+3 (uint2)
    #pragma unroll
    for (int mi = 0; mi < 2; ++mi) {
        const int gm = m0 + wm * 32 + mi * 16 + rsel;
        if (gm >= M) continue;
        const float d = dis[gm];
        #pragma unroll
        for (int ni = 0; ni < NFR; ++ni) {
            uint2 o;
            o.x = (uint_t)f2bf(acc[mi][ni][0] * d) | ((uint_t)f2bf(acc[mi][ni][1] * d) << 16);
            o.y = (uint_t)f2bf(acc[mi][ni][2] * d) | ((uint_t)f2bf(acc[mi][ni][3] * d) << 16);
            *(uint2*)(C + (size_t)gm * ldc + wn * (BN / 2) + ni * 16 + q * 4) = o;
        }
    }
}

// ---------------------------- aggregation ---------------------------------
// h rows pre-scaled (h' = dis*h), row = 256B aligned. 4 nodes per wave,
// 16 lanes per node (lane = 16B chunk). 8 gathers in flight per iter.
// No cross-lane merge; prologue/epilogue/store all 64 lanes productive.
template <int F>
__global__ void aggregate128_kernel(const ushort_t* __restrict__ h, const int* __restrict__ row_start,
                                    const int* __restrict__ csr_src,
                                    const float* __restrict__ dis, const float* __restrict__ bias,
                                    ushort_t* __restrict__ out, int n) {
    const int lane = threadIdx.x & 63;
    const int grp  = lane >> 4;                     // node-group within wave
    const int node = blockIdx.x * 16 + (int)(threadIdx.x >> 6) * 4 + grp;
    if (node >= n) return;
    const uint_t fbb = (uint_t)(lane & 15) << 4;    // byte offset within row
    const char* hb = (const char*)h;
    float a[8];
    #pragma unroll
    for (int j = 0; j < 8; ++j) a[j] = 0.f;

    int i = row_start[node];
    const int end = row_start[node + 1];

#define LOADR(S) (*(const uint4*)(hb + (((uint_t)(S) << 8) + fbb)))
#define ACC8(U)                                                     \
    do {                                                            \
        a[0] += bflo((U).x); a[1] += bfhi((U).x);                   \
        a[2] += bflo((U).y); a[3] += bfhi((U).y);                   \
        a[4] += bflo((U).z); a[5] += bfhi((U).z);                   \
        a[6] += bflo((U).w); a[7] += bfhi((U).w);                   \
    } while (0)

    for (; i + 8 <= end; i += 8) {                  // 8 gathers in flight
        int s0 = csr_src[i];
        int s1 = csr_src[i + 1];
        int s2 = csr_src[i + 2];
        int s3 = csr_src[i + 3];
        int s4 = csr_src[i + 4];
        int s5 = csr_src[i + 5];
        int s6 = csr_src[i + 6];
        int s7 = csr_src[i + 7];
        uint4 u0 = LOADR(s0);
        uint4 u1 = LOADR(s1);
        uint4 u2 = LOADR(s2);
        uint4 u3 = LOADR(s3);
        uint4 u4 = LOADR(s4);
        uint4 u5 = LOADR(s5);
        uint4 u6 = LOADR(s6);
        uint4 u7 = LOADR(s7);
        ACC8(u0); ACC8(u1); ACC8(u2); ACC8(u3);
        ACC8(u4); ACC8(u5); ACC8(u6); ACC8(u7);
    }
    for (; i + 4 <= end; i += 4) {
        int s0 = csr_src[i];
        int s1 = csr_src[i + 1];
        int s2 = csr_src[i + 2];
        int s3 = csr_src[i + 3];
        uint4 u0 = LOADR(s0);
        uint4 u1 = LOADR(s1);
        uint4 u2 = LOADR(s2);
        uint4 u3 = LOADR(s3);
        ACC8(u0); ACC8(u1); ACC8(u2); ACC8(u3);
    }
    for (; i < end; ++i) {
        uint4 u = LOADR(csr_src[i]);
        ACC8(u);
    }
    {
        uint4 su = LOADR(node);                     // self-loop (pre-scaled)
        ACC8(su);
    }
    float dn = dis[node];
    const int fb = (lane & 15) * 8;
    #pragma unroll
    for (int j = 0; j < 8; ++j) {
        float b = (fb + j < F) ? bias[fb + j] : 0.f;
        float v = a[j] * dn + b;
        v = (v > 0.f) ? v : 0.1f * v;
        if (fb + j >= F) v = 0.f;                   // keep K-padding exactly zero
        a[j] = v;
    }
    uint4 o;
    o.x = (uint_t)f2bf(a[0]) | ((uint_t)f2bf(a[1]) << 16);
    o.y = (uint_t)f2bf(a[2]) | ((uint_t)f2bf(a[3]) << 16);
    o.z = (uint_t)f2bf(a[4]) | ((uint_t)f2bf(a[5]) << 16);
    o.w = (uint_t)f2bf(a[6]) | ((uint_t)f2bf(a[7]) << 16);
    *(uint4*)((char*)out + (((uint_t)node << 8) + fbb)) = o;
#undef ACC8
#undef LOADR
}

// F=32 aggregation fused with layer-4 GEMM (32->2): 16-lane group per node
// (2 features/lane), 4 nodes/wave. After bias+lrelu, each lane computes its
// 2x2 partial product with W4, 4-round shfl_xor reduce, lane0 writes
// C4[node] = dis[node] * (h3[node] @ W4).
__global__ void aggregate32_w4_kernel(const ushort_t* __restrict__ h, const int* __restrict__ row_start,
                                      const int* __restrict__ csr_src,
                                      const float* __restrict__ dis, const float* __restrict__ bias,
                                      const float* __restrict__ W4, float* __restrict__ C4, int n) {
    int lane16 = threadIdx.x & 15;
    int node = blockIdx.x * (blockDim.x >> 4) + (threadIdx.x >> 4);
    if (node >= n) return;
    const uint_t fbb = (uint_t)lane16 << 2;        // byte offset within 64B row
    const char* hb = (const char*)h;
#define LOADR32(S) (*(const uint_t*)(hb + (((uint_t)(S) << 6) + fbb)))
    uint_t v = LOADR32(node);
    float acc0 = bflo(v);               // self-loop (pre-scaled)
    float acc1 = bfhi(v);
    int i = row_start[node], end = row_start[node + 1];
    for (; i + 4 <= end; i += 4) {
        uint_t u0 = LOADR32(csr_src[i]);
        uint_t u1 = LOADR32(csr_src[i + 1]);
        uint_t u2 = LOADR32(csr_src[i + 2]);
        uint_t u3 = LOADR32(csr_src[i + 3]);
        acc0 += bflo(u0) + bflo(u1) + bflo(u2) + bflo(u3);
        acc1 += bfhi(u0) + bfhi(u1) + bfhi(u2) + bfhi(u3);
    }
    for (; i < end; ++i) {
        uint_t u = LOADR32(csr_src[i]);
        acc0 += bflo(u); acc1 += bfhi(u);
    }
#undef LOADR32
    float dn = dis[node];
    const int f0 = 2 * lane16;
    acc0 = acc0 * dn + bias[f0];
    acc1 = acc1 * dn + bias[f0 + 1];
    acc0 = (acc0 > 0.f) ? acc0 : 0.1f * acc0;
    acc1 = (acc1 > 0.f) ? acc1 : 0.1f * acc1;
    // fused 32->2 GEMM: W4 row-major [32][2]; lane covers rows f0, f0+1
    const float4 w = *(const float4*)(W4 + 4 * lane16);  // {W4[f0][0],W4[f0][1],W4[f1][0],W4[f1][1]}
    float p0 = acc0 * w.x + acc1 * w.z;
    float p1 = acc0 * w.y + acc1 * w.w;
    #pragma unroll
    for (int m = 1; m < 16; m <<= 1) {
        p0 += __shfl_xor(p0, m);
        p1 += __shfl_xor(p1, m);
    }
    if (lane16 == 0) {
        float2 o = { p0 * dn, p1 * dn };
        *(float2*)(C4 + 2 * (size_t)node) = o;
    }
}

// final aggregation (F=2, h pre-scaled) + bias + softmax, one thread per node
__global__ void aggregate2_softmax_kernel(const float* __restrict__ h, const int* __restrict__ row_start,
                                          const int* __restrict__ csr_src,
                                          const float* __restrict__ dis, const float* __restrict__ bias,
                                          float* __restrict__ out, int n) {
    int node = blockIdx.x * blockDim.x + threadIdx.x;
    if (node >= n) return;
    const char* hb = (const char*)h;
    float a0 = h[2 * (size_t)node];
    float a1 = h[2 * (size_t)node + 1];
    int beg = row_start[node], end = row_start[node + 1];
    for (int i = beg; i < end; ++i) {
        uint_t off = (uint_t)csr_src[i] << 3;
        float2 u = *(const float2*)(hb + off);
        a0 += u.x;
        a1 += u.y;
    }
    float dn = dis[node];
    a0 = a0 * dn + bias[0];
    a1 = a1 * dn + bias[1];
    float m  = fmaxf(a0, a1);
    float e0 = expf(a0 - m), e1 = expf(a1 - m);
    float inv = 1.f / (e0 + e1);
    out[2 * (size_t)node]     = e0 * inv;
    out[2 * (size_t)node + 1] = e1 * inv;
}

// ---------------------------------------------------------------------------

extern "C" void kernel_launch(void* const* d_in, const int* in_sizes, int n_in,
                              void* d_out, int out_size, void* d_ws, size_t ws_size,
                              hipStream_t stream) {
    const float* x  = (const float*)d_in[0];
    const int*   ei = (const int*)d_in[1];
    const float* W1 = (const float*)d_in[2];
    const float* b1 = (const float*)d_in[3];
    const float* W2 = (const float*)d_in[4];
    const float* b2 = (const float*)d_in[5];
    const float* W3 = (const float*)d_in[6];
    const float* b3 = (const float*)d_in[7];
    const float* W4 = (const float*)d_in[8];
    const float* b4 = (const float*)d_in[9];

    const int N = in_sizes[0] / 256;
    const int E = in_sizes[1] / 2;
    const int* srcA = ei;
    const int* dstA = ei + E;
    const int nbkt = (N + 255) >> BKT_SHIFT;

    char* ws = (char*)d_ws;
    size_t off = 0;
    auto alloc = [&](size_t bytes) {
        void* p = ws + off;
        off = (off + bytes + 255) & ~(size_t)255;
        return p;
    };
    float*    dis        = (float*)alloc((size_t)N * 4);
    int*      row_start  = (int*)alloc((size_t)(N + 1) * 4);
    int*      bkt_cursor = (int*)alloc(512 * 4);
    int*      bkt_base   = (int*)alloc(512 * 4);
    int*      csr_src    = (int*)alloc((size_t)E * 4);
    uint_t*   staging    = (uint_t*)alloc((size_t)nbkt * BKT_CAP * 4);
    ushort_t* bufA       = (ushort_t*)alloc((size_t)N * 128 * 2);
    ushort_t* bufB       = (ushort_t*)alloc((size_t)N * 128 * 2);
    float*    C4         = (float*)alloc((size_t)N * 2 * 4);
    ushort_t* Wt1        = (ushort_t*)alloc((size_t)128 * 256 * 2);
    ushort_t* Wt2        = (ushort_t*)alloc((size_t)128 * 128 * 2);
    ushort_t* Wt3        = (ushort_t*)alloc((size_t)64 * 128 * 2);
    (void)ws_size;

    hipMemsetAsync(bkt_cursor, 0, 512 * 4, stream);

    // graph prep (bucketed, fused, packed staging)
    bin_kernel<<<(E + BIN_CHUNK - 1) / BIN_CHUNK, 256, 0, stream>>>(
        srcA, dstA, bkt_cursor, staging, E, nbkt);
    bucket_scan_kernel<<<1, 512, 0, stream>>>(bkt_cursor, bkt_base, row_start, nbkt, N);
    csr_build2_kernel<<<nbkt, 256, 0, stream>>>(staging, bkt_cursor, bkt_base,
                                                row_start, dis, csr_src, N);

    // weight transposes (bf16, padded)
    wt_all_kernel<<<(57344 + 255) / 256, 256, 0, stream>>>(W1, W2, W3, Wt1, Wt2, Wt3);

    const int gx = (N + 63) / 64;            // 64 rows per block
    const int aggBlocks = (N + 15) / 16;     // 16 nodes/block

    // layer 1: 256 -> 128, fp32 A converted in-staging (x read once)
    gemm_tile<true, 4><<<gx, 256, 0, stream>>>(x, Wt1, bufA, dis, N, 256, 256, 256, 128);
    aggregate128_kernel<128><<<aggBlocks, 256, 0, stream>>>(
        bufA, row_start, csr_src, dis, b1, bufB, N);
    // layer 2: 128 -> 100 (padded to 128, 256B-aligned rows)
    gemm_tile<false, 4><<<gx, 256, 0, stream>>>(bufB, Wt2, bufA, dis, N, 128, 128, 128, 128);
    aggregate128_kernel<100><<<aggBlocks, 256, 0, stream>>>(
        bufA, row_start, csr_src, dis, b2, bufB, N);
    // layer 3: 128(pad) -> 32 (BN=32)
    gemm_tile<false, 1><<<gx, 256, 0, stream>>>(bufB, Wt3, bufA, dis, N, 128, 128, 128, 32);
    // layer 3 aggregation + fused layer-4 GEMM (32 -> 2)
    aggregate32_w4_kernel<<<aggBlocks, 256, 0, stream>>>(
        bufA, row_start, csr_src, dis, b3, W4, C4, N);
    // final aggregation + softmax
    aggregate2_softmax_kernel<<<(N + 255) / 256, 256, 0, stream>>>(
        C4, row_start, csr_src, dis, b4, (float*)d_out, N);
}